// Round 8
// baseline (1456.428 us; speedup 1.0000x reference)
//
#include <hip/hip_runtime.h>

#define LLEN 128
#define BB 4
#define DD 768
#define HH 300
#define G5 1500
#define H3 900
#define NTT 7
#define NRR 12
#define NCHB 10
#define RPB 150
#define OPB 30

// ---- fp32 workspace layout (ws as float*) ----
#define C_WIH  0
#define C_X    1152000
#define C_WHH2 1545216
#define C_WTR2 1995216
#define F_BIH  2265216
#define F_BTR  2266720
#define F_PRE  2267040
// PRE region reused after the scan:
#define F_HG0  (F_PRE)
#define F_HG1  (F_PRE+153600)
#define F_A0   (F_PRE+307200)
#define F_E0   (F_PRE+460800)
#define F_GF0  (F_PRE+616832)
#define F_GF1  (F_PRE+618048)
// beyond PRE:
#define F_HNER (F_PRE+768000)
#define F_HRE  (F_HNER+153600)
#define F_HSH  (F_HRE+153600)
#define F_A1   0
#define F_E1   153600
#define F_AUX  (F_HSH+153600)
// scanA exchange buffers in the scan-dead C_WIH region [0,1152000):
//   partials: part(buf,b) = buf*96000 + b*24000: 1500 rows x 16 floats
//   (cols 0..9 partial sums, 10..11 zero pads, 12..15 never read) [R6-proven]
//   c_pub: 192000 + (buf*4+b)*304
#define P_CPUB 192000
// aux per-batch (AUXB floats): selftest words only
//   scanA: tst @ gb+2176, seflag @ gb+2208 ; scanB: tst @ gb+2240, seflag @ gb+2272
#define AUXB   2432
#define AUX_FL 9728
// int area (2048 ints, zeroed per launch):
//   chunk0 (scanA): claim [0,32); per batch b: slotsA[16] atf[0..4] abort@+24 at [32+64b)
//   chunk1 (scanB): claim [640,672); per batch b: slotsA[16] slotsB[16] atf[5] at [672+64b)
//   done[4] @ [1536,1540)  (scanA completion counters; scanB skips batch iff ==NCHB)
#define WS_NEED_BYTES ((size_t)(F_AUX+11776)*4)

typedef unsigned short u16;
typedef unsigned int u32;
typedef float f4 __attribute__((ext_vector_type(4)));
typedef int i4 __attribute__((ext_vector_type(4)));

__device__ __forceinline__ float bf2f(u16 u) {
  union { u32 i; float f; } v; v.i = ((u32)u) << 16; return v.f;
}
__device__ __forceinline__ u16 f2bf(float f) {
  union { float f; u32 i; } v; v.f = f;
  u32 r = v.i + 0x7fffu + ((v.i >> 16) & 1u);
  return (u16)(r >> 16);
}
__device__ __forceinline__ float ldin(const void* p, int i, bool f32) {
  return f32 ? ((const float*)p)[i] : bf2f(((const u16*)p)[i]);
}
__device__ __forceinline__ bool is32(const void* mk) {
  return ((const u16*)mk)[0] == 0;
}
__device__ __forceinline__ float wsum(float x) {
  #pragma unroll
  for (int d = 1; d < 64; d <<= 1) x += __shfl_xor(x, d);
  return x;
}
// ---- agent-scope (LLC) accessors ----
__device__ __forceinline__ void astore(float* p, float v) {
  union { float f; int i; } u; u.f = v;
  __hip_atomic_store((int*)p, u.i, __ATOMIC_RELAXED, __HIP_MEMORY_SCOPE_AGENT);
}
// proven agent-scope inter-block barrier (selftest/claim only)
__device__ __forceinline__ void gbar(int* flag, int tid, int target) {
  __syncthreads();
  if (tid == 0) {
    __builtin_amdgcn_s_waitcnt(0);
    __hip_atomic_fetch_add(flag, 1, __ATOMIC_RELAXED, __HIP_MEMORY_SCOPE_AGENT);
    int it = 0;
    while (__hip_atomic_load(flag, __ATOMIC_RELAXED, __HIP_MEMORY_SCOPE_AGENT) < target) {
      __builtin_amdgcn_s_sleep(1);
      if (++it > 50000) break;
    }
  }
  __syncthreads();
}
// ---- scoped exchange primitives (mode 1 = XCD/L2, mode 0 = agent/LLC) ----
__device__ __forceinline__ f4 ld4x(const f4* p, int mode) {
  f4 v;
  if (mode)
    asm volatile("global_load_dwordx4 %0, %1, off sc0\n\ts_waitcnt vmcnt(0)"
                 : "=v"(v) : "v"(p) : "memory");
  else
    asm volatile("global_load_dwordx4 %0, %1, off sc0 sc1\n\ts_waitcnt vmcnt(0)"
                 : "=v"(v) : "v"(p) : "memory");
  return v;
}
__device__ __forceinline__ float ld1x(const float* p, int mode) {
  float v;
  if (mode)
    asm volatile("global_load_dword %0, %1, off sc0\n\ts_waitcnt vmcnt(0)"
                 : "=v"(v) : "v"(p) : "memory");
  else
    asm volatile("global_load_dword %0, %1, off sc0 sc1\n\ts_waitcnt vmcnt(0)"
                 : "=v"(v) : "v"(p) : "memory");
  return v;
}
__device__ __forceinline__ int ldix(const int* p, int mode) {
  int v;
  if (mode)
    asm volatile("global_load_dword %0, %1, off sc0\n\ts_waitcnt vmcnt(0)"
                 : "=v"(v) : "v"(p) : "memory");
  else
    asm volatile("global_load_dword %0, %1, off sc0 sc1\n\ts_waitcnt vmcnt(0)"
                 : "=v"(v) : "v"(p) : "memory");
  return v;
}
__device__ __forceinline__ void exst(float* p, float v, int mode) {
  if (mode) *p = v; else astore(p, v);
}
// 9 overlapped dwordx4 from one 64B-aligned base (3 rows x 3 quads), mode-1 only
__device__ __forceinline__ void ld9(const float* base,
                                    f4& a0, f4& a1, f4& a2, f4& a3, f4& a4,
                                    f4& a5, f4& a6, f4& a7, f4& a8) {
  asm volatile(
    "global_load_dwordx4 %0, %9, off sc0\n\t"
    "global_load_dwordx4 %1, %9, off offset:16 sc0\n\t"
    "global_load_dwordx4 %2, %9, off offset:32 sc0\n\t"
    "global_load_dwordx4 %3, %9, off offset:64 sc0\n\t"
    "global_load_dwordx4 %4, %9, off offset:80 sc0\n\t"
    "global_load_dwordx4 %5, %9, off offset:96 sc0\n\t"
    "global_load_dwordx4 %6, %9, off offset:128 sc0\n\t"
    "global_load_dwordx4 %7, %9, off offset:144 sc0\n\t"
    "global_load_dwordx4 %8, %9, off offset:160 sc0\n\t"
    "s_waitcnt vmcnt(0)"
    : "=&v"(a0), "=&v"(a1), "=&v"(a2), "=&v"(a3), "=&v"(a4),
      "=&v"(a5), "=&v"(a6), "=&v"(a7), "=&v"(a8)
    : "v"(base) : "memory");
}
// poll all 10 arrival slots (12 loaded; last 2 zero padding)
__device__ __forceinline__ int poll10(const int* slots, int tok, int mode) {
  i4 a, b, c;
  if (mode)
    asm volatile("global_load_dwordx4 %0, %3, off sc0\n\t"
                 "global_load_dwordx4 %1, %4, off sc0\n\t"
                 "global_load_dwordx4 %2, %5, off sc0\n\t"
                 "s_waitcnt vmcnt(0)"
                 : "=&v"(a), "=&v"(b), "=&v"(c)
                 : "v"(slots), "v"(slots + 4), "v"(slots + 8) : "memory");
  else
    asm volatile("global_load_dwordx4 %0, %3, off sc0 sc1\n\t"
                 "global_load_dwordx4 %1, %4, off sc0 sc1\n\t"
                 "global_load_dwordx4 %2, %5, off sc0 sc1\n\t"
                 "s_waitcnt vmcnt(0)"
                 : "=&v"(a), "=&v"(b), "=&v"(c)
                 : "v"(slots), "v"(slots + 4), "v"(slots + 8) : "memory");
  return (a.x >= tok) & (a.y >= tok) & (a.z >= tok) & (a.w >= tok) &
         (b.x >= tok) & (b.y >= tok) & (b.z >= tok) & (b.w >= tok) &
         (c.x >= tok) & (c.y >= tok);
}
// slot barrier (scanB, proven): drain + sync + tid0 token store; wave 0 polls
__device__ __forceinline__ void sbar(int* slots, int ch, int tok, int tid, int mode) {
  asm volatile("s_waitcnt vmcnt(0)" ::: "memory");
  __syncthreads();
  if (tid == 0) {
    if (mode) slots[ch] = tok;
    else __hip_atomic_store(slots + ch, tok, __ATOMIC_RELAXED, __HIP_MEMORY_SCOPE_AGENT);
  }
  if (tid < 64) {
    int it = 0;
    while (!poll10(slots, tok, mode)) {
      __builtin_amdgcn_s_sleep(1);
      if (++it > 5000) break;
    }
  }
  __syncthreads();
}
// scanA slot barrier: mode-1, with timeout detection + abort propagation
__device__ __forceinline__ void sbarA(int* slots, int* abf, int ch, int tok, int tid,
                                      volatile int* s_fail) {
  asm volatile("s_waitcnt vmcnt(0)" ::: "memory");
  __syncthreads();
  if (tid == 0) slots[ch] = tok;
  if (tid < 64) {
    int it = 0;
    while (!poll10(slots, tok, 1)) {
      __builtin_amdgcn_s_sleep(1);
      ++it;
      if ((it & 255) == 0 &&
          __hip_atomic_load(abf, __ATOMIC_RELAXED, __HIP_MEMORY_SCOPE_AGENT) != 0) {
        *s_fail = 1; break;
      }
      if (it > 5000) {
        __hip_atomic_store(abf, 1, __ATOMIC_RELAXED, __HIP_MEMORY_SCOPE_AGENT);
        *s_fail = 1; break;
      }
    }
  }
  __syncthreads();
}
// claim (xcd, rank) via HW_REG_XCC_ID + grid rendezvous
__device__ __forceinline__ int claim_bc(int* cl, int nb) {
  unsigned xcd;
  asm volatile("s_getreg_b32 %0, hwreg(HW_REG_XCC_ID)" : "=s"(xcd));
  xcd &= 7u;
  int rank = __hip_atomic_fetch_add(cl + xcd, 1, __ATOMIC_RELAXED, __HIP_MEMORY_SCOPE_AGENT);
  __hip_atomic_fetch_add(cl + 8, 1, __ATOMIC_RELAXED, __HIP_MEMORY_SCOPE_AGENT);
  int it = 0;
  while (__hip_atomic_load(cl + 8, __ATOMIC_RELAXED, __HIP_MEMORY_SCOPE_AGENT) < nb) {
    __builtin_amdgcn_s_sleep(2);
    if (++it > 100000) break;
  }
  int base = 0;
  for (unsigned x = 0; x < xcd; ++x)
    base += __hip_atomic_load(cl + x, __ATOMIC_RELAXED, __HIP_MEMORY_SCOPE_AGENT) / NCHB;
  int cnt = __hip_atomic_load(cl + xcd, __ATOMIC_RELAXED, __HIP_MEMORY_SCOPE_AGENT);
  int slot = base + rank / NCHB;
  return (rank < (cnt / NCHB) * NCHB && slot < BB) ? (slot * 16 + rank % NCHB) : -1;
}

// ---- canonicalize ----
__global__ void k_canon(const void* xo, const void* mk, const void* Wih, const void* bih,
                        const void* Whh, const void* bhh, const void* Wtr, const void* btr,
                        float* ws) {
  bool f32 = is32(mk);
  int piece = blockIdx.y;
  int i = blockIdx.x * 256 + threadIdx.x;
  switch (piece) {
    case 0: if (!f32 && i < 1152000) ws[C_WIH + i] = ldin(Wih, i, f32); break;
    case 1: if (!f32 && i < 393216)  ws[C_X + i]   = ldin(xo, i, f32);  break;
    case 2: if (i < 225000) {
      int k2 = i / G5, out = i - k2 * G5;
      float2 v;
      v.x = ldin(Whh, out * HH + 2 * k2, f32);
      v.y = ldin(Whh, out * HH + 2 * k2 + 1, f32);
      ((float2*)(ws + C_WHH2))[i] = v;
    } break;
    case 3: if (i < 135000) {
      int k2 = i / HH, out = i - k2 * HH;
      float2 v;
      v.x = ldin(Wtr, out * H3 + 2 * k2, f32);
      v.y = ldin(Wtr, out * H3 + 2 * k2 + 1, f32);
      ((float2*)(ws + C_WTR2))[i] = v;
    } break;
    case 4: {
      if (i < 1504) ws[F_BIH + i] = (i < G5) ? ldin(bih, i, f32) + ldin(bhh, i, f32) : 0.f;
      else if (i < 1824) { int j = i - 1504; ws[F_BTR + j] = (j < HH) ? ldin(btr, j, f32) : 0.f; }
    } break;
    case 5: if (i < 11776) ws[F_AUX + i] = 0.f; break;
  }
}

// ---- pre = x @ W_ih^T + (b_ih + b_hh) ----
__global__ void k_pre2(const void* xo, const void* Wo, const void* mk,
                       const float* cX, const float* cW, const float* biasf, float* pre) {
  bool f32 = is32(mk);
  const float* X = f32 ? (const float*)xo : cX;
  const float* W = f32 ? (const float*)Wo : cW;
  __shared__ __align__(16) float xl[8 * DD];
  int tid = threadIdx.x;
  int lb0 = (blockIdx.x >> 1) * 8;
  int half = blockIdx.x & 1;
  for (int e = tid; e < 8 * DD; e += 256) xl[e] = X[(size_t)lb0 * DD + e];
  __syncthreads();
  for (int j = half * 750 + tid; j < half * 750 + 750; j += 256) {
    const float4* w = (const float4*)(W + (size_t)j * DD);
    float acc[8] = {0.f, 0.f, 0.f, 0.f, 0.f, 0.f, 0.f, 0.f};
    #pragma unroll 2
    for (int k = 0; k < DD / 4; ++k) {
      float4 u = w[k];
      #pragma unroll
      for (int r = 0; r < 8; ++r) {
        const float4 p = *(const float4*)(xl + r * DD + k * 4);
        acc[r] += u.x * p.x + u.y * p.y + u.z * p.z + u.w * p.w;
      }
    }
    float bias = biasf[j];
    #pragma unroll
    for (int r = 0; r < 8; ++r) pre[(size_t)(lb0 + r) * G5 + j] = acc[r] + bias;
  }
}

// ---- scanA: 1-barrier/step, MODE-1 ONLY; warm-form selftest gate + end verification ----
__global__ void __launch_bounds__(512, 2) k_scanA(const float* pre, const float2* W2h, const float2* W2t,
                                                  const float* btrf, float* hner, float* hre, float* hsh,
                                                  float* aux, float* xw) {
  __shared__ __align__(16) float ga_l[1504];
  __shared__ __align__(16) float vv_l[1204];
  __shared__ __align__(16) float tnh_l[304];
  __shared__ __align__(16) float cat_l[904];
  __shared__ __align__(16) float ci_l[304];
  __shared__ __align__(16) float ps[512];
  __shared__ __align__(16) float h_loc[32];
  __shared__ int s_bc, s_mode;
  __shared__ int s_fail;
  int tid = threadIdx.x;
  int* ibase = (int*)(aux + AUX_FL);
  if (tid == 0) { s_bc = claim_bc(ibase, (int)gridDim.x); s_fail = 0; }
  __syncthreads();
  int bc = s_bc;
  if (bc < 0) return;
  int b = bc >> 4, ch = bc & 15;
  float* gb = aux + b * AUXB;
  int* slotsA = ibase + 32 + b * 64;
  int* atf    = slotsA + 16;
  int* abf    = slotsA + 24;
  int* done   = ibase + 1536;

  // ---- warm-form runtime coherence selftest (VERBATIM proven form; own words) ----
  {
    float* tst = gb + 2176;
    int* seflag = (int*)(gb + 2208);
    if (ch == 0 && tid == 0) tst[0] = 1.0f;
    gbar(atf + 0, tid, NCHB);
    if (tid == 0) { float w1 = ld1x(tst, 1); (void)w1; }
    gbar(atf + 1, tid, NCHB);
    if (ch == 0 && tid == 0) { tst[0] = 2.0f; __builtin_amdgcn_s_waitcnt(0); }
    if (ch == 1 && tid == 0)
      __hip_atomic_fetch_add(seflag, 1, __ATOMIC_RELAXED, __HIP_MEMORY_SCOPE_WORKGROUP);
    gbar(atf + 2, tid, NCHB);
    if (tid == 0) {
      float w2 = ld1x(tst, 1);
      int fv = ldix(seflag, 1);
      if (w2 != 2.0f || fv != 1)
        __hip_atomic_fetch_or(atf + 4, 1, __ATOMIC_RELAXED, __HIP_MEMORY_SCOPE_AGENT);
    }
    gbar(atf + 3, tid, NCHB);
    if (tid == 0)
      s_mode = (__hip_atomic_load(atf + 4, __ATOMIC_RELAXED, __HIP_MEMORY_SCOPE_AGENT) == 0) ? 1 : 0;
    __syncthreads();
  }
  if (s_mode == 0) return;  // scanB handles this batch (done stays < NCHB)

  // zero pad columns (10,11) of both partial buffers (plain; published by sbarA(1))
  if (ch < 2) {
    float* pb0 = xw + (size_t)ch * 96000 + b * 24000;
    for (int i = tid; i < 3000; i += 512) {
      int row = i >> 1, col = 10 + (i & 1);
      pb0[row * 16 + col] = 0.f;
    }
  }

  int o0 = 3 * tid;
  float2 wh2[45];
  if (tid < 500) {
    #pragma unroll
    for (int j = 0; j < 3; ++j)
      #pragma unroll
      for (int kk = 0; kk < 15; ++kk)
        wh2[j * 15 + kk] = W2h[(size_t)(ch * 15 + kk) * G5 + (o0 + j)];
  }
  int o2 = tid % OPB, jj = tid / OPB;
  float2 wt[29];
  int k2b = jj * 29;
  int k2e = (k2b + 29 < 450) ? (k2b + 29) : 450;
  int nk2 = k2e - k2b;
  if (tid < 480) {
    const float2* wp = W2t + (size_t)k2b * HH + (ch * OPB + o2);
    #pragma unroll
    for (int q = 0; q < 29; ++q) if (q < nk2) wt[q] = wp[(size_t)q * HH];
  }
  float pv0 = 0.f, pv1 = 0.f, pv2 = 0.f;
  if (tid < 500) {
    const float* pr = pre + (size_t)b * G5 + o0;
    pv0 = pr[0]; pv1 = pr[1]; pv2 = pr[2];
  }
  __syncthreads();

  for (int t = 0; t < LLEN; ++t) {
    int buf = t & 1;
    float* pb = xw + (size_t)buf * 96000 + b * 24000;
    if (t > 0) {
      if (tid < 500) {
        float2 h2[15];
        #pragma unroll
        for (int kk = 0; kk < 15; ++kk) h2[kk] = *(const float2*)(h_loc + 2 * kk);
        #pragma unroll
        for (int j = 0; j < 3; ++j) {
          float acc = 0.f;
          #pragma unroll
          for (int kk = 0; kk < 15; ++kk)
            acc += wh2[j * 15 + kk].x * h2[kk].x + wh2[j * 15 + kk].y * h2[kk].y;
          pb[(size_t)(o0 + j) * 16 + ch] = acc;
        }
      }
      sbarA(slotsA, abf, ch, t, tid, &s_fail);  // the ONLY inter-block barrier
      if (s_fail) return;                        // desync: scanB will redo batch
      if (tid < 500) {
        f4 a0, a1, a2, a3, a4, a5, a6, a7, a8;
        ld9(pb + (size_t)o0 * 16, a0, a1, a2, a3, a4, a5, a6, a7, a8);
        ga_l[o0]     = pv0 + (((a0.x + a0.y) + (a0.z + a0.w)) +
                              ((a1.x + a1.y) + (a1.z + a1.w)) +
                              ((a2.x + a2.y) + (a2.z + a2.w)));
        ga_l[o0 + 1] = pv1 + (((a3.x + a3.y) + (a3.z + a3.w)) +
                              ((a4.x + a4.y) + (a4.z + a4.w)) +
                              ((a5.x + a5.y) + (a5.z + a5.w)));
        ga_l[o0 + 2] = pv2 + (((a6.x + a6.y) + (a6.z + a6.w)) +
                              ((a7.x + a7.y) + (a7.z + a7.w)) +
                              ((a8.x + a8.y) + (a8.z + a8.w)));
      }
      if (tid < 75) {
        const float* cp = xw + P_CPUB + (size_t)(((t - 1) & 1) * 4 + b) * 304;
        f4 v = ld4x((const f4*)cp + tid, 1);
        *(f4*)(ci_l + 4 * tid) = v;
      }
    } else {
      if (tid < 500) { ga_l[o0] = pv0; ga_l[o0 + 1] = pv1; ga_l[o0 + 2] = pv2; }
    }
    __syncthreads();
    if (tid < HH) tnh_l[tid] = tanhf(ga_l[tid]);
    {
      int w = tid >> 6, ln = tid & 63;
      if (w >= 4) {
        int c = w - 3;
        const float* g = ga_l + c * 300;
        int e0 = ln * 5;
        float ex0 = 0.f, ex1 = 0.f, ex2 = 0.f, ex3 = 0.f, ex4 = 0.f;
        if (ln < 60) {
          ex0 = __expf(g[e0]); ex1 = __expf(g[e0 + 1]); ex2 = __expf(g[e0 + 2]);
          ex3 = __expf(g[e0 + 3]); ex4 = __expf(g[e0 + 4]);
        }
        float p = ((ex0 + ex1) + (ex2 + ex3)) + ex4;
        float inc = p;
        #pragma unroll
        for (int d = 1; d < 64; d <<= 1) { float o = __shfl_up(inc, d); if (ln >= d) inc += o; }
        float S = __shfl(inc, 59);
        float invS = 1.f / S;
        float run = inc - p;
        if (ln < 60) {
          float* vv = vv_l + (c - 1) * 300 + e0;
          run += ex0; vv[0] = run * invS;
          run += ex1; vv[1] = run * invS;
          run += ex2; vv[2] = run * invS;
          run += ex3; vv[3] = run * invS;
          run += ex4; vv[4] = run * invS;
        }
      }
    }
    if (t + 1 < LLEN && tid < 500) {
      const float* pr = pre + ((size_t)(t + 1) * BB + b) * G5 + o0;
      pv0 = pr[0]; pv1 = pr[1]; pv2 = pr[2];
    }
    __syncthreads();
    if (tid < HH) {
      float c = tnh_l[tid];
      float v0 = vv_l[tid], v1 = vv_l[300 + tid], v2 = vv_l[600 + tid], v3 = vv_l[900 + tid];
      float eg_cin = 1.f - v0, rg_cin = v1, eg_c = 1.f - v2, rg_c = v3;
      float ci = (t > 0) ? ci_l[tid] : 0.f;
      float ov_c = rg_c * eg_c;
      float up_c = rg_c - ov_c, dn_c = eg_c - ov_c;
      float ov_i = rg_cin * eg_cin;
      float up_i = rg_cin - ov_i, dn_i = eg_cin - ov_i;
      float share = ov_i * ci + ov_c * c;
      float c_re  = up_i * ci + up_c * c + share;
      float c_ner = dn_i * ci + dn_c * c + share;
      cat_l[tid] = c_re; cat_l[HH + tid] = c_ner; cat_l[2 * HH + tid] = share;
      int sb = ch * OPB;
      if (tid >= sb && tid < sb + OPB) {
        size_t ob = ((size_t)t * BB + b) * HH + tid;
        hner[ob] = tanhf(c_ner); hre[ob] = tanhf(c_re); hsh[ob] = tanhf(share);
      }
    }
    __syncthreads();
    if (tid < 480) {
      float acc = 0.f;
      #pragma unroll
      for (int q = 0; q < 29; ++q)
        if (q < nk2) acc += wt[q].x * cat_l[2 * (k2b + q)] + wt[q].y * cat_l[2 * (k2b + q) + 1];
      ps[tid] = acc;
    }
    __syncthreads();
    if (tid < OPB) {
      float co = btrf[ch * OPB + tid];
      #pragma unroll
      for (int q = 0; q < 16; ++q) co += ps[q * OPB + tid];
      h_loc[tid] = tanhf(co);
      float* cp = xw + P_CPUB + (size_t)(buf * 4 + b) * 304;
      cp[ch * OPB + tid] = co;
    }
    __syncthreads();
  }
  // completed with zero timeouts -> publish; scanB (stream-serialized) skips batch
  if (tid == 0 && s_fail == 0)
    __hip_atomic_fetch_add(done + b, 1, __ATOMIC_RELAXED, __HIP_MEMORY_SCOPE_AGENT);
}

// ---- scanB: R4-proven 2-barrier kernel; per-batch skip iff scanA fully done ----
__global__ void __launch_bounds__(512, 2) k_scanB(const float* pre, const float2* W2h, const float2* W2t,
                                                  const float* btrf, float* hner, float* hre, float* hsh,
                                                  float* aux) {
  __shared__ __align__(16) float h_l[304];
  __shared__ __align__(16) float ci_l[304];
  __shared__ __align__(16) float ga_l[1504];
  __shared__ __align__(16) float cat_l[904];
  __shared__ __align__(16) float ps[512];
  __shared__ __align__(16) float sums_l[8];
  __shared__ float exv[160];
  __shared__ int s_bc, s_mode, s_skip;
  int tid = threadIdx.x;
  int* ibase = (int*)(aux + AUX_FL);
  int* cl2 = ibase + 640;
  if (tid == 0) s_bc = claim_bc(cl2, (int)gridDim.x);
  __syncthreads();
  int bc = s_bc;
  if (bc < 0) return;
  int b = bc >> 4, ch = bc & 15;
  int* done = ibase + 1536;
  if (tid == 0)
    s_skip = (__hip_atomic_load(done + b, __ATOMIC_RELAXED, __HIP_MEMORY_SCOPE_AGENT) == NCHB);
  __syncthreads();
  if (s_skip) return;  // scanA fully produced this batch
  int s = ch >> 1;
  int r0 = ch * RPB;
  float* gb   = aux + b * AUXB;
  float* cb   = gb + 1504;
  float* hb   = gb + 1808;
  float* sums = gb + 2112;
  int* slotsA = ibase + 672 + b * 64;
  int* slotsB = slotsA + 16;
  int* atf    = slotsA + 32;

  // ---- selftest (R4-proven form; distinct words from scanA) ----
  {
    float* tst = gb + 2240;
    int* seflag = (int*)(gb + 2272);
    if (ch == 0 && tid == 0) tst[0] = 1.0f;
    gbar(atf + 0, tid, NCHB);
    if (tid == 0) { float w1 = ld1x(tst, 1); (void)w1; }
    gbar(atf + 1, tid, NCHB);
    if (ch == 0 && tid == 0) { tst[0] = 2.0f; __builtin_amdgcn_s_waitcnt(0); }
    if (ch == 1 && tid == 0)
      __hip_atomic_fetch_add(seflag, 1, __ATOMIC_RELAXED, __HIP_MEMORY_SCOPE_WORKGROUP);
    gbar(atf + 2, tid, NCHB);
    if (tid == 0) {
      float w2 = ld1x(tst, 1);
      int fv = ldix(seflag, 1);
      if (w2 != 2.0f || fv != 1)
        __hip_atomic_fetch_or(atf + 4, 1, __ATOMIC_RELAXED, __HIP_MEMORY_SCOPE_AGENT);
    }
    gbar(atf + 3, tid, NCHB);
    if (tid == 0)
      s_mode = (__hip_atomic_load(atf + 4, __ATOMIC_RELAXED, __HIP_MEMORY_SCOPE_AGENT) == 0) ? 1 : 0;
    __syncthreads();
  }
  int mode = s_mode;

  int j = tid / RPB, r = tid - j * RPB;
  int o2 = tid % OPB, jj = tid / OPB;
  int kb = j * 100;

  float2 wh[50];
  if (tid < 450) {
    const float2* wp = W2h + (size_t)(j * 50) * G5 + (r0 + r);
    #pragma unroll
    for (int kk = 0; kk < 50; ++kk) wh[kk] = wp[(size_t)kk * G5];
  }
  float2 wt[29];
  int k2b = jj * 29;
  int k2e = (k2b + 29 < 450) ? (k2b + 29) : 450;
  int nk2 = k2e - k2b;
  if (tid < 480) {
    const float2* wp = W2t + (size_t)k2b * HH + (ch * OPB + o2);
    #pragma unroll
    for (int q = 0; q < 29; ++q) if (q < nk2) wt[q] = wp[(size_t)q * HH];
  }
  float pv = 0.f;
  if (tid < RPB) pv = pre[(size_t)b * G5 + r0 + tid];
  __syncthreads();

  for (int t = 0; t < LLEN; ++t) {
    if (t > 0) {
      if (tid < 75)       { f4 v = ld4x((const f4*)hb + tid, mode); *(f4*)(h_l + 4 * tid) = v; }
      else if (tid < 150) { int q = tid - 75; f4 v = ld4x((const f4*)cb + q, mode); *(f4*)(ci_l + 4 * q) = v; }
      __syncthreads();
    }
    if (tid < 450) {
      float acc = (j == 0) ? pv : 0.f;
      if (t > 0) {
        #pragma unroll
        for (int kk = 0; kk < 50; ++kk)
          acc += wh[kk].x * h_l[kb + 2 * kk] + wh[kk].y * h_l[kb + 2 * kk + 1];
      }
      ps[tid] = acc;
    }
    __syncthreads();
    if (tid < RPB) {
      float g = ps[tid] + ps[RPB + tid] + ps[2 * RPB + tid];
      if (s == 0) exst(gb + r0 + tid, tanhf(g), mode);
      else exv[tid] = __expf(g);
    }
    if (s > 0) {
      __syncthreads();
      if (tid < 30) {
        int base2 = tid * 5;
        float e0 = exv[base2], e1 = exv[base2 + 1], e2 = exv[base2 + 2],
              e3 = exv[base2 + 3], e4 = exv[base2 + 4];
        float p = ((e0 + e1) + (e2 + e3)) + e4;
        float inc = p;
        #pragma unroll
        for (int d = 1; d < 32; d <<= 1) { float o = __shfl_up(inc, d); if (tid >= d) inc += o; }
        float tot = __shfl(inc, 29);
        float run = inc - p;
        run += e0; exst(gb + r0 + base2,     run, mode);
        run += e1; exst(gb + r0 + base2 + 1, run, mode);
        run += e2; exst(gb + r0 + base2 + 2, run, mode);
        run += e3; exst(gb + r0 + base2 + 3, run, mode);
        run += e4; exst(gb + r0 + base2 + 4, run, mode);
        if (tid == 0) exst(sums + (ch - 2), tot, mode);
      }
    }
    sbar(slotsA, ch, t + 1, tid, mode);
    if (tid < 375)      { f4 v = ld4x((const f4*)gb + tid, mode); *(f4*)(ga_l + 4 * tid) = v; }
    else if (tid < 377) { int q = tid - 375; f4 v = ld4x((const f4*)sums + q, mode); *(f4*)(sums_l + 4 * q) = v; }
    float pvn = 0.f;
    if (t + 1 < LLEN && tid < RPB) pvn = pre[((size_t)(t + 1) * BB + b) * G5 + r0 + tid];
    __syncthreads();
    if (tid < HH) {
      float c = ga_l[tid];
      float v[4];
      #pragma unroll
      for (int s1 = 0; s1 < 4; ++s1) {
        float raw = ga_l[(s1 + 1) * HH + tid];
        float off = (tid >= RPB) ? sums_l[2 * s1] : 0.f;
        float S = sums_l[2 * s1] + sums_l[2 * s1 + 1];
        v[s1] = (raw + off) / S;
      }
      float eg_cin = 1.f - v[0], rg_cin = v[1], eg_c = 1.f - v[2], rg_c = v[3];
      float ci = (t > 0) ? ci_l[tid] : 0.f;
      float ov_c = rg_c * eg_c;
      float up_c = rg_c - ov_c, dn_c = eg_c - ov_c;
      float ov_i = rg_cin * eg_cin;
      float up_i = rg_cin - ov_i, dn_i = eg_cin - ov_i;
      float share = ov_i * ci + ov_c * c;
      float c_re  = up_i * ci + up_c * c + share;
      float c_ner = dn_i * ci + dn_c * c + share;
      cat_l[tid] = c_re; cat_l[HH + tid] = c_ner; cat_l[2 * HH + tid] = share;
      int sb = ch * OPB;
      if (tid >= sb && tid < sb + OPB) {
        size_t ob = ((size_t)t * BB + b) * HH + tid;
        hner[ob] = tanhf(c_ner); hre[ob] = tanhf(c_re); hsh[ob] = tanhf(share);
      }
    }
    __syncthreads();
    if (tid < 480) {
      float acc = 0.f;
      #pragma unroll
      for (int q = 0; q < 29; ++q)
        if (q < nk2) acc += wt[q].x * cat_l[2 * (k2b + q)] + wt[q].y * cat_l[2 * (k2b + q) + 1];
      ps[tid] = acc;
    }
    __syncthreads();
    if (tid < OPB) {
      float co = btrf[ch * OPB + tid];
      #pragma unroll
      for (int q = 0; q < 16; ++q) co += ps[q * OPB + tid];
      exst(cb + ch * OPB + tid, co, mode);
      exst(hb + ch * OPB + tid, tanhf(co), mode);
    }
    if (t + 1 < LLEN) sbar(slotsB, ch, t + 1, tid, mode);
    pv = pvn;
  }
}

// ---- h_glob ----
__global__ void k_glob3(const float* hsh, const float* hner, const float* hre,
                        const void* nW, const void* nb, const void* rW, const void* rb,
                        const void* mk, float* hg0, float* hg1) {
  bool f32 = is32(mk);
  int task = blockIdx.x >> 7;
  int lb0 = (blockIdx.x & 127) * 4;
  const float* tsk = task ? hre : hner;
  const void* gWo = task ? rW : nW;
  const void* gbo = task ? rb : nb;
  float* hg = task ? hg1 : hg0;
  __shared__ __align__(16) float catl[2400];
  int tid = threadIdx.x;
  for (int e = tid; e < 2400; e += 320) {
    int rr = e / 600, c = e - rr * 600;
    catl[e] = (c < HH) ? hsh[(size_t)(lb0 + rr) * HH + c] : tsk[(size_t)(lb0 + rr) * HH + (c - HH)];
  }
  __syncthreads();
  if (tid < HH) {
    float bias = ldin(gbo, tid, f32);
    float acc[4] = {bias, bias, bias, bias};
    if (f32) {
      const float4* row = (const float4*)((const float*)gWo + (size_t)tid * 600);
      #pragma unroll 2
      for (int k = 0; k < 150; ++k) {
        float4 u = row[k];
        #pragma unroll
        for (int rr = 0; rr < 4; ++rr) {
          const float4 cv = *(const float4*)(catl + rr * 600 + 4 * k);
          acc[rr] += u.x * cv.x + u.y * cv.y + u.z * cv.z + u.w * cv.w;
        }
      }
    } else {
      for (int k = 0; k < 600; ++k) {
        float w = ldin(gWo, tid * 600 + k, f32);
        #pragma unroll
        for (int rr = 0; rr < 4; ++rr) acc[rr] += w * catl[rr * 600 + k];
      }
    }
    #pragma unroll
    for (int rr = 0; rr < 4; ++rr) hg[(size_t)(lb0 + rr) * HH + tid] = tanhf(acc[rr]);
  }
}

// ---- A/E features ----
__global__ void k_feat2(const float* hner, const float* hre,
                        const void* nhW, const void* nhb, const void* rhW, const void* rhb,
                        const void* mk, float* A0, float* E0, float* A1, float* E1) {
  bool f32 = is32(mk);
  int task = blockIdx.x >> 7;
  int lb0 = (blockIdx.x & 127) * 4;
  const float* tsk = task ? hre : hner;
  const void* hWo = task ? rhW : nhW;
  const void* hbo = task ? rhb : nhb;
  float* A = task ? A1 : A0;
  float* E = task ? E1 : E0;
  __shared__ __align__(16) float tl[1200];
  int tid = threadIdx.x;
  for (int e = tid; e < 1200; e += 320) {
    int rr = e / 300, c = e - rr * 300;
    tl[e] = tsk[(size_t)(lb0 + rr) * HH + c];
  }
  __syncthreads();
  if (tid < HH) {
    float bias = ldin(hbo, tid, f32);
    float a[4] = {bias, bias, bias, bias};
    float ev[4] = {0.f, 0.f, 0.f, 0.f};
    if (f32) {
      const float4* r1 = (const float4*)((const float*)hWo + (size_t)tid * H3);
      const float4* r2 = (const float4*)((const float*)hWo + (size_t)tid * H3 + HH);
      #pragma unroll 2
      for (int k = 0; k < 75; ++k) {
        float4 u = r1[k], w2 = r2[k];
        #pragma unroll
        for (int rr = 0; rr < 4; ++rr) {
          const float4 tv = *(const float4*)(tl + rr * 300 + 4 * k);
          a[rr]  += u.x * tv.x + u.y * tv.y + u.z * tv.z + u.w * tv.w;
          ev[rr] += w2.x * tv.x + w2.y * tv.y + w2.z * tv.z + w2.w * tv.w;
        }
      }
    } else {
      for (int k = 0; k < HH; ++k) {
        float w1 = ldin(hWo, tid * H3 + k, f32);
        float w2 = ldin(hWo, tid * H3 + HH + k, f32);
        #pragma unroll
        for (int rr = 0; rr < 4; ++rr) {
          a[rr] += w1 * tl[rr * 300 + k];
          ev[rr] += w2 * tl[rr * 300 + k];
        }
      }
    }
    #pragma unroll
    for (int rr = 0; rr < 4; ++rr) {
      A[(size_t)(lb0 + rr) * HH + tid] = a[rr];
      E[(size_t)(lb0 + rr) * HH + tid] = ev[rr];
    }
  }
}

// ---- fused gmax + gf ----
__global__ void k_gmf(const float* hg0, const float* hg1, const void* nhW, const void* rhW,
                      const void* mk, float* Gf0, float* Gf1) {
  bool f32 = is32(mk);
  int task = blockIdx.x >> 2, b = blockIdx.x & 3;
  const float* hg = task ? hg1 : hg0;
  const void* hWo = task ? rhW : nhW;
  float* Gf = task ? Gf1 : Gf0;
  __shared__ __align__(16) float gl[304];
  int tid = threadIdx.x;
  if (tid < HH) {
    float m = -1e30f;
    for (int l = 0; l < LLEN; ++l) m = fmaxf(m, hg[((size_t)l * BB + b) * HH + tid]);
    gl[tid] = m;
  }
  __syncthreads();
  if (tid < HH) {
    float acc = 0.f;
    if (f32) {
      const float4* row = (const float4*)((const float*)hWo + (size_t)tid * H3 + 600);
      #pragma unroll 5
      for (int k = 0; k < 75; ++k) {
        float4 u = row[k];
        const float4 gv = *(const float4*)(gl + 4 * k);
        acc += u.x * gv.x + u.y * gv.y + u.z * gv.z + u.w * gv.w;
      }
    } else {
      for (int k = 0; k < HH; ++k) acc += gl[k] * ldin(hWo, tid * H3 + 600 + k, f32);
    }
    Gf[b * HH + tid] = acc;
  }
}

// ---- pair epilogue ----
__global__ void __launch_bounds__(256) k_pair6(const float* A0, const float* E0, const float* Gf0,
                                               const void* lg0, const void* lb0_, const void* tW0, const void* tb0,
                                               const float* A1, const float* E1, const float* Gf1,
                                               const void* lg1, const void* lb1_, const void* tW1, const void* tb1,
                                               const void* mk, void* outv) {
  __shared__ float lg_l[304], lb_l[304], tb_l[16];
  __shared__ float tw_l[3616];
  bool f32 = is32(mk);
  int tau = blockIdx.x >> 12;
  int bid = blockIdx.x & 4095;
  const float* A  = tau ? A1 : A0;
  const float* E  = tau ? E1 : E0;
  const float* Gf = tau ? Gf1 : Gf0;
  const void* lgo = tau ? lg1 : lg0;
  const void* lbo = tau ? lb1_ : lb0_;
  const void* tWo = tau ? tW1 : tW0;
  const void* tbo = tau ? tb1 : tb0;
  int T = tau ? NRR : NTT;
  int diag = tau ? 0 : 1;
  int Toff = tau ? 458752 : 0;
  int tid = threadIdx.x;
  for (int i2 = tid; i2 < HH; i2 += 256) { lg_l[i2] = ldin(lgo, i2, f32); lb_l[i2] = ldin(lbo, i2, f32); }
  for (int i2 = tid; i2 < T * HH; i2 += 256) tw_l[i2] = ldin(tWo, i2, f32);
  if (tid < T) tb_l[tid] = ldin(tbo, tid, f32);
  __syncthreads();
  int i = bid >> 5;
  int j0 = (bid & 31) << 2;
  int b = tid >> 6, ln = tid & 63;
  const float* ar = A  + (size_t)(i * BB + b) * HH;
  const float* gr = Gf + (size_t)b * HH;
  bool ok4 = ln < 44;
  float a0 = ar[ln]       + gr[ln];
  float a1 = ar[64 + ln]  + gr[64 + ln];
  float a2 = ar[128 + ln] + gr[128 + ln];
  float a3 = ar[192 + ln] + gr[192 + ln];
  float a4 = ok4 ? (ar[256 + ln] + gr[256 + ln]) : 0.f;
  float mi = ldin(mk, i * BB + b, f32);
  for (int dj = 0; dj < 4; ++dj) {
    int jx = j0 + dj;
    const float* er = E + (size_t)(jx * BB + b) * HH;
    float u0 = a0 + er[ln];
    float u1 = a1 + er[64 + ln];
    float u2 = a2 + er[128 + ln];
    float u3 = a3 + er[192 + ln];
    float u4 = ok4 ? (a4 + er[256 + ln]) : 0.f;
    float s1 = ((u0 + u1) + (u2 + u3)) + u4;
    float s2 = ((u0 * u0 + u1 * u1) + (u2 * u2 + u3 * u3)) + u4 * u4;
    #pragma unroll
    for (int d = 1; d < 64; d <<= 1) { s1 += __shfl_xor(s1, d); s2 += __shfl_xor(s2, d); }
    float mean = s1 * (1.f / 300.f);
    float var = s2 * (1.f / 300.f) - mean * mean;
    float rstd = rsqrtf(var + 1e-5f);
    {
      float y;
      y = (u0 - mean) * rstd * lg_l[ln]       + lb_l[ln];       u0 = (y > 0.f) ? y : __expf(y) - 1.f;
      y = (u1 - mean) * rstd * lg_l[64 + ln]  + lb_l[64 + ln];  u1 = (y > 0.f) ? y : __expf(y) - 1.f;
      y = (u2 - mean) * rstd * lg_l[128 + ln] + lb_l[128 + ln]; u2 = (y > 0.f) ? y : __expf(y) - 1.f;
      y = (u3 - mean) * rstd * lg_l[192 + ln] + lb_l[192 + ln]; u3 = (y > 0.f) ? y : __expf(y) - 1.f;
      if (ok4) {
        y = (u4 - mean) * rstd * lg_l[256 + ln] + lb_l[256 + ln];
        u4 = (y > 0.f) ? y : __expf(y) - 1.f;
      }
    }
    float m = mi * ldin(mk, jx * BB + b, f32);
    if (diag && jx < i) m = 0.f;
    size_t obase = (size_t)Toff + ((size_t)(i * LLEN + jx) * BB + b) * T;
    float mine = 0.f;
    for (int t = 0; t < T; ++t) {
      const float* twr = tw_l + t * HH;
      float s = u0 * twr[ln] + u1 * twr[64 + ln] + u2 * twr[128 + ln] + u3 * twr[192 + ln];
      if (ok4) s += u4 * twr[256 + ln];
      s = wsum(s);
      s += tb_l[t];
      float o = m / (1.f + __expf(-s));
      mine = (ln == t) ? o : mine;
    }
    if (ln < T) {
      if (f32) ((float*)outv)[obase + ln] = mine;
      else ((u16*)outv)[obase + ln] = f2bf(mine);
    }
  }
}

// ---- sentinel ----
__global__ void k_sent(const void* mk, const void* xo, void* outv, int hostcode) {
  __shared__ int bad;
  if (threadIdx.x == 0) bad = 0;
  __syncthreads();
  bool f32 = is32(mk);
  for (int i = threadIdx.x; i < 4096; i += 256) {
    float v = ldin(xo, i, f32);
    if (!(v == v) || fabsf(v) > 1e6f) bad = 1;
  }
  __syncthreads();
  if (threadIdx.x == 0) {
    float code = (float)hostcode;
    if (bad) code = fmaxf(code, 88.f);
    if (code > 0.f) {
      if (f32) ((float*)outv)[0] = code;
      else ((u16*)outv)[0] = f2bf(code);
    }
  }
}

extern "C" void kernel_launch(void* const* d_in, const int* in_sizes, int n_in,
                              void* d_out, int out_size, void* d_ws, size_t ws_size,
                              hipStream_t stream) {
  const void* x    = d_in[0];
  const void* mask = d_in[1];
  const void* Wih  = d_in[2];
  const void* bih  = d_in[3];
  const void* Whh  = d_in[4];
  const void* bhh  = d_in[5];
  const void* Wtr  = d_in[6];
  const void* btr  = d_in[7];
  const void* nW   = d_in[8];
  const void* nb   = d_in[9];
  const void* nhW  = d_in[10];
  const void* nhb  = d_in[11];
  const void* ng   = d_in[12];
  const void* nbe  = d_in[13];
  const void* ntW  = d_in[14];
  const void* ntb  = d_in[15];
  const void* rW   = d_in[16];
  const void* rb   = d_in[17];
  const void* rhW  = d_in[18];
  const void* rhb  = d_in[19];
  const void* rg   = d_in[20];
  const void* rbe  = d_in[21];
  const void* rtW  = d_in[22];
  const void* rtb  = d_in[23];
  float* ws = (float*)d_ws;

  static const int exp_sz[24] = {393216, 512, 1152000, 1500, 450000, 1500, 270000, 300,
                                 180000, 300, 270000, 300, 300, 300, 2100, 7,
                                 180000, 300, 270000, 300, 300, 300, 3600, 12};
  int hostcode = 0;
  if (n_in != 24) hostcode = 890;
  else {
    for (int ii = 0; ii < 24; ++ii)
      if (in_sizes[ii] != exp_sz[ii]) { hostcode = 900 + ii; break; }
  }
  if (hostcode == 0 && out_size != 1245184) hostcode = 880;
  if (hostcode == 0 && ws_size < WS_NEED_BYTES) hostcode = 1099;

  dim3 gc(4500, 6);
  k_canon<<<gc, 256, 0, stream>>>(x, mask, Wih, bih, Whh, bhh, Wtr, btr, ws);
  k_pre2<<<128, 256, 0, stream>>>(x, Wih, mask, ws + C_X, ws + C_WIH, ws + F_BIH, ws + F_PRE);
  k_scanA<<<256, 512, 0, stream>>>(ws + F_PRE, (const float2*)(ws + C_WHH2), (const float2*)(ws + C_WTR2),
                                   ws + F_BTR, ws + F_HNER, ws + F_HRE, ws + F_HSH, ws + F_AUX, ws);
  k_scanB<<<256, 512, 0, stream>>>(ws + F_PRE, (const float2*)(ws + C_WHH2), (const float2*)(ws + C_WTR2),
                                   ws + F_BTR, ws + F_HNER, ws + F_HRE, ws + F_HSH, ws + F_AUX);
  k_glob3<<<256, 320, 0, stream>>>(ws + F_HSH, ws + F_HNER, ws + F_HRE,
                                   nW, nb, rW, rb, mask, ws + F_HG0, ws + F_HG1);
  k_feat2<<<256, 320, 0, stream>>>(ws + F_HNER, ws + F_HRE, nhW, nhb, rhW, rhb, mask,
                                   ws + F_A0, ws + F_E0, ws + F_A1, ws + F_E1);
  k_gmf<<<8, 320, 0, stream>>>(ws + F_HG0, ws + F_HG1, nhW, rhW, mask, ws + F_GF0, ws + F_GF1);
  k_pair6<<<8192, 256, 0, stream>>>(ws + F_A0, ws + F_E0, ws + F_GF0, ng, nbe, ntW, ntb,
                                    ws + F_A1, ws + F_E1, ws + F_GF1, rg, rbe, rtW, rtb,
                                    mask, d_out);
  k_sent<<<1, 256, 0, stream>>>(mask, x, d_out, hostcode);
}

// Round 9
// 1437.865 us; speedup vs baseline: 1.0129x; 1.0129x over previous
//
#include <hip/hip_runtime.h>

#define LLEN 128
#define BB 4
#define DD 768
#define HH 300
#define G5 1500
#define H3 900
#define NTT 7
#define NRR 12
#define NCHB 10
#define RPB 150
#define OPB 30

// ---- fp32 workspace layout (ws as float*) ----
#define C_WIH  0
#define C_X    1152000
#define C_WHH2 1545216
#define C_WTR2 1995216
#define F_BIH  2265216
#define F_BTR  2266720
#define F_PRE  2267040
// PRE region reused after the scan:
#define F_HG0  (F_PRE)
#define F_HG1  (F_PRE+153600)
#define F_A0   (F_PRE+307200)
#define F_E0   (F_PRE+460800)
#define F_GF0  (F_PRE+616832)
#define F_GF1  (F_PRE+618048)
// beyond PRE:
#define F_HNER (F_PRE+768000)
#define F_HRE  (F_HNER+153600)
#define F_HSH  (F_HRE+153600)
#define F_A1   0
#define F_E1   153600
#define F_AUX  (F_HSH+153600)
// scanA exchange buffers in the scan-dead C_WIH region [0,1152000):
//   partials: part(buf,b) = buf*96000 + b*24000: 1500 rows x 16 floats
//   (cols 0..9 partial sums, 10..11 zero pads, 12..15 never read) [R6-proven]
//   c_pub: 192000 + (buf*4+b)*304
#define P_CPUB 192000
// aux per-batch (AUXB floats): scanB selftest words (tst @ gb+2240, seflag @ gb+2272)
#define AUXB   2432
#define AUX_FL 9728
// int area (2048 ints, zeroed per launch with AGENT stores — these lines are
// touched EXCLUSIVELY by agent-scope ops by every kernel, so LLC is authoritative):
//   chunk0 (scanA): claim [0,32); per batch b at [32+64b): slots[0..15], abort@+24
//   chunk1 (scanB): claim [640,672); per batch b at [672+64b): slotsA[16] slotsB[16] atf[5]
//   done[4] @ [1536,1540)  (scanA completion counters; scanB skips batch iff ==NCHB)
#define WS_NEED_BYTES ((size_t)(F_AUX+11776)*4)

typedef unsigned short u16;
typedef unsigned int u32;
typedef float f4 __attribute__((ext_vector_type(4)));
typedef int i4 __attribute__((ext_vector_type(4)));

__device__ __forceinline__ float bf2f(u16 u) {
  union { u32 i; float f; } v; v.i = ((u32)u) << 16; return v.f;
}
__device__ __forceinline__ u16 f2bf(float f) {
  union { float f; u32 i; } v; v.f = f;
  u32 r = v.i + 0x7fffu + ((v.i >> 16) & 1u);
  return (u16)(r >> 16);
}
__device__ __forceinline__ float ldin(const void* p, int i, bool f32) {
  return f32 ? ((const float*)p)[i] : bf2f(((const u16*)p)[i]);
}
__device__ __forceinline__ bool is32(const void* mk) {
  return ((const u16*)mk)[0] == 0;
}
__device__ __forceinline__ float wsum(float x) {
  #pragma unroll
  for (int d = 1; d < 64; d <<= 1) x += __shfl_xor(x, d);
  return x;
}
// ---- agent-scope (LLC) accessors ----
__device__ __forceinline__ void astore(float* p, float v) {
  union { float f; int i; } u; u.f = v;
  __hip_atomic_store((int*)p, u.i, __ATOMIC_RELAXED, __HIP_MEMORY_SCOPE_AGENT);
}
// proven agent-scope inter-block barrier (scanB selftest/claim only)
__device__ __forceinline__ void gbar(int* flag, int tid, int target) {
  __syncthreads();
  if (tid == 0) {
    __builtin_amdgcn_s_waitcnt(0);
    __hip_atomic_fetch_add(flag, 1, __ATOMIC_RELAXED, __HIP_MEMORY_SCOPE_AGENT);
    int it = 0;
    while (__hip_atomic_load(flag, __ATOMIC_RELAXED, __HIP_MEMORY_SCOPE_AGENT) < target) {
      __builtin_amdgcn_s_sleep(1);
      if (++it > 50000) break;
    }
  }
  __syncthreads();
}
// ---- scoped exchange primitives (mode 1 = XCD/L2, mode 0 = agent/LLC) ----
__device__ __forceinline__ f4 ld4x(const f4* p, int mode) {
  f4 v;
  if (mode)
    asm volatile("global_load_dwordx4 %0, %1, off sc0\n\ts_waitcnt vmcnt(0)"
                 : "=v"(v) : "v"(p) : "memory");
  else
    asm volatile("global_load_dwordx4 %0, %1, off sc0 sc1\n\ts_waitcnt vmcnt(0)"
                 : "=v"(v) : "v"(p) : "memory");
  return v;
}
__device__ __forceinline__ float ld1x(const float* p, int mode) {
  float v;
  if (mode)
    asm volatile("global_load_dword %0, %1, off sc0\n\ts_waitcnt vmcnt(0)"
                 : "=v"(v) : "v"(p) : "memory");
  else
    asm volatile("global_load_dword %0, %1, off sc0 sc1\n\ts_waitcnt vmcnt(0)"
                 : "=v"(v) : "v"(p) : "memory");
  return v;
}
__device__ __forceinline__ int ldix(const int* p, int mode) {
  int v;
  if (mode)
    asm volatile("global_load_dword %0, %1, off sc0\n\ts_waitcnt vmcnt(0)"
                 : "=v"(v) : "v"(p) : "memory");
  else
    asm volatile("global_load_dword %0, %1, off sc0 sc1\n\ts_waitcnt vmcnt(0)"
                 : "=v"(v) : "v"(p) : "memory");
  return v;
}
__device__ __forceinline__ void exst(float* p, float v, int mode) {
  if (mode) *p = v; else astore(p, v);
}
// 9 overlapped dwordx4 from one 64B-aligned base (3 rows x 3 quads), L2-local
__device__ __forceinline__ void ld9(const float* base,
                                    f4& a0, f4& a1, f4& a2, f4& a3, f4& a4,
                                    f4& a5, f4& a6, f4& a7, f4& a8) {
  asm volatile(
    "global_load_dwordx4 %0, %9, off sc0\n\t"
    "global_load_dwordx4 %1, %9, off offset:16 sc0\n\t"
    "global_load_dwordx4 %2, %9, off offset:32 sc0\n\t"
    "global_load_dwordx4 %3, %9, off offset:64 sc0\n\t"
    "global_load_dwordx4 %4, %9, off offset:80 sc0\n\t"
    "global_load_dwordx4 %5, %9, off offset:96 sc0\n\t"
    "global_load_dwordx4 %6, %9, off offset:128 sc0\n\t"
    "global_load_dwordx4 %7, %9, off offset:144 sc0\n\t"
    "global_load_dwordx4 %8, %9, off offset:160 sc0\n\t"
    "s_waitcnt vmcnt(0)"
    : "=&v"(a0), "=&v"(a1), "=&v"(a2), "=&v"(a3), "=&v"(a4),
      "=&v"(a5), "=&v"(a6), "=&v"(a7), "=&v"(a8)
    : "v"(base) : "memory");
}
// poll all 10 arrival slots (12 loaded; last 2 zero padding)
__device__ __forceinline__ int poll10(const int* slots, int tok, int mode) {
  i4 a, b, c;
  if (mode)
    asm volatile("global_load_dwordx4 %0, %3, off sc0\n\t"
                 "global_load_dwordx4 %1, %4, off sc0\n\t"
                 "global_load_dwordx4 %2, %5, off sc0\n\t"
                 "s_waitcnt vmcnt(0)"
                 : "=&v"(a), "=&v"(b), "=&v"(c)
                 : "v"(slots), "v"(slots + 4), "v"(slots + 8) : "memory");
  else
    asm volatile("global_load_dwordx4 %0, %3, off sc0 sc1\n\t"
                 "global_load_dwordx4 %1, %4, off sc0 sc1\n\t"
                 "global_load_dwordx4 %2, %5, off sc0 sc1\n\t"
                 "s_waitcnt vmcnt(0)"
                 : "=&v"(a), "=&v"(b), "=&v"(c)
                 : "v"(slots), "v"(slots + 4), "v"(slots + 8) : "memory");
  return (a.x >= tok) & (a.y >= tok) & (a.z >= tok) & (a.w >= tok) &
         (b.x >= tok) & (b.y >= tok) & (b.z >= tok) & (b.w >= tok) &
         (c.x >= tok) & (c.y >= tok);
}
// slot barrier (scanB, proven): drain + sync + tid0 token store; wave 0 polls
__device__ __forceinline__ void sbar(int* slots, int ch, int tok, int tid, int mode) {
  asm volatile("s_waitcnt vmcnt(0)" ::: "memory");
  __syncthreads();
  if (tid == 0) {
    if (mode) slots[ch] = tok;
    else __hip_atomic_store(slots + ch, tok, __ATOMIC_RELAXED, __HIP_MEMORY_SCOPE_AGENT);
  }
  if (tid < 64) {
    int it = 0;
    while (!poll10(slots, tok, mode)) {
      __builtin_amdgcn_s_sleep(1);
      if (++it > 5000) break;
    }
  }
  __syncthreads();
}
// scanA slot barrier: AGENT-scope tokens (LLC-exclusive lines, stale-proof) +
// L2-local payload (covered by drain-before-token). Timeout -> abort propagation.
__device__ __forceinline__ void sbarA(int* slots, int* abf, int ch, int tok, int tid,
                                      volatile int* s_fail) {
  asm volatile("s_waitcnt vmcnt(0)" ::: "memory");  // payload drained to our L2
  __syncthreads();
  if (tid == 0)
    __hip_atomic_store(slots + ch, tok, __ATOMIC_RELAXED, __HIP_MEMORY_SCOPE_AGENT);
  if (tid < 64) {
    int it = 0;
    while (!poll10(slots, tok, 0)) {   // mode 0 = agent/LLC reads
      __builtin_amdgcn_s_sleep(1);
      ++it;
      if ((it & 255) == 0 &&
          __hip_atomic_load(abf, __ATOMIC_RELAXED, __HIP_MEMORY_SCOPE_AGENT) != 0) {
        *s_fail = 1; break;
      }
      if (it > 8000) {
        __hip_atomic_store(abf, 1, __ATOMIC_RELAXED, __HIP_MEMORY_SCOPE_AGENT);
        *s_fail = 1; break;
      }
    }
  }
  __syncthreads();
}
// claim (xcd, rank) via HW_REG_XCC_ID + grid rendezvous (agent-only lines)
__device__ __forceinline__ int claim_bc(int* cl, int nb) {
  unsigned xcd;
  asm volatile("s_getreg_b32 %0, hwreg(HW_REG_XCC_ID)" : "=s"(xcd));
  xcd &= 7u;
  int rank = __hip_atomic_fetch_add(cl + xcd, 1, __ATOMIC_RELAXED, __HIP_MEMORY_SCOPE_AGENT);
  __hip_atomic_fetch_add(cl + 8, 1, __ATOMIC_RELAXED, __HIP_MEMORY_SCOPE_AGENT);
  int it = 0;
  while (__hip_atomic_load(cl + 8, __ATOMIC_RELAXED, __HIP_MEMORY_SCOPE_AGENT) < nb) {
    __builtin_amdgcn_s_sleep(2);
    if (++it > 100000) break;
  }
  int base = 0;
  for (unsigned x = 0; x < xcd; ++x)
    base += __hip_atomic_load(cl + x, __ATOMIC_RELAXED, __HIP_MEMORY_SCOPE_AGENT) / NCHB;
  int cnt = __hip_atomic_load(cl + xcd, __ATOMIC_RELAXED, __HIP_MEMORY_SCOPE_AGENT);
  int slot = base + rank / NCHB;
  return (rank < (cnt / NCHB) * NCHB && slot < BB) ? (slot * 16 + rank % NCHB) : -1;
}

// ---- canonicalize ----
__global__ void k_canon(const void* xo, const void* mk, const void* Wih, const void* bih,
                        const void* Whh, const void* bhh, const void* Wtr, const void* btr,
                        float* ws) {
  bool f32 = is32(mk);
  int piece = blockIdx.y;
  int i = blockIdx.x * 256 + threadIdx.x;
  switch (piece) {
    case 0: if (!f32 && i < 1152000) ws[C_WIH + i] = ldin(Wih, i, f32); break;
    case 1: if (!f32 && i < 393216)  ws[C_X + i]   = ldin(xo, i, f32);  break;
    case 2: if (i < 225000) {
      int k2 = i / G5, out = i - k2 * G5;
      float2 v;
      v.x = ldin(Whh, out * HH + 2 * k2, f32);
      v.y = ldin(Whh, out * HH + 2 * k2 + 1, f32);
      ((float2*)(ws + C_WHH2))[i] = v;
    } break;
    case 3: if (i < 135000) {
      int k2 = i / HH, out = i - k2 * HH;
      float2 v;
      v.x = ldin(Wtr, out * H3 + 2 * k2, f32);
      v.y = ldin(Wtr, out * H3 + 2 * k2 + 1, f32);
      ((float2*)(ws + C_WTR2))[i] = v;
    } break;
    case 4: {
      if (i < 1504) ws[F_BIH + i] = (i < G5) ? ldin(bih, i, f32) + ldin(bhh, i, f32) : 0.f;
      else if (i < 1824) { int j = i - 1504; ws[F_BTR + j] = (j < HH) ? ldin(btr, j, f32) : 0.f; }
    } break;
    case 5: {
      if (i < AUX_FL) ws[F_AUX + i] = 0.f;                      // float aux (selftest words)
      else if (i < 11776) {                                      // int control area: AGENT zero
        int* ip = (int*)(ws + F_AUX + AUX_FL);
        __hip_atomic_store(ip + (i - AUX_FL), 0, __ATOMIC_RELAXED, __HIP_MEMORY_SCOPE_AGENT);
      }
    } break;
  }
}

// ---- pre = x @ W_ih^T + (b_ih + b_hh) ----
__global__ void k_pre2(const void* xo, const void* Wo, const void* mk,
                       const float* cX, const float* cW, const float* biasf, float* pre) {
  bool f32 = is32(mk);
  const float* X = f32 ? (const float*)xo : cX;
  const float* W = f32 ? (const float*)Wo : cW;
  __shared__ __align__(16) float xl[8 * DD];
  int tid = threadIdx.x;
  int lb0 = (blockIdx.x >> 1) * 8;
  int half = blockIdx.x & 1;
  for (int e = tid; e < 8 * DD; e += 256) xl[e] = X[(size_t)lb0 * DD + e];
  __syncthreads();
  for (int j = half * 750 + tid; j < half * 750 + 750; j += 256) {
    const float4* w = (const float4*)(W + (size_t)j * DD);
    float acc[8] = {0.f, 0.f, 0.f, 0.f, 0.f, 0.f, 0.f, 0.f};
    #pragma unroll 2
    for (int k = 0; k < DD / 4; ++k) {
      float4 u = w[k];
      #pragma unroll
      for (int r = 0; r < 8; ++r) {
        const float4 p = *(const float4*)(xl + r * DD + k * 4);
        acc[r] += u.x * p.x + u.y * p.y + u.z * p.z + u.w * p.w;
      }
    }
    float bias = biasf[j];
    #pragma unroll
    for (int r = 0; r < 8; ++r) pre[(size_t)(lb0 + r) * G5 + j] = acc[r] + bias;
  }
}

// ---- scanA: 1-barrier/step; sound-by-construction (agent tokens, covered L2 payload) ----
__global__ void __launch_bounds__(512, 2) k_scanA(const float* pre, const float2* W2h, const float2* W2t,
                                                  const float* btrf, float* hner, float* hre, float* hsh,
                                                  float* aux, float* xw) {
  __shared__ __align__(16) float ga_l[1504];
  __shared__ __align__(16) float vv_l[1204];
  __shared__ __align__(16) float tnh_l[304];
  __shared__ __align__(16) float cat_l[904];
  __shared__ __align__(16) float ci_l[304];
  __shared__ __align__(16) float ps[512];
  __shared__ __align__(16) float h_loc[32];
  __shared__ int s_bc;
  __shared__ int s_fail;
  int tid = threadIdx.x;
  int* ibase = (int*)(aux + AUX_FL);
  if (tid == 0) { s_bc = claim_bc(ibase, (int)gridDim.x); s_fail = 0; }
  __syncthreads();
  int bc = s_bc;
  if (bc < 0) return;
  int b = bc >> 4, ch = bc & 15;
  int* slots = ibase + 32 + b * 64;
  int* abf   = slots + 24;
  int* done  = ibase + 1536;

  // zero pad columns (10,11) of both partial buffers (plain stores to our L2;
  // covered for readers by the drain in the first sbarA)
  if (ch < 2) {
    float* pb0 = xw + (size_t)ch * 96000 + b * 24000;
    for (int i = tid; i < 3000; i += 512) {
      int row = i >> 1, col = 10 + (i & 1);
      pb0[row * 16 + col] = 0.f;
    }
  }

  int o0 = 3 * tid;
  float2 wh2[45];
  if (tid < 500) {
    #pragma unroll
    for (int j = 0; j < 3; ++j)
      #pragma unroll
      for (int kk = 0; kk < 15; ++kk)
        wh2[j * 15 + kk] = W2h[(size_t)(ch * 15 + kk) * G5 + (o0 + j)];
  }
  int o2 = tid % OPB, jj = tid / OPB;
  float2 wt[29];
  int k2b = jj * 29;
  int k2e = (k2b + 29 < 450) ? (k2b + 29) : 450;
  int nk2 = k2e - k2b;
  if (tid < 480) {
    const float2* wp = W2t + (size_t)k2b * HH + (ch * OPB + o2);
    #pragma unroll
    for (int q = 0; q < 29; ++q) if (q < nk2) wt[q] = wp[(size_t)q * HH];
  }
  float pv0 = 0.f, pv1 = 0.f, pv2 = 0.f;
  if (tid < 500) {
    const float* pr = pre + (size_t)b * G5 + o0;
    pv0 = pr[0]; pv1 = pr[1]; pv2 = pr[2];
  }
  __syncthreads();

  for (int t = 0; t < LLEN; ++t) {
    int buf = t & 1;
    float* pb = xw + (size_t)buf * 96000 + b * 24000;
    if (t > 0) {
      if (tid < 500) {
        float2 h2[15];
        #pragma unroll
        for (int kk = 0; kk < 15; ++kk) h2[kk] = *(const float2*)(h_loc + 2 * kk);
        #pragma unroll
        for (int j = 0; j < 3; ++j) {
          float acc = 0.f;
          #pragma unroll
          for (int kk = 0; kk < 15; ++kk)
            acc += wh2[j * 15 + kk].x * h2[kk].x + wh2[j * 15 + kk].y * h2[kk].y;
          pb[(size_t)(o0 + j) * 16 + ch] = acc;
        }
      }
      sbarA(slots, abf, ch, t, tid, &s_fail);   // the ONLY inter-block barrier
      if (s_fail) return;                        // desync: scanB redoes this batch
      if (tid < 500) {
        f4 a0, a1, a2, a3, a4, a5, a6, a7, a8;
        ld9(pb + (size_t)o0 * 16, a0, a1, a2, a3, a4, a5, a6, a7, a8);
        ga_l[o0]     = pv0 + (((a0.x + a0.y) + (a0.z + a0.w)) +
                              ((a1.x + a1.y) + (a1.z + a1.w)) +
                              ((a2.x + a2.y) + (a2.z + a2.w)));
        ga_l[o0 + 1] = pv1 + (((a3.x + a3.y) + (a3.z + a3.w)) +
                              ((a4.x + a4.y) + (a4.z + a4.w)) +
                              ((a5.x + a5.y) + (a5.z + a5.w)));
        ga_l[o0 + 2] = pv2 + (((a6.x + a6.y) + (a6.z + a6.w)) +
                              ((a7.x + a7.y) + (a7.z + a7.w)) +
                              ((a8.x + a8.y) + (a8.z + a8.w)));
      }
      if (tid < 75) {
        const float* cp = xw + P_CPUB + (size_t)(((t - 1) & 1) * 4 + b) * 304;
        f4 v = ld4x((const f4*)cp + tid, 1);
        *(f4*)(ci_l + 4 * tid) = v;
      }
    } else {
      if (tid < 500) { ga_l[o0] = pv0; ga_l[o0 + 1] = pv1; ga_l[o0 + 2] = pv2; }
    }
    __syncthreads();
    if (tid < HH) tnh_l[tid] = tanhf(ga_l[tid]);
    {
      int w = tid >> 6, ln = tid & 63;
      if (w >= 4) {
        int c = w - 3;
        const float* g = ga_l + c * 300;
        int e0 = ln * 5;
        float ex0 = 0.f, ex1 = 0.f, ex2 = 0.f, ex3 = 0.f, ex4 = 0.f;
        if (ln < 60) {
          ex0 = __expf(g[e0]); ex1 = __expf(g[e0 + 1]); ex2 = __expf(g[e0 + 2]);
          ex3 = __expf(g[e0 + 3]); ex4 = __expf(g[e0 + 4]);
        }
        float p = ((ex0 + ex1) + (ex2 + ex3)) + ex4;
        float inc = p;
        #pragma unroll
        for (int d = 1; d < 64; d <<= 1) { float o = __shfl_up(inc, d); if (ln >= d) inc += o; }
        float S = __shfl(inc, 59);
        float invS = 1.f / S;
        float run = inc - p;
        if (ln < 60) {
          float* vv = vv_l + (c - 1) * 300 + e0;
          run += ex0; vv[0] = run * invS;
          run += ex1; vv[1] = run * invS;
          run += ex2; vv[2] = run * invS;
          run += ex3; vv[3] = run * invS;
          run += ex4; vv[4] = run * invS;
        }
      }
    }
    if (t + 1 < LLEN && tid < 500) {
      const float* pr = pre + ((size_t)(t + 1) * BB + b) * G5 + o0;
      pv0 = pr[0]; pv1 = pr[1]; pv2 = pr[2];
    }
    __syncthreads();
    if (tid < HH) {
      float c = tnh_l[tid];
      float v0 = vv_l[tid], v1 = vv_l[300 + tid], v2 = vv_l[600 + tid], v3 = vv_l[900 + tid];
      float eg_cin = 1.f - v0, rg_cin = v1, eg_c = 1.f - v2, rg_c = v3;
      float ci = (t > 0) ? ci_l[tid] : 0.f;
      float ov_c = rg_c * eg_c;
      float up_c = rg_c - ov_c, dn_c = eg_c - ov_c;
      float ov_i = rg_cin * eg_cin;
      float up_i = rg_cin - ov_i, dn_i = eg_cin - ov_i;
      float share = ov_i * ci + ov_c * c;
      float c_re  = up_i * ci + up_c * c + share;
      float c_ner = dn_i * ci + dn_c * c + share;
      cat_l[tid] = c_re; cat_l[HH + tid] = c_ner; cat_l[2 * HH + tid] = share;
      int sb = ch * OPB;
      if (tid >= sb && tid < sb + OPB) {
        size_t ob = ((size_t)t * BB + b) * HH + tid;
        hner[ob] = tanhf(c_ner); hre[ob] = tanhf(c_re); hsh[ob] = tanhf(share);
      }
    }
    __syncthreads();
    if (tid < 480) {
      float acc = 0.f;
      #pragma unroll
      for (int q = 0; q < 29; ++q)
        if (q < nk2) acc += wt[q].x * cat_l[2 * (k2b + q)] + wt[q].y * cat_l[2 * (k2b + q) + 1];
      ps[tid] = acc;
    }
    __syncthreads();
    if (tid < OPB) {
      float co = btrf[ch * OPB + tid];
      #pragma unroll
      for (int q = 0; q < 16; ++q) co += ps[q * OPB + tid];
      h_loc[tid] = tanhf(co);
      float* cp = xw + P_CPUB + (size_t)(buf * 4 + b) * 304;
      cp[ch * OPB + tid] = co;
    }
    __syncthreads();
  }
  // completed with zero timeouts -> publish; scanB (stream-serialized) skips batch
  if (tid == 0 && s_fail == 0)
    __hip_atomic_fetch_add(done + b, 1, __ATOMIC_RELAXED, __HIP_MEMORY_SCOPE_AGENT);
}

// ---- scanB: R4-proven 2-barrier kernel; per-batch skip iff scanA fully done ----
__global__ void __launch_bounds__(512, 2) k_scanB(const float* pre, const float2* W2h, const float2* W2t,
                                                  const float* btrf, float* hner, float* hre, float* hsh,
                                                  float* aux) {
  __shared__ __align__(16) float h_l[304];
  __shared__ __align__(16) float ci_l[304];
  __shared__ __align__(16) float ga_l[1504];
  __shared__ __align__(16) float cat_l[904];
  __shared__ __align__(16) float ps[512];
  __shared__ __align__(16) float sums_l[8];
  __shared__ float exv[160];
  __shared__ int s_bc, s_mode, s_skip;
  int tid = threadIdx.x;
  int* ibase = (int*)(aux + AUX_FL);
  int* cl2 = ibase + 640;
  if (tid == 0) s_bc = claim_bc(cl2, (int)gridDim.x);
  __syncthreads();
  int bc = s_bc;
  if (bc < 0) return;
  int b = bc >> 4, ch = bc & 15;
  int* done = ibase + 1536;
  if (tid == 0)
    s_skip = (__hip_atomic_load(done + b, __ATOMIC_RELAXED, __HIP_MEMORY_SCOPE_AGENT) == NCHB);
  __syncthreads();
  if (s_skip) return;  // scanA fully produced this batch
  int s = ch >> 1;
  int r0 = ch * RPB;
  float* gb   = aux + b * AUXB;
  float* cb   = gb + 1504;
  float* hb   = gb + 1808;
  float* sums = gb + 2112;
  int* slotsA = ibase + 672 + b * 64;
  int* slotsB = slotsA + 16;
  int* atf    = slotsA + 32;

  // ---- selftest (R4-proven form) ----
  {
    float* tst = gb + 2240;
    int* seflag = (int*)(gb + 2272);
    if (ch == 0 && tid == 0) tst[0] = 1.0f;
    gbar(atf + 0, tid, NCHB);
    if (tid == 0) { float w1 = ld1x(tst, 1); (void)w1; }
    gbar(atf + 1, tid, NCHB);
    if (ch == 0 && tid == 0) { tst[0] = 2.0f; __builtin_amdgcn_s_waitcnt(0); }
    if (ch == 1 && tid == 0)
      __hip_atomic_fetch_add(seflag, 1, __ATOMIC_RELAXED, __HIP_MEMORY_SCOPE_WORKGROUP);
    gbar(atf + 2, tid, NCHB);
    if (tid == 0) {
      float w2 = ld1x(tst, 1);
      int fv = ldix(seflag, 1);
      if (w2 != 2.0f || fv != 1)
        __hip_atomic_fetch_or(atf + 4, 1, __ATOMIC_RELAXED, __HIP_MEMORY_SCOPE_AGENT);
    }
    gbar(atf + 3, tid, NCHB);
    if (tid == 0)
      s_mode = (__hip_atomic_load(atf + 4, __ATOMIC_RELAXED, __HIP_MEMORY_SCOPE_AGENT) == 0) ? 1 : 0;
    __syncthreads();
  }
  int mode = s_mode;

  int j = tid / RPB, r = tid - j * RPB;
  int o2 = tid % OPB, jj = tid / OPB;
  int kb = j * 100;

  float2 wh[50];
  if (tid < 450) {
    const float2* wp = W2h + (size_t)(j * 50) * G5 + (r0 + r);
    #pragma unroll
    for (int kk = 0; kk < 50; ++kk) wh[kk] = wp[(size_t)kk * G5];
  }
  float2 wt[29];
  int k2b = jj * 29;
  int k2e = (k2b + 29 < 450) ? (k2b + 29) : 450;
  int nk2 = k2e - k2b;
  if (tid < 480) {
    const float2* wp = W2t + (size_t)k2b * HH + (ch * OPB + o2);
    #pragma unroll
    for (int q = 0; q < 29; ++q) if (q < nk2) wt[q] = wp[(size_t)q * HH];
  }
  float pv = 0.f;
  if (tid < RPB) pv = pre[(size_t)b * G5 + r0 + tid];
  __syncthreads();

  for (int t = 0; t < LLEN; ++t) {
    if (t > 0) {
      if (tid < 75)       { f4 v = ld4x((const f4*)hb + tid, mode); *(f4*)(h_l + 4 * tid) = v; }
      else if (tid < 150) { int q = tid - 75; f4 v = ld4x((const f4*)cb + q, mode); *(f4*)(ci_l + 4 * q) = v; }
      __syncthreads();
    }
    if (tid < 450) {
      float acc = (j == 0) ? pv : 0.f;
      if (t > 0) {
        #pragma unroll
        for (int kk = 0; kk < 50; ++kk)
          acc += wh[kk].x * h_l[kb + 2 * kk] + wh[kk].y * h_l[kb + 2 * kk + 1];
      }
      ps[tid] = acc;
    }
    __syncthreads();
    if (tid < RPB) {
      float g = ps[tid] + ps[RPB + tid] + ps[2 * RPB + tid];
      if (s == 0) exst(gb + r0 + tid, tanhf(g), mode);
      else exv[tid] = __expf(g);
    }
    if (s > 0) {
      __syncthreads();
      if (tid < 30) {
        int base2 = tid * 5;
        float e0 = exv[base2], e1 = exv[base2 + 1], e2 = exv[base2 + 2],
              e3 = exv[base2 + 3], e4 = exv[base2 + 4];
        float p = ((e0 + e1) + (e2 + e3)) + e4;
        float inc = p;
        #pragma unroll
        for (int d = 1; d < 32; d <<= 1) { float o = __shfl_up(inc, d); if (tid >= d) inc += o; }
        float tot = __shfl(inc, 29);
        float run = inc - p;
        run += e0; exst(gb + r0 + base2,     run, mode);
        run += e1; exst(gb + r0 + base2 + 1, run, mode);
        run += e2; exst(gb + r0 + base2 + 2, run, mode);
        run += e3; exst(gb + r0 + base2 + 3, run, mode);
        run += e4; exst(gb + r0 + base2 + 4, run, mode);
        if (tid == 0) exst(sums + (ch - 2), tot, mode);
      }
    }
    sbar(slotsA, ch, t + 1, tid, mode);
    if (tid < 375)      { f4 v = ld4x((const f4*)gb + tid, mode); *(f4*)(ga_l + 4 * tid) = v; }
    else if (tid < 377) { int q = tid - 375; f4 v = ld4x((const f4*)sums + q, mode); *(f4*)(sums_l + 4 * q) = v; }
    float pvn = 0.f;
    if (t + 1 < LLEN && tid < RPB) pvn = pre[((size_t)(t + 1) * BB + b) * G5 + r0 + tid];
    __syncthreads();
    if (tid < HH) {
      float c = ga_l[tid];
      float v[4];
      #pragma unroll
      for (int s1 = 0; s1 < 4; ++s1) {
        float raw = ga_l[(s1 + 1) * HH + tid];
        float off = (tid >= RPB) ? sums_l[2 * s1] : 0.f;
        float S = sums_l[2 * s1] + sums_l[2 * s1 + 1];
        v[s1] = (raw + off) / S;
      }
      float eg_cin = 1.f - v[0], rg_cin = v[1], eg_c = 1.f - v[2], rg_c = v[3];
      float ci = (t > 0) ? ci_l[tid] : 0.f;
      float ov_c = rg_c * eg_c;
      float up_c = rg_c - ov_c, dn_c = eg_c - ov_c;
      float ov_i = rg_cin * eg_cin;
      float up_i = rg_cin - ov_i, dn_i = eg_cin - ov_i;
      float share = ov_i * ci + ov_c * c;
      float c_re  = up_i * ci + up_c * c + share;
      float c_ner = dn_i * ci + dn_c * c + share;
      cat_l[tid] = c_re; cat_l[HH + tid] = c_ner; cat_l[2 * HH + tid] = share;
      int sb = ch * OPB;
      if (tid >= sb && tid < sb + OPB) {
        size_t ob = ((size_t)t * BB + b) * HH + tid;
        hner[ob] = tanhf(c_ner); hre[ob] = tanhf(c_re); hsh[ob] = tanhf(share);
      }
    }
    __syncthreads();
    if (tid < 480) {
      float acc = 0.f;
      #pragma unroll
      for (int q = 0; q < 29; ++q)
        if (q < nk2) acc += wt[q].x * cat_l[2 * (k2b + q)] + wt[q].y * cat_l[2 * (k2b + q) + 1];
      ps[tid] = acc;
    }
    __syncthreads();
    if (tid < OPB) {
      float co = btrf[ch * OPB + tid];
      #pragma unroll
      for (int q = 0; q < 16; ++q) co += ps[q * OPB + tid];
      exst(cb + ch * OPB + tid, co, mode);
      exst(hb + ch * OPB + tid, tanhf(co), mode);
    }
    if (t + 1 < LLEN) sbar(slotsB, ch, t + 1, tid, mode);
    pv = pvn;
  }
}

// ---- h_glob ----
__global__ void k_glob3(const float* hsh, const float* hner, const float* hre,
                        const void* nW, const void* nb, const void* rW, const void* rb,
                        const void* mk, float* hg0, float* hg1) {
  bool f32 = is32(mk);
  int task = blockIdx.x >> 7;
  int lb0 = (blockIdx.x & 127) * 4;
  const float* tsk = task ? hre : hner;
  const void* gWo = task ? rW : nW;
  const void* gbo = task ? rb : nb;
  float* hg = task ? hg1 : hg0;
  __shared__ __align__(16) float catl[2400];
  int tid = threadIdx.x;
  for (int e = tid; e < 2400; e += 320) {
    int rr = e / 600, c = e - rr * 600;
    catl[e] = (c < HH) ? hsh[(size_t)(lb0 + rr) * HH + c] : tsk[(size_t)(lb0 + rr) * HH + (c - HH)];
  }
  __syncthreads();
  if (tid < HH) {
    float bias = ldin(gbo, tid, f32);
    float acc[4] = {bias, bias, bias, bias};
    if (f32) {
      const float4* row = (const float4*)((const float*)gWo + (size_t)tid * 600);
      #pragma unroll 2
      for (int k = 0; k < 150; ++k) {
        float4 u = row[k];
        #pragma unroll
        for (int rr = 0; rr < 4; ++rr) {
          const float4 cv = *(const float4*)(catl + rr * 600 + 4 * k);
          acc[rr] += u.x * cv.x + u.y * cv.y + u.z * cv.z + u.w * cv.w;
        }
      }
    } else {
      for (int k = 0; k < 600; ++k) {
        float w = ldin(gWo, tid * 600 + k, f32);
        #pragma unroll
        for (int rr = 0; rr < 4; ++rr) acc[rr] += w * catl[rr * 600 + k];
      }
    }
    #pragma unroll
    for (int rr = 0; rr < 4; ++rr) hg[(size_t)(lb0 + rr) * HH + tid] = tanhf(acc[rr]);
  }
}

// ---- A/E features ----
__global__ void k_feat2(const float* hner, const float* hre,
                        const void* nhW, const void* nhb, const void* rhW, const void* rhb,
                        const void* mk, float* A0, float* E0, float* A1, float* E1) {
  bool f32 = is32(mk);
  int task = blockIdx.x >> 7;
  int lb0 = (blockIdx.x & 127) * 4;
  const float* tsk = task ? hre : hner;
  const void* hWo = task ? rhW : nhW;
  const void* hbo = task ? rhb : nhb;
  float* A = task ? A1 : A0;
  float* E = task ? E1 : E0;
  __shared__ __align__(16) float tl[1200];
  int tid = threadIdx.x;
  for (int e = tid; e < 1200; e += 320) {
    int rr = e / 300, c = e - rr * 300;
    tl[e] = tsk[(size_t)(lb0 + rr) * HH + c];
  }
  __syncthreads();
  if (tid < HH) {
    float bias = ldin(hbo, tid, f32);
    float a[4] = {bias, bias, bias, bias};
    float ev[4] = {0.f, 0.f, 0.f, 0.f};
    if (f32) {
      const float4* r1 = (const float4*)((const float*)hWo + (size_t)tid * H3);
      const float4* r2 = (const float4*)((const float*)hWo + (size_t)tid * H3 + HH);
      #pragma unroll 2
      for (int k = 0; k < 75; ++k) {
        float4 u = r1[k], w2 = r2[k];
        #pragma unroll
        for (int rr = 0; rr < 4; ++rr) {
          const float4 tv = *(const float4*)(tl + rr * 300 + 4 * k);
          a[rr]  += u.x * tv.x + u.y * tv.y + u.z * tv.z + u.w * tv.w;
          ev[rr] += w2.x * tv.x + w2.y * tv.y + w2.z * tv.z + w2.w * tv.w;
        }
      }
    } else {
      for (int k = 0; k < HH; ++k) {
        float w1 = ldin(hWo, tid * H3 + k, f32);
        float w2 = ldin(hWo, tid * H3 + HH + k, f32);
        #pragma unroll
        for (int rr = 0; rr < 4; ++rr) {
          a[rr] += w1 * tl[rr * 300 + k];
          ev[rr] += w2 * tl[rr * 300 + k];
        }
      }
    }
    #pragma unroll
    for (int rr = 0; rr < 4; ++rr) {
      A[(size_t)(lb0 + rr) * HH + tid] = a[rr];
      E[(size_t)(lb0 + rr) * HH + tid] = ev[rr];
    }
  }
}

// ---- fused gmax + gf ----
__global__ void k_gmf(const float* hg0, const float* hg1, const void* nhW, const void* rhW,
                      const void* mk, float* Gf0, float* Gf1) {
  bool f32 = is32(mk);
  int task = blockIdx.x >> 2, b = blockIdx.x & 3;
  const float* hg = task ? hg1 : hg0;
  const void* hWo = task ? rhW : nhW;
  float* Gf = task ? Gf1 : Gf0;
  __shared__ __align__(16) float gl[304];
  int tid = threadIdx.x;
  if (tid < HH) {
    float m = -1e30f;
    for (int l = 0; l < LLEN; ++l) m = fmaxf(m, hg[((size_t)l * BB + b) * HH + tid]);
    gl[tid] = m;
  }
  __syncthreads();
  if (tid < HH) {
    float acc = 0.f;
    if (f32) {
      const float4* row = (const float4*)((const float*)hWo + (size_t)tid * H3 + 600);
      #pragma unroll 5
      for (int k = 0; k < 75; ++k) {
        float4 u = row[k];
        const float4 gv = *(const float4*)(gl + 4 * k);
        acc += u.x * gv.x + u.y * gv.y + u.z * gv.z + u.w * gv.w;
      }
    } else {
      for (int k = 0; k < HH; ++k) acc += gl[k] * ldin(hWo, tid * H3 + 600 + k, f32);
    }
    Gf[b * HH + tid] = acc;
  }
}

// ---- pair epilogue ----
__global__ void __launch_bounds__(256) k_pair6(const float* A0, const float* E0, const float* Gf0,
                                               const void* lg0, const void* lb0_, const void* tW0, const void* tb0,
                                               const float* A1, const float* E1, const float* Gf1,
                                               const void* lg1, const void* lb1_, const void* tW1, const void* tb1,
                                               const void* mk, void* outv) {
  __shared__ float lg_l[304], lb_l[304], tb_l[16];
  __shared__ float tw_l[3616];
  bool f32 = is32(mk);
  int tau = blockIdx.x >> 12;
  int bid = blockIdx.x & 4095;
  const float* A  = tau ? A1 : A0;
  const float* E  = tau ? E1 : E0;
  const float* Gf = tau ? Gf1 : Gf0;
  const void* lgo = tau ? lg1 : lg0;
  const void* lbo = tau ? lb1_ : lb0_;
  const void* tWo = tau ? tW1 : tW0;
  const void* tbo = tau ? tb1 : tb0;
  int T = tau ? NRR : NTT;
  int diag = tau ? 0 : 1;
  int Toff = tau ? 458752 : 0;
  int tid = threadIdx.x;
  for (int i2 = tid; i2 < HH; i2 += 256) { lg_l[i2] = ldin(lgo, i2, f32); lb_l[i2] = ldin(lbo, i2, f32); }
  for (int i2 = tid; i2 < T * HH; i2 += 256) tw_l[i2] = ldin(tWo, i2, f32);
  if (tid < T) tb_l[tid] = ldin(tbo, tid, f32);
  __syncthreads();
  int i = bid >> 5;
  int j0 = (bid & 31) << 2;
  int b = tid >> 6, ln = tid & 63;
  const float* ar = A  + (size_t)(i * BB + b) * HH;
  const float* gr = Gf + (size_t)b * HH;
  bool ok4 = ln < 44;
  float a0 = ar[ln]       + gr[ln];
  float a1 = ar[64 + ln]  + gr[64 + ln];
  float a2 = ar[128 + ln] + gr[128 + ln];
  float a3 = ar[192 + ln] + gr[192 + ln];
  float a4 = ok4 ? (ar[256 + ln] + gr[256 + ln]) : 0.f;
  float mi = ldin(mk, i * BB + b, f32);
  for (int dj = 0; dj < 4; ++dj) {
    int jx = j0 + dj;
    const float* er = E + (size_t)(jx * BB + b) * HH;
    float u0 = a0 + er[ln];
    float u1 = a1 + er[64 + ln];
    float u2 = a2 + er[128 + ln];
    float u3 = a3 + er[192 + ln];
    float u4 = ok4 ? (a4 + er[256 + ln]) : 0.f;
    float s1 = ((u0 + u1) + (u2 + u3)) + u4;
    float s2 = ((u0 * u0 + u1 * u1) + (u2 * u2 + u3 * u3)) + u4 * u4;
    #pragma unroll
    for (int d = 1; d < 64; d <<= 1) { s1 += __shfl_xor(s1, d); s2 += __shfl_xor(s2, d); }
    float mean = s1 * (1.f / 300.f);
    float var = s2 * (1.f / 300.f) - mean * mean;
    float rstd = rsqrtf(var + 1e-5f);
    {
      float y;
      y = (u0 - mean) * rstd * lg_l[ln]       + lb_l[ln];       u0 = (y > 0.f) ? y : __expf(y) - 1.f;
      y = (u1 - mean) * rstd * lg_l[64 + ln]  + lb_l[64 + ln];  u1 = (y > 0.f) ? y : __expf(y) - 1.f;
      y = (u2 - mean) * rstd * lg_l[128 + ln] + lb_l[128 + ln]; u2 = (y > 0.f) ? y : __expf(y) - 1.f;
      y = (u3 - mean) * rstd * lg_l[192 + ln] + lb_l[192 + ln]; u3 = (y > 0.f) ? y : __expf(y) - 1.f;
      if (ok4) {
        y = (u4 - mean) * rstd * lg_l[256 + ln] + lb_l[256 + ln];
        u4 = (y > 0.f) ? y : __expf(y) - 1.f;
      }
    }
    float m = mi * ldin(mk, jx * BB + b, f32);
    if (diag && jx < i) m = 0.f;
    size_t obase = (size_t)Toff + ((size_t)(i * LLEN + jx) * BB + b) * T;
    float mine = 0.f;
    for (int t = 0; t < T; ++t) {
      const float* twr = tw_l + t * HH;
      float s = u0 * twr[ln] + u1 * twr[64 + ln] + u2 * twr[128 + ln] + u3 * twr[192 + ln];
      if (ok4) s += u4 * twr[256 + ln];
      s = wsum(s);
      s += tb_l[t];
      float o = m / (1.f + __expf(-s));
      mine = (ln == t) ? o : mine;
    }
    if (ln < T) {
      if (f32) ((float*)outv)[obase + ln] = mine;
      else ((u16*)outv)[obase + ln] = f2bf(mine);
    }
  }
}

// ---- sentinel ----
__global__ void k_sent(const void* mk, const void* xo, void* outv, int hostcode) {
  __shared__ int bad;
  if (threadIdx.x == 0) bad = 0;
  __syncthreads();
  bool f32 = is32(mk);
  for (int i = threadIdx.x; i < 4096; i += 256) {
    float v = ldin(xo, i, f32);
    if (!(v == v) || fabsf(v) > 1e6f) bad = 1;
  }
  __syncthreads();
  if (threadIdx.x == 0) {
    float code = (float)hostcode;
    if (bad) code = fmaxf(code, 88.f);
    if (code > 0.f) {
      if (f32) ((float*)outv)[0] = code;
      else ((u16*)outv)[0] = f2bf(code);
    }
  }
}

extern "C" void kernel_launch(void* const* d_in, const int* in_sizes, int n_in,
                              void* d_out, int out_size, void* d_ws, size_t ws_size,
                              hipStream_t stream) {
  const void* x    = d_in[0];
  const void* mask = d_in[1];
  const void* Wih  = d_in[2];
  const void* bih  = d_in[3];
  const void* Whh  = d_in[4];
  const void* bhh  = d_in[5];
  const void* Wtr  = d_in[6];
  const void* btr  = d_in[7];
  const void* nW   = d_in[8];
  const void* nb   = d_in[9];
  const void* nhW  = d_in[10];
  const void* nhb  = d_in[11];
  const void* ng   = d_in[12];
  const void* nbe  = d_in[13];
  const void* ntW  = d_in[14];
  const void* ntb  = d_in[15];
  const void* rW   = d_in[16];
  const void* rb   = d_in[17];
  const void* rhW  = d_in[18];
  const void* rhb  = d_in[19];
  const void* rg   = d_in[20];
  const void* rbe  = d_in[21];
  const void* rtW  = d_in[22];
  const void* rtb  = d_in[23];
  float* ws = (float*)d_ws;

  static const int exp_sz[24] = {393216, 512, 1152000, 1500, 450000, 1500, 270000, 300,
                                 180000, 300, 270000, 300, 300, 300, 2100, 7,
                                 180000, 300, 270000, 300, 300, 300, 3600, 12};
  int hostcode = 0;
  if (n_in != 24) hostcode = 890;
  else {
    for (int ii = 0; ii < 24; ++ii)
      if (in_sizes[ii] != exp_sz[ii]) { hostcode = 900 + ii; break; }
  }
  if (hostcode == 0 && out_size != 1245184) hostcode = 880;
  if (hostcode == 0 && ws_size < WS_NEED_BYTES) hostcode = 1099;

  dim3 gc(4500, 6);
  k_canon<<<gc, 256, 0, stream>>>(x, mask, Wih, bih, Whh, bhh, Wtr, btr, ws);
  k_pre2<<<128, 256, 0, stream>>>(x, Wih, mask, ws + C_X, ws + C_WIH, ws + F_BIH, ws + F_PRE);
  k_scanA<<<256, 512, 0, stream>>>(ws + F_PRE, (const float2*)(ws + C_WHH2), (const float2*)(ws + C_WTR2),
                                   ws + F_BTR, ws + F_HNER, ws + F_HRE, ws + F_HSH, ws + F_AUX, ws);
  k_scanB<<<256, 512, 0, stream>>>(ws + F_PRE, (const float2*)(ws + C_WHH2), (const float2*)(ws + C_WTR2),
                                   ws + F_BTR, ws + F_HNER, ws + F_HRE, ws + F_HSH, ws + F_AUX);
  k_glob3<<<256, 320, 0, stream>>>(ws + F_HSH, ws + F_HNER, ws + F_HRE,
                                   nW, nb, rW, rb, mask, ws + F_HG0, ws + F_HG1);
  k_feat2<<<256, 320, 0, stream>>>(ws + F_HNER, ws + F_HRE, nhW, nhb, rhW, rhb, mask,
                                   ws + F_A0, ws + F_E0, ws + F_A1, ws + F_E1);
  k_gmf<<<8, 320, 0, stream>>>(ws + F_HG0, ws + F_HG1, nhW, rhW, mask, ws + F_GF0, ws + F_GF1);
  k_pair6<<<8192, 256, 0, stream>>>(ws + F_A0, ws + F_E0, ws + F_GF0, ng, nbe, ntW, ntb,
                                    ws + F_A1, ws + F_E1, ws + F_GF1, rg, rbe, rtW, rtb,
                                    mask, d_out);
  k_sent<<<1, 256, 0, stream>>>(mask, x, d_out, hostcode);
}

// Round 10
// 1367.058 us; speedup vs baseline: 1.0654x; 1.0518x over previous
//
#include <hip/hip_runtime.h>

#define LLEN 128
#define BB 4
#define DD 768
#define HH 300
#define G5 1500
#define H3 900
#define NTT 7
#define NRR 12
#define NCHB 10
#define RPB 150
#define OPB 30

// ---- fp32 workspace layout (ws as float*) ----
#define C_WIH  0
#define C_X    1152000
#define C_WHH2 1545216
#define C_WTR2 1995216
#define F_BIH  2265216
#define F_BTR  2266720
#define F_PRE  2267040
// PRE region reused after the scan:
#define F_HG0  (F_PRE)
#define F_HG1  (F_PRE+153600)
#define F_A0   (F_PRE+307200)
#define F_E0   (F_PRE+460800)
#define F_GF0  (F_PRE+616832)
#define F_GF1  (F_PRE+618048)
// beyond PRE:
#define F_HNER (F_PRE+768000)
#define F_HRE  (F_HNER+153600)
#define F_HSH  (F_HRE+153600)
#define F_A1   0
#define F_E1   153600
#define F_AUX  (F_HSH+153600)
// scanA exchange buffers in the scan-dead C_WIH region [0,1152000):
//   partials: part(buf,b) = buf*96000 + b*24000: 1500 rows x 16 floats
//   (cols 0..9 partial sums, 10..11 zero pads, 12..15 never read) [R6/R9-proven]
//   c_pub: 192000 + (buf*4+b)*304
#define P_CPUB 192000
// aux per-batch (AUXB floats): scanB selftest words (tst @ gb+2240, seflag @ gb+2272)
#define AUXB   2432
#define AUX_FL 9728
// int area (2048 ints, zeroed per launch with AGENT stores — these lines are
// touched EXCLUSIVELY by agent-scope ops by every kernel, so LLC is authoritative):
//   chunk0 (scanA): claim [0,32); per batch b at [32+64b): slots[0..15], abort@+24
//   chunk1 (scanB): claim [640,672); per batch b at [672+64b): slotsA[16] slotsB[16] atf[5]
//   done[4] @ [1536,1540)  (scanA completion counters; scanB skips batch iff ==NCHB)
#define WS_NEED_BYTES ((size_t)(F_AUX+11776)*4)

typedef unsigned short u16;
typedef unsigned int u32;
typedef float f4 __attribute__((ext_vector_type(4)));
typedef int i4 __attribute__((ext_vector_type(4)));

__device__ __forceinline__ float bf2f(u16 u) {
  union { u32 i; float f; } v; v.i = ((u32)u) << 16; return v.f;
}
__device__ __forceinline__ u16 f2bf(float f) {
  union { float f; u32 i; } v; v.f = f;
  u32 r = v.i + 0x7fffu + ((v.i >> 16) & 1u);
  return (u16)(r >> 16);
}
__device__ __forceinline__ float ldin(const void* p, int i, bool f32) {
  return f32 ? ((const float*)p)[i] : bf2f(((const u16*)p)[i]);
}
__device__ __forceinline__ bool is32(const void* mk) {
  return ((const u16*)mk)[0] == 0;
}
__device__ __forceinline__ float wsum(float x) {
  #pragma unroll
  for (int d = 1; d < 64; d <<= 1) x += __shfl_xor(x, d);
  return x;
}
// ---- agent-scope (LLC) accessors ----
__device__ __forceinline__ void astore(float* p, float v) {
  union { float f; int i; } u; u.f = v;
  __hip_atomic_store((int*)p, u.i, __ATOMIC_RELAXED, __HIP_MEMORY_SCOPE_AGENT);
}
// proven agent-scope inter-block barrier (scanB selftest/claim only)
__device__ __forceinline__ void gbar(int* flag, int tid, int target) {
  __syncthreads();
  if (tid == 0) {
    __builtin_amdgcn_s_waitcnt(0);
    __hip_atomic_fetch_add(flag, 1, __ATOMIC_RELAXED, __HIP_MEMORY_SCOPE_AGENT);
    int it = 0;
    while (__hip_atomic_load(flag, __ATOMIC_RELAXED, __HIP_MEMORY_SCOPE_AGENT) < target) {
      __builtin_amdgcn_s_sleep(1);
      if (++it > 50000) break;
    }
  }
  __syncthreads();
}
// ---- scoped exchange primitives (mode 1 = XCD/L2, mode 0 = agent/LLC) ----
__device__ __forceinline__ f4 ld4x(const f4* p, int mode) {
  f4 v;
  if (mode)
    asm volatile("global_load_dwordx4 %0, %1, off sc0\n\ts_waitcnt vmcnt(0)"
                 : "=v"(v) : "v"(p) : "memory");
  else
    asm volatile("global_load_dwordx4 %0, %1, off sc0 sc1\n\ts_waitcnt vmcnt(0)"
                 : "=v"(v) : "v"(p) : "memory");
  return v;
}
__device__ __forceinline__ float ld1x(const float* p, int mode) {
  float v;
  if (mode)
    asm volatile("global_load_dword %0, %1, off sc0\n\ts_waitcnt vmcnt(0)"
                 : "=v"(v) : "v"(p) : "memory");
  else
    asm volatile("global_load_dword %0, %1, off sc0 sc1\n\ts_waitcnt vmcnt(0)"
                 : "=v"(v) : "v"(p) : "memory");
  return v;
}
__device__ __forceinline__ int ldix(const int* p, int mode) {
  int v;
  if (mode)
    asm volatile("global_load_dword %0, %1, off sc0\n\ts_waitcnt vmcnt(0)"
                 : "=v"(v) : "v"(p) : "memory");
  else
    asm volatile("global_load_dword %0, %1, off sc0 sc1\n\ts_waitcnt vmcnt(0)"
                 : "=v"(v) : "v"(p) : "memory");
  return v;
}
__device__ __forceinline__ void exst(float* p, float v, int mode) {
  if (mode) *p = v; else astore(p, v);
}
// 9 overlapped dwordx4 from one 64B-aligned base (3 rows x 3 quads), L2-local
__device__ __forceinline__ void ld9(const float* base,
                                    f4& a0, f4& a1, f4& a2, f4& a3, f4& a4,
                                    f4& a5, f4& a6, f4& a7, f4& a8) {
  asm volatile(
    "global_load_dwordx4 %0, %9, off sc0\n\t"
    "global_load_dwordx4 %1, %9, off offset:16 sc0\n\t"
    "global_load_dwordx4 %2, %9, off offset:32 sc0\n\t"
    "global_load_dwordx4 %3, %9, off offset:64 sc0\n\t"
    "global_load_dwordx4 %4, %9, off offset:80 sc0\n\t"
    "global_load_dwordx4 %5, %9, off offset:96 sc0\n\t"
    "global_load_dwordx4 %6, %9, off offset:128 sc0\n\t"
    "global_load_dwordx4 %7, %9, off offset:144 sc0\n\t"
    "global_load_dwordx4 %8, %9, off offset:160 sc0\n\t"
    "s_waitcnt vmcnt(0)"
    : "=&v"(a0), "=&v"(a1), "=&v"(a2), "=&v"(a3), "=&v"(a4),
      "=&v"(a5), "=&v"(a6), "=&v"(a7), "=&v"(a8)
    : "v"(base) : "memory");
}
// poll all 10 arrival slots (12 loaded; last 2 zero padding)
__device__ __forceinline__ int poll10(const int* slots, int tok, int mode) {
  i4 a, b, c;
  if (mode)
    asm volatile("global_load_dwordx4 %0, %3, off sc0\n\t"
                 "global_load_dwordx4 %1, %4, off sc0\n\t"
                 "global_load_dwordx4 %2, %5, off sc0\n\t"
                 "s_waitcnt vmcnt(0)"
                 : "=&v"(a), "=&v"(b), "=&v"(c)
                 : "v"(slots), "v"(slots + 4), "v"(slots + 8) : "memory");
  else
    asm volatile("global_load_dwordx4 %0, %3, off sc0 sc1\n\t"
                 "global_load_dwordx4 %1, %4, off sc0 sc1\n\t"
                 "global_load_dwordx4 %2, %5, off sc0 sc1\n\t"
                 "s_waitcnt vmcnt(0)"
                 : "=&v"(a), "=&v"(b), "=&v"(c)
                 : "v"(slots), "v"(slots + 4), "v"(slots + 8) : "memory");
  return (a.x >= tok) & (a.y >= tok) & (a.z >= tok) & (a.w >= tok) &
         (b.x >= tok) & (b.y >= tok) & (b.z >= tok) & (b.w >= tok) &
         (c.x >= tok) & (c.y >= tok);
}
// slot barrier (scanB, proven): drain + sync + tid0 token store; wave 0 polls
__device__ __forceinline__ void sbar(int* slots, int ch, int tok, int tid, int mode) {
  asm volatile("s_waitcnt vmcnt(0)" ::: "memory");
  __syncthreads();
  if (tid == 0) {
    if (mode) slots[ch] = tok;
    else __hip_atomic_store(slots + ch, tok, __ATOMIC_RELAXED, __HIP_MEMORY_SCOPE_AGENT);
  }
  if (tid < 64) {
    int it = 0;
    while (!poll10(slots, tok, mode)) {
      __builtin_amdgcn_s_sleep(1);
      if (++it > 5000) break;
    }
  }
  __syncthreads();
}
// scanA slot barrier: AGENT-scope tokens (LLC-exclusive lines, stale-proof) +
// L2-local payload (covered by drain-before-token). Timeout -> abort propagation.
__device__ __forceinline__ void sbarA(int* slots, int* abf, int ch, int tok, int tid,
                                      volatile int* s_fail) {
  asm volatile("s_waitcnt vmcnt(0)" ::: "memory");  // payload drained to our L2
  __syncthreads();
  if (tid == 0)
    __hip_atomic_store(slots + ch, tok, __ATOMIC_RELAXED, __HIP_MEMORY_SCOPE_AGENT);
  if (tid < 64) {
    int it = 0;
    while (!poll10(slots, tok, 0)) {   // mode 0 = agent/LLC reads
      __builtin_amdgcn_s_sleep(1);
      ++it;
      if ((it & 255) == 0 &&
          __hip_atomic_load(abf, __ATOMIC_RELAXED, __HIP_MEMORY_SCOPE_AGENT) != 0) {
        *s_fail = 1; break;
      }
      if (it > 8000) {
        __hip_atomic_store(abf, 1, __ATOMIC_RELAXED, __HIP_MEMORY_SCOPE_AGENT);
        *s_fail = 1; break;
      }
    }
  }
  __syncthreads();
}
// claim (xcd, rank) via HW_REG_XCC_ID + grid rendezvous (agent-only lines)
__device__ __forceinline__ int claim_bc(int* cl, int nb) {
  unsigned xcd;
  asm volatile("s_getreg_b32 %0, hwreg(HW_REG_XCC_ID)" : "=s"(xcd));
  xcd &= 7u;
  int rank = __hip_atomic_fetch_add(cl + xcd, 1, __ATOMIC_RELAXED, __HIP_MEMORY_SCOPE_AGENT);
  __hip_atomic_fetch_add(cl + 8, 1, __ATOMIC_RELAXED, __HIP_MEMORY_SCOPE_AGENT);
  int it = 0;
  while (__hip_atomic_load(cl + 8, __ATOMIC_RELAXED, __HIP_MEMORY_SCOPE_AGENT) < nb) {
    __builtin_amdgcn_s_sleep(2);
    if (++it > 100000) break;
  }
  int base = 0;
  for (unsigned x = 0; x < xcd; ++x)
    base += __hip_atomic_load(cl + x, __ATOMIC_RELAXED, __HIP_MEMORY_SCOPE_AGENT) / NCHB;
  int cnt = __hip_atomic_load(cl + xcd, __ATOMIC_RELAXED, __HIP_MEMORY_SCOPE_AGENT);
  int slot = base + rank / NCHB;
  return (rank < (cnt / NCHB) * NCHB && slot < BB) ? (slot * 16 + rank % NCHB) : -1;
}

// ---- canonicalize (compact grid-stride; dispatch overhead was the cost) ----
__global__ void k_canon(const void* xo, const void* mk, const void* Wih, const void* bih,
                        const void* Whh, const void* bhh, const void* Wtr, const void* btr,
                        float* ws) {
  bool f32 = is32(mk);
  int piece = blockIdx.y;
  int i0 = blockIdx.x * 256 + threadIdx.x;
  int stride = gridDim.x * 256;
  switch (piece) {
    case 0: if (!f32) for (int i = i0; i < 1152000; i += stride) ws[C_WIH + i] = ldin(Wih, i, f32); break;
    case 1: if (!f32) for (int i = i0; i < 393216; i += stride) ws[C_X + i] = ldin(xo, i, f32); break;
    case 2: for (int i = i0; i < 225000; i += stride) {
      int k2 = i / G5, out = i - k2 * G5;
      float2 v;
      v.x = ldin(Whh, out * HH + 2 * k2, f32);
      v.y = ldin(Whh, out * HH + 2 * k2 + 1, f32);
      ((float2*)(ws + C_WHH2))[i] = v;
    } break;
    case 3: for (int i = i0; i < 135000; i += stride) {
      int k2 = i / HH, out = i - k2 * HH;
      float2 v;
      v.x = ldin(Wtr, out * H3 + 2 * k2, f32);
      v.y = ldin(Wtr, out * H3 + 2 * k2 + 1, f32);
      ((float2*)(ws + C_WTR2))[i] = v;
    } break;
    case 4: for (int i = i0; i < 1824; i += stride) {
      if (i < 1504) ws[F_BIH + i] = (i < G5) ? ldin(bih, i, f32) + ldin(bhh, i, f32) : 0.f;
      else { int j = i - 1504; ws[F_BTR + j] = (j < HH) ? ldin(btr, j, f32) : 0.f; }
    } break;
    case 5: for (int i = i0; i < 11776; i += stride) {
      if (i < AUX_FL) ws[F_AUX + i] = 0.f;                     // float aux (selftest words)
      else {                                                    // int control area: AGENT zero
        int* ip = (int*)(ws + F_AUX + AUX_FL);
        __hip_atomic_store(ip + (i - AUX_FL), 0, __ATOMIC_RELAXED, __HIP_MEMORY_SCOPE_AGENT);
      }
    } break;
  }
}

// ---- pre = x @ W_ih^T + (b_ih + b_hh) ----
__global__ void k_pre2(const void* xo, const void* Wo, const void* mk,
                       const float* cX, const float* cW, const float* biasf, float* pre) {
  bool f32 = is32(mk);
  const float* X = f32 ? (const float*)xo : cX;
  const float* W = f32 ? (const float*)Wo : cW;
  __shared__ __align__(16) float xl[8 * DD];
  int tid = threadIdx.x;
  int lb0 = (blockIdx.x >> 1) * 8;
  int half = blockIdx.x & 1;
  for (int e = tid; e < 8 * DD; e += 256) xl[e] = X[(size_t)lb0 * DD + e];
  __syncthreads();
  for (int j = half * 750 + tid; j < half * 750 + 750; j += 256) {
    const float4* w = (const float4*)(W + (size_t)j * DD);
    float acc[8] = {0.f, 0.f, 0.f, 0.f, 0.f, 0.f, 0.f, 0.f};
    #pragma unroll 2
    for (int k = 0; k < DD / 4; ++k) {
      float4 u = w[k];
      #pragma unroll
      for (int r = 0; r < 8; ++r) {
        const float4 p = *(const float4*)(xl + r * DD + k * 4);
        acc[r] += u.x * p.x + u.y * p.y + u.z * p.z + u.w * p.w;
      }
    }
    float bias = biasf[j];
    #pragma unroll
    for (int r = 0; r < 8; ++r) pre[(size_t)(lb0 + r) * G5 + j] = acc[r] + bias;
  }
}

// ---- scanA: R9-proven 1-barrier/step (unchanged; grid shrunk to 128 blocks) ----
__global__ void __launch_bounds__(512, 2) k_scanA(const float* pre, const float2* W2h, const float2* W2t,
                                                  const float* btrf, float* hner, float* hre, float* hsh,
                                                  float* aux, float* xw) {
  __shared__ __align__(16) float ga_l[1504];
  __shared__ __align__(16) float vv_l[1204];
  __shared__ __align__(16) float tnh_l[304];
  __shared__ __align__(16) float cat_l[904];
  __shared__ __align__(16) float ci_l[304];
  __shared__ __align__(16) float ps[512];
  __shared__ __align__(16) float h_loc[32];
  __shared__ int s_bc;
  __shared__ int s_fail;
  int tid = threadIdx.x;
  int* ibase = (int*)(aux + AUX_FL);
  if (tid == 0) { s_bc = claim_bc(ibase, (int)gridDim.x); s_fail = 0; }
  __syncthreads();
  int bc = s_bc;
  if (bc < 0) return;
  int b = bc >> 4, ch = bc & 15;
  int* slots = ibase + 32 + b * 64;
  int* abf   = slots + 24;
  int* done  = ibase + 1536;

  // zero pad columns (10,11) of both partial buffers (plain stores to our L2;
  // covered for readers by the drain in the first sbarA)
  if (ch < 2) {
    float* pb0 = xw + (size_t)ch * 96000 + b * 24000;
    for (int i = tid; i < 3000; i += 512) {
      int row = i >> 1, col = 10 + (i & 1);
      pb0[row * 16 + col] = 0.f;
    }
  }

  int o0 = 3 * tid;
  float2 wh2[45];
  if (tid < 500) {
    #pragma unroll
    for (int j = 0; j < 3; ++j)
      #pragma unroll
      for (int kk = 0; kk < 15; ++kk)
        wh2[j * 15 + kk] = W2h[(size_t)(ch * 15 + kk) * G5 + (o0 + j)];
  }
  int o2 = tid % OPB, jj = tid / OPB;
  float2 wt[29];
  int k2b = jj * 29;
  int k2e = (k2b + 29 < 450) ? (k2b + 29) : 450;
  int nk2 = k2e - k2b;
  if (tid < 480) {
    const float2* wp = W2t + (size_t)k2b * HH + (ch * OPB + o2);
    #pragma unroll
    for (int q = 0; q < 29; ++q) if (q < nk2) wt[q] = wp[(size_t)q * HH];
  }
  float pv0 = 0.f, pv1 = 0.f, pv2 = 0.f;
  if (tid < 500) {
    const float* pr = pre + (size_t)b * G5 + o0;
    pv0 = pr[0]; pv1 = pr[1]; pv2 = pr[2];
  }
  __syncthreads();

  for (int t = 0; t < LLEN; ++t) {
    int buf = t & 1;
    float* pb = xw + (size_t)buf * 96000 + b * 24000;
    if (t > 0) {
      if (tid < 500) {
        float2 h2[15];
        #pragma unroll
        for (int kk = 0; kk < 15; ++kk) h2[kk] = *(const float2*)(h_loc + 2 * kk);
        #pragma unroll
        for (int j = 0; j < 3; ++j) {
          float acc = 0.f;
          #pragma unroll
          for (int kk = 0; kk < 15; ++kk)
            acc += wh2[j * 15 + kk].x * h2[kk].x + wh2[j * 15 + kk].y * h2[kk].y;
          pb[(size_t)(o0 + j) * 16 + ch] = acc;
        }
      }
      sbarA(slots, abf, ch, t, tid, &s_fail);   // the ONLY inter-block barrier
      if (s_fail) return;                        // desync: scanB redoes this batch
      if (tid < 500) {
        f4 a0, a1, a2, a3, a4, a5, a6, a7, a8;
        ld9(pb + (size_t)o0 * 16, a0, a1, a2, a3, a4, a5, a6, a7, a8);
        ga_l[o0]     = pv0 + (((a0.x + a0.y) + (a0.z + a0.w)) +
                              ((a1.x + a1.y) + (a1.z + a1.w)) +
                              ((a2.x + a2.y) + (a2.z + a2.w)));
        ga_l[o0 + 1] = pv1 + (((a3.x + a3.y) + (a3.z + a3.w)) +
                              ((a4.x + a4.y) + (a4.z + a4.w)) +
                              ((a5.x + a5.y) + (a5.z + a5.w)));
        ga_l[o0 + 2] = pv2 + (((a6.x + a6.y) + (a6.z + a6.w)) +
                              ((a7.x + a7.y) + (a7.z + a7.w)) +
                              ((a8.x + a8.y) + (a8.z + a8.w)));
      }
      if (tid < 75) {
        const float* cp = xw + P_CPUB + (size_t)(((t - 1) & 1) * 4 + b) * 304;
        f4 v = ld4x((const f4*)cp + tid, 1);
        *(f4*)(ci_l + 4 * tid) = v;
      }
    } else {
      if (tid < 500) { ga_l[o0] = pv0; ga_l[o0 + 1] = pv1; ga_l[o0 + 2] = pv2; }
    }
    __syncthreads();
    if (tid < HH) tnh_l[tid] = tanhf(ga_l[tid]);
    {
      int w = tid >> 6, ln = tid & 63;
      if (w >= 4) {
        int c = w - 3;
        const float* g = ga_l + c * 300;
        int e0 = ln * 5;
        float ex0 = 0.f, ex1 = 0.f, ex2 = 0.f, ex3 = 0.f, ex4 = 0.f;
        if (ln < 60) {
          ex0 = __expf(g[e0]); ex1 = __expf(g[e0 + 1]); ex2 = __expf(g[e0 + 2]);
          ex3 = __expf(g[e0 + 3]); ex4 = __expf(g[e0 + 4]);
        }
        float p = ((ex0 + ex1) + (ex2 + ex3)) + ex4;
        float inc = p;
        #pragma unroll
        for (int d = 1; d < 64; d <<= 1) { float o = __shfl_up(inc, d); if (ln >= d) inc += o; }
        float S = __shfl(inc, 59);
        float invS = 1.f / S;
        float run = inc - p;
        if (ln < 60) {
          float* vv = vv_l + (c - 1) * 300 + e0;
          run += ex0; vv[0] = run * invS;
          run += ex1; vv[1] = run * invS;
          run += ex2; vv[2] = run * invS;
          run += ex3; vv[3] = run * invS;
          run += ex4; vv[4] = run * invS;
        }
      }
    }
    if (t + 1 < LLEN && tid < 500) {
      const float* pr = pre + ((size_t)(t + 1) * BB + b) * G5 + o0;
      pv0 = pr[0]; pv1 = pr[1]; pv2 = pr[2];
    }
    __syncthreads();
    if (tid < HH) {
      float c = tnh_l[tid];
      float v0 = vv_l[tid], v1 = vv_l[300 + tid], v2 = vv_l[600 + tid], v3 = vv_l[900 + tid];
      float eg_cin = 1.f - v0, rg_cin = v1, eg_c = 1.f - v2, rg_c = v3;
      float ci = (t > 0) ? ci_l[tid] : 0.f;
      float ov_c = rg_c * eg_c;
      float up_c = rg_c - ov_c, dn_c = eg_c - ov_c;
      float ov_i = rg_cin * eg_cin;
      float up_i = rg_cin - ov_i, dn_i = eg_cin - ov_i;
      float share = ov_i * ci + ov_c * c;
      float c_re  = up_i * ci + up_c * c + share;
      float c_ner = dn_i * ci + dn_c * c + share;
      cat_l[tid] = c_re; cat_l[HH + tid] = c_ner; cat_l[2 * HH + tid] = share;
      int sb = ch * OPB;
      if (tid >= sb && tid < sb + OPB) {
        size_t ob = ((size_t)t * BB + b) * HH + tid;
        hner[ob] = tanhf(c_ner); hre[ob] = tanhf(c_re); hsh[ob] = tanhf(share);
      }
    }
    __syncthreads();
    if (tid < 480) {
      float acc = 0.f;
      #pragma unroll
      for (int q = 0; q < 29; ++q)
        if (q < nk2) acc += wt[q].x * cat_l[2 * (k2b + q)] + wt[q].y * cat_l[2 * (k2b + q) + 1];
      ps[tid] = acc;
    }
    __syncthreads();
    if (tid < OPB) {
      float co = btrf[ch * OPB + tid];
      #pragma unroll
      for (int q = 0; q < 16; ++q) co += ps[q * OPB + tid];
      h_loc[tid] = tanhf(co);
      float* cp = xw + P_CPUB + (size_t)(buf * 4 + b) * 304;
      cp[ch * OPB + tid] = co;
    }
    __syncthreads();
  }
  // completed with zero timeouts -> publish; scanB (stream-serialized) skips batch
  if (tid == 0 && s_fail == 0)
    __hip_atomic_fetch_add(done + b, 1, __ATOMIC_RELAXED, __HIP_MEMORY_SCOPE_AGENT);
}

// ---- scanB: R4-proven 2-barrier kernel; per-batch skip iff scanA fully done ----
__global__ void __launch_bounds__(512, 2) k_scanB(const float* pre, const float2* W2h, const float2* W2t,
                                                  const float* btrf, float* hner, float* hre, float* hsh,
                                                  float* aux) {
  __shared__ __align__(16) float h_l[304];
  __shared__ __align__(16) float ci_l[304];
  __shared__ __align__(16) float ga_l[1504];
  __shared__ __align__(16) float cat_l[904];
  __shared__ __align__(16) float ps[512];
  __shared__ __align__(16) float sums_l[8];
  __shared__ float exv[160];
  __shared__ int s_bc, s_mode, s_skip;
  int tid = threadIdx.x;
  int* ibase = (int*)(aux + AUX_FL);
  int* cl2 = ibase + 640;
  if (tid == 0) s_bc = claim_bc(cl2, (int)gridDim.x);
  __syncthreads();
  int bc = s_bc;
  if (bc < 0) return;
  int b = bc >> 4, ch = bc & 15;
  int* done = ibase + 1536;
  if (tid == 0)
    s_skip = (__hip_atomic_load(done + b, __ATOMIC_RELAXED, __HIP_MEMORY_SCOPE_AGENT) == NCHB);
  __syncthreads();
  if (s_skip) return;  // scanA fully produced this batch
  int s = ch >> 1;
  int r0 = ch * RPB;
  float* gb   = aux + b * AUXB;
  float* cb   = gb + 1504;
  float* hb   = gb + 1808;
  float* sums = gb + 2112;
  int* slotsA = ibase + 672 + b * 64;
  int* slotsB = slotsA + 16;
  int* atf    = slotsA + 32;

  // ---- selftest (R4-proven form) ----
  {
    float* tst = gb + 2240;
    int* seflag = (int*)(gb + 2272);
    if (ch == 0 && tid == 0) tst[0] = 1.0f;
    gbar(atf + 0, tid, NCHB);
    if (tid == 0) { float w1 = ld1x(tst, 1); (void)w1; }
    gbar(atf + 1, tid, NCHB);
    if (ch == 0 && tid == 0) { tst[0] = 2.0f; __builtin_amdgcn_s_waitcnt(0); }
    if (ch == 1 && tid == 0)
      __hip_atomic_fetch_add(seflag, 1, __ATOMIC_RELAXED, __HIP_MEMORY_SCOPE_WORKGROUP);
    gbar(atf + 2, tid, NCHB);
    if (tid == 0) {
      float w2 = ld1x(tst, 1);
      int fv = ldix(seflag, 1);
      if (w2 != 2.0f || fv != 1)
        __hip_atomic_fetch_or(atf + 4, 1, __ATOMIC_RELAXED, __HIP_MEMORY_SCOPE_AGENT);
    }
    gbar(atf + 3, tid, NCHB);
    if (tid == 0)
      s_mode = (__hip_atomic_load(atf + 4, __ATOMIC_RELAXED, __HIP_MEMORY_SCOPE_AGENT) == 0) ? 1 : 0;
    __syncthreads();
  }
  int mode = s_mode;

  int j = tid / RPB, r = tid - j * RPB;
  int o2 = tid % OPB, jj = tid / OPB;
  int kb = j * 100;

  float2 wh[50];
  if (tid < 450) {
    const float2* wp = W2h + (size_t)(j * 50) * G5 + (r0 + r);
    #pragma unroll
    for (int kk = 0; kk < 50; ++kk) wh[kk] = wp[(size_t)kk * G5];
  }
  float2 wt[29];
  int k2b = jj * 29;
  int k2e = (k2b + 29 < 450) ? (k2b + 29) : 450;
  int nk2 = k2e - k2b;
  if (tid < 480) {
    const float2* wp = W2t + (size_t)k2b * HH + (ch * OPB + o2);
    #pragma unroll
    for (int q = 0; q < 29; ++q) if (q < nk2) wt[q] = wp[(size_t)q * HH];
  }
  float pv = 0.f;
  if (tid < RPB) pv = pre[(size_t)b * G5 + r0 + tid];
  __syncthreads();

  for (int t = 0; t < LLEN; ++t) {
    if (t > 0) {
      if (tid < 75)       { f4 v = ld4x((const f4*)hb + tid, mode); *(f4*)(h_l + 4 * tid) = v; }
      else if (tid < 150) { int q = tid - 75; f4 v = ld4x((const f4*)cb + q, mode); *(f4*)(ci_l + 4 * q) = v; }
      __syncthreads();
    }
    if (tid < 450) {
      float acc = (j == 0) ? pv : 0.f;
      if (t > 0) {
        #pragma unroll
        for (int kk = 0; kk < 50; ++kk)
          acc += wh[kk].x * h_l[kb + 2 * kk] + wh[kk].y * h_l[kb + 2 * kk + 1];
      }
      ps[tid] = acc;
    }
    __syncthreads();
    if (tid < RPB) {
      float g = ps[tid] + ps[RPB + tid] + ps[2 * RPB + tid];
      if (s == 0) exst(gb + r0 + tid, tanhf(g), mode);
      else exv[tid] = __expf(g);
    }
    if (s > 0) {
      __syncthreads();
      if (tid < 30) {
        int base2 = tid * 5;
        float e0 = exv[base2], e1 = exv[base2 + 1], e2 = exv[base2 + 2],
              e3 = exv[base2 + 3], e4 = exv[base2 + 4];
        float p = ((e0 + e1) + (e2 + e3)) + e4;
        float inc = p;
        #pragma unroll
        for (int d = 1; d < 32; d <<= 1) { float o = __shfl_up(inc, d); if (tid >= d) inc += o; }
        float tot = __shfl(inc, 29);
        float run = inc - p;
        run += e0; exst(gb + r0 + base2,     run, mode);
        run += e1; exst(gb + r0 + base2 + 1, run, mode);
        run += e2; exst(gb + r0 + base2 + 2, run, mode);
        run += e3; exst(gb + r0 + base2 + 3, run, mode);
        run += e4; exst(gb + r0 + base2 + 4, run, mode);
        if (tid == 0) exst(sums + (ch - 2), tot, mode);
      }
    }
    sbar(slotsA, ch, t + 1, tid, mode);
    if (tid < 375)      { f4 v = ld4x((const f4*)gb + tid, mode); *(f4*)(ga_l + 4 * tid) = v; }
    else if (tid < 377) { int q = tid - 375; f4 v = ld4x((const f4*)sums + q, mode); *(f4*)(sums_l + 4 * q) = v; }
    float pvn = 0.f;
    if (t + 1 < LLEN && tid < RPB) pvn = pre[((size_t)(t + 1) * BB + b) * G5 + r0 + tid];
    __syncthreads();
    if (tid < HH) {
      float c = ga_l[tid];
      float v[4];
      #pragma unroll
      for (int s1 = 0; s1 < 4; ++s1) {
        float raw = ga_l[(s1 + 1) * HH + tid];
        float off = (tid >= RPB) ? sums_l[2 * s1] : 0.f;
        float S = sums_l[2 * s1] + sums_l[2 * s1 + 1];
        v[s1] = (raw + off) / S;
      }
      float eg_cin = 1.f - v[0], rg_cin = v[1], eg_c = 1.f - v[2], rg_c = v[3];
      float ci = (t > 0) ? ci_l[tid] : 0.f;
      float ov_c = rg_c * eg_c;
      float up_c = rg_c - ov_c, dn_c = eg_c - ov_c;
      float ov_i = rg_cin * eg_cin;
      float up_i = rg_cin - ov_i, dn_i = eg_cin - ov_i;
      float share = ov_i * ci + ov_c * c;
      float c_re  = up_i * ci + up_c * c + share;
      float c_ner = dn_i * ci + dn_c * c + share;
      cat_l[tid] = c_re; cat_l[HH + tid] = c_ner; cat_l[2 * HH + tid] = share;
      int sb = ch * OPB;
      if (tid >= sb && tid < sb + OPB) {
        size_t ob = ((size_t)t * BB + b) * HH + tid;
        hner[ob] = tanhf(c_ner); hre[ob] = tanhf(c_re); hsh[ob] = tanhf(share);
      }
    }
    __syncthreads();
    if (tid < 480) {
      float acc = 0.f;
      #pragma unroll
      for (int q = 0; q < 29; ++q)
        if (q < nk2) acc += wt[q].x * cat_l[2 * (k2b + q)] + wt[q].y * cat_l[2 * (k2b + q) + 1];
      ps[tid] = acc;
    }
    __syncthreads();
    if (tid < OPB) {
      float co = btrf[ch * OPB + tid];
      #pragma unroll
      for (int q = 0; q < 16; ++q) co += ps[q * OPB + tid];
      exst(cb + ch * OPB + tid, co, mode);
      exst(hb + ch * OPB + tid, tanhf(co), mode);
    }
    if (t + 1 < LLEN) sbar(slotsB, ch, t + 1, tid, mode);
    pv = pvn;
  }
}

// ---- fused h_glob + A/E features (independent; previously serialized launches) ----
__global__ void k_post(const float* hsh, const float* hner, const float* hre,
                       const void* nW, const void* nb, const void* rW, const void* rb,
                       const void* nhW, const void* nhb, const void* rhW, const void* rhb,
                       const void* mk, float* hg0, float* hg1,
                       float* A0, float* E0, float* A1, float* E1) {
  bool f32 = is32(mk);
  int role = blockIdx.x >> 8;   // 0 = glob, 1 = feat
  int sub  = blockIdx.x & 255;
  int task = sub >> 7;
  int lb0 = (sub & 127) * 4;
  __shared__ __align__(16) float buf[2400];
  int tid = threadIdx.x;
  if (role == 0) {
    const float* tsk = task ? hre : hner;
    const void* gWo = task ? rW : nW;
    const void* gbo = task ? rb : nb;
    float* hg = task ? hg1 : hg0;
    for (int e = tid; e < 2400; e += 320) {
      int rr = e / 600, c = e - rr * 600;
      buf[e] = (c < HH) ? hsh[(size_t)(lb0 + rr) * HH + c] : tsk[(size_t)(lb0 + rr) * HH + (c - HH)];
    }
    __syncthreads();
    if (tid < HH) {
      float bias = ldin(gbo, tid, f32);
      float acc[4] = {bias, bias, bias, bias};
      if (f32) {
        const float4* row = (const float4*)((const float*)gWo + (size_t)tid * 600);
        #pragma unroll 2
        for (int k = 0; k < 150; ++k) {
          float4 u = row[k];
          #pragma unroll
          for (int rr = 0; rr < 4; ++rr) {
            const float4 cv = *(const float4*)(buf + rr * 600 + 4 * k);
            acc[rr] += u.x * cv.x + u.y * cv.y + u.z * cv.z + u.w * cv.w;
          }
        }
      } else {
        for (int k = 0; k < 600; ++k) {
          float w = ldin(gWo, tid * 600 + k, f32);
          #pragma unroll
          for (int rr = 0; rr < 4; ++rr) acc[rr] += w * buf[rr * 600 + k];
        }
      }
      #pragma unroll
      for (int rr = 0; rr < 4; ++rr) hg[(size_t)(lb0 + rr) * HH + tid] = tanhf(acc[rr]);
    }
  } else {
    const float* tsk = task ? hre : hner;
    const void* hWo = task ? rhW : nhW;
    const void* hbo = task ? rhb : nhb;
    float* A = task ? A1 : A0;
    float* E = task ? E1 : E0;
    for (int e = tid; e < 1200; e += 320) {
      int rr = e / 300, c = e - rr * 300;
      buf[e] = tsk[(size_t)(lb0 + rr) * HH + c];
    }
    __syncthreads();
    if (tid < HH) {
      float bias = ldin(hbo, tid, f32);
      float a[4] = {bias, bias, bias, bias};
      float ev[4] = {0.f, 0.f, 0.f, 0.f};
      if (f32) {
        const float4* r1 = (const float4*)((const float*)hWo + (size_t)tid * H3);
        const float4* r2 = (const float4*)((const float*)hWo + (size_t)tid * H3 + HH);
        #pragma unroll 2
        for (int k = 0; k < 75; ++k) {
          float4 u = r1[k], w2 = r2[k];
          #pragma unroll
          for (int rr = 0; rr < 4; ++rr) {
            const float4 tv = *(const float4*)(buf + rr * 300 + 4 * k);
            a[rr]  += u.x * tv.x + u.y * tv.y + u.z * tv.z + u.w * tv.w;
            ev[rr] += w2.x * tv.x + w2.y * tv.y + w2.z * tv.z + w2.w * tv.w;
          }
        }
      } else {
        for (int k = 0; k < HH; ++k) {
          float w1 = ldin(hWo, tid * H3 + k, f32);
          float w2 = ldin(hWo, tid * H3 + HH + k, f32);
          #pragma unroll
          for (int rr = 0; rr < 4; ++rr) {
            a[rr] += w1 * buf[rr * 300 + k];
            ev[rr] += w2 * buf[rr * 300 + k];
          }
        }
      }
      #pragma unroll
      for (int rr = 0; rr < 4; ++rr) {
        A[(size_t)(lb0 + rr) * HH + tid] = a[rr];
        E[(size_t)(lb0 + rr) * HH + tid] = ev[rr];
      }
    }
  }
}

// ---- fused gmax + gf ----
__global__ void k_gmf(const float* hg0, const float* hg1, const void* nhW, const void* rhW,
                      const void* mk, float* Gf0, float* Gf1) {
  bool f32 = is32(mk);
  int task = blockIdx.x >> 2, b = blockIdx.x & 3;
  const float* hg = task ? hg1 : hg0;
  const void* hWo = task ? rhW : nhW;
  float* Gf = task ? Gf1 : Gf0;
  __shared__ __align__(16) float gl[304];
  int tid = threadIdx.x;
  if (tid < HH) {
    float m = -1e30f;
    for (int l = 0; l < LLEN; ++l) m = fmaxf(m, hg[((size_t)l * BB + b) * HH + tid]);
    gl[tid] = m;
  }
  __syncthreads();
  if (tid < HH) {
    float acc = 0.f;
    if (f32) {
      const float4* row = (const float4*)((const float*)hWo + (size_t)tid * H3 + 600);
      #pragma unroll 5
      for (int k = 0; k < 75; ++k) {
        float4 u = row[k];
        const float4 gv = *(const float4*)(gl + 4 * k);
        acc += u.x * gv.x + u.y * gv.y + u.z * gv.z + u.w * gv.w;
      }
    } else {
      for (int k = 0; k < HH; ++k) acc += gl[k] * ldin(hWo, tid * H3 + 600 + k, f32);
    }
    Gf[b * HH + tid] = acc;
  }
}

// ---- pair epilogue v7: 8 j-pairs per block; fully-masked NER blocks skip compute ----
__global__ void __launch_bounds__(256) k_pair7(const float* A0, const float* E0, const float* Gf0,
                                               const void* lg0, const void* lb0_, const void* tW0, const void* tb0,
                                               const float* A1, const float* E1, const float* Gf1,
                                               const void* lg1, const void* lb1_, const void* tW1, const void* tb1,
                                               const void* mk, void* outv) {
  __shared__ float lg_l[304], lb_l[304], tb_l[16];
  __shared__ float tw_l[3616];
  bool f32 = is32(mk);
  int tau = blockIdx.x >> 11;
  int bid = blockIdx.x & 2047;
  int i = bid >> 4;
  int j0 = (bid & 15) << 3;
  int T = tau ? NRR : NTT;
  int diag = tau ? 0 : 1;
  int Toff = tau ? 458752 : 0;
  int tid = threadIdx.x;
  int b = tid >> 6, ln = tid & 63;
  if (diag && j0 + 7 < i) {  // block-uniform: entire 8-j tile below diagonal -> zeros
    if (ln < T) {
      #pragma unroll
      for (int dj = 0; dj < 8; ++dj) {
        size_t obase = (size_t)Toff + ((size_t)(i * LLEN + j0 + dj) * BB + b) * T;
        if (f32) ((float*)outv)[obase + ln] = 0.f;
        else ((u16*)outv)[obase + ln] = 0;
      }
    }
    return;
  }
  const float* A  = tau ? A1 : A0;
  const float* E  = tau ? E1 : E0;
  const float* Gf = tau ? Gf1 : Gf0;
  const void* lgo = tau ? lg1 : lg0;
  const void* lbo = tau ? lb1_ : lb0_;
  const void* tWo = tau ? tW1 : tW0;
  const void* tbo = tau ? tb1 : tb0;
  for (int i2 = tid; i2 < HH; i2 += 256) { lg_l[i2] = ldin(lgo, i2, f32); lb_l[i2] = ldin(lbo, i2, f32); }
  for (int i2 = tid; i2 < T * HH; i2 += 256) tw_l[i2] = ldin(tWo, i2, f32);
  if (tid < T) tb_l[tid] = ldin(tbo, tid, f32);
  __syncthreads();
  const float* ar = A  + (size_t)(i * BB + b) * HH;
  const float* gr = Gf + (size_t)b * HH;
  bool ok4 = ln < 44;
  float a0 = ar[ln]       + gr[ln];
  float a1 = ar[64 + ln]  + gr[64 + ln];
  float a2 = ar[128 + ln] + gr[128 + ln];
  float a3 = ar[192 + ln] + gr[192 + ln];
  float a4 = ok4 ? (ar[256 + ln] + gr[256 + ln]) : 0.f;
  float mi = ldin(mk, i * BB + b, f32);
  for (int dj = 0; dj < 8; ++dj) {
    int jx = j0 + dj;
    const float* er = E + (size_t)(jx * BB + b) * HH;
    float u0 = a0 + er[ln];
    float u1 = a1 + er[64 + ln];
    float u2 = a2 + er[128 + ln];
    float u3 = a3 + er[192 + ln];
    float u4 = ok4 ? (a4 + er[256 + ln]) : 0.f;
    float s1 = ((u0 + u1) + (u2 + u3)) + u4;
    float s2 = ((u0 * u0 + u1 * u1) + (u2 * u2 + u3 * u3)) + u4 * u4;
    #pragma unroll
    for (int d = 1; d < 64; d <<= 1) { s1 += __shfl_xor(s1, d); s2 += __shfl_xor(s2, d); }
    float mean = s1 * (1.f / 300.f);
    float var = s2 * (1.f / 300.f) - mean * mean;
    float rstd = rsqrtf(var + 1e-5f);
    {
      float y;
      y = (u0 - mean) * rstd * lg_l[ln]       + lb_l[ln];       u0 = (y > 0.f) ? y : __expf(y) - 1.f;
      y = (u1 - mean) * rstd * lg_l[64 + ln]  + lb_l[64 + ln];  u1 = (y > 0.f) ? y : __expf(y) - 1.f;
      y = (u2 - mean) * rstd * lg_l[128 + ln] + lb_l[128 + ln]; u2 = (y > 0.f) ? y : __expf(y) - 1.f;
      y = (u3 - mean) * rstd * lg_l[192 + ln] + lb_l[192 + ln]; u3 = (y > 0.f) ? y : __expf(y) - 1.f;
      if (ok4) {
        y = (u4 - mean) * rstd * lg_l[256 + ln] + lb_l[256 + ln];
        u4 = (y > 0.f) ? y : __expf(y) - 1.f;
      }
    }
    float m = mi * ldin(mk, jx * BB + b, f32);
    if (diag && jx < i) m = 0.f;
    size_t obase = (size_t)Toff + ((size_t)(i * LLEN + jx) * BB + b) * T;
    float mine = 0.f;
    for (int t = 0; t < T; ++t) {
      const float* twr = tw_l + t * HH;
      float s = u0 * twr[ln] + u1 * twr[64 + ln] + u2 * twr[128 + ln] + u3 * twr[192 + ln];
      if (ok4) s += u4 * twr[256 + ln];
      s = wsum(s);
      s += tb_l[t];
      float o = m / (1.f + __expf(-s));
      mine = (ln == t) ? o : mine;
    }
    if (ln < T) {
      if (f32) ((float*)outv)[obase + ln] = mine;
      else ((u16*)outv)[obase + ln] = f2bf(mine);
    }
  }
}

// ---- sentinel ----
__global__ void k_sent(const void* mk, const void* xo, void* outv, int hostcode) {
  __shared__ int bad;
  if (threadIdx.x == 0) bad = 0;
  __syncthreads();
  bool f32 = is32(mk);
  for (int i = threadIdx.x; i < 4096; i += 256) {
    float v = ldin(xo, i, f32);
    if (!(v == v) || fabsf(v) > 1e6f) bad = 1;
  }
  __syncthreads();
  if (threadIdx.x == 0) {
    float code = (float)hostcode;
    if (bad) code = fmaxf(code, 88.f);
    if (code > 0.f) {
      if (f32) ((float*)outv)[0] = code;
      else ((u16*)outv)[0] = f2bf(code);
    }
  }
}

extern "C" void kernel_launch(void* const* d_in, const int* in_sizes, int n_in,
                              void* d_out, int out_size, void* d_ws, size_t ws_size,
                              hipStream_t stream) {
  const void* x    = d_in[0];
  const void* mask = d_in[1];
  const void* Wih  = d_in[2];
  const void* bih  = d_in[3];
  const void* Whh  = d_in[4];
  const void* bhh  = d_in[5];
  const void* Wtr  = d_in[6];
  const void* btr  = d_in[7];
  const void* nW   = d_in[8];
  const void* nb   = d_in[9];
  const void* nhW  = d_in[10];
  const void* nhb  = d_in[11];
  const void* ng   = d_in[12];
  const void* nbe  = d_in[13];
  const void* ntW  = d_in[14];
  const void* ntb  = d_in[15];
  const void* rW   = d_in[16];
  const void* rb   = d_in[17];
  const void* rhW  = d_in[18];
  const void* rhb  = d_in[19];
  const void* rg   = d_in[20];
  const void* rbe  = d_in[21];
  const void* rtW  = d_in[22];
  const void* rtb  = d_in[23];
  float* ws = (float*)d_ws;

  static const int exp_sz[24] = {393216, 512, 1152000, 1500, 450000, 1500, 270000, 300,
                                 180000, 300, 270000, 300, 300, 300, 2100, 7,
                                 180000, 300, 270000, 300, 300, 300, 3600, 12};
  int hostcode = 0;
  if (n_in != 24) hostcode = 890;
  else {
    for (int ii = 0; ii < 24; ++ii)
      if (in_sizes[ii] != exp_sz[ii]) { hostcode = 900 + ii; break; }
  }
  if (hostcode == 0 && out_size != 1245184) hostcode = 880;
  if (hostcode == 0 && ws_size < WS_NEED_BYTES) hostcode = 1099;

  dim3 gc(512, 6);
  k_canon<<<gc, 256, 0, stream>>>(x, mask, Wih, bih, Whh, bhh, Wtr, btr, ws);
  k_pre2<<<128, 256, 0, stream>>>(x, Wih, mask, ws + C_X, ws + C_WIH, ws + F_BIH, ws + F_PRE);
  k_scanA<<<128, 512, 0, stream>>>(ws + F_PRE, (const float2*)(ws + C_WHH2), (const float2*)(ws + C_WTR2),
                                   ws + F_BTR, ws + F_HNER, ws + F_HRE, ws + F_HSH, ws + F_AUX, ws);
  k_scanB<<<128, 512, 0, stream>>>(ws + F_PRE, (const float2*)(ws + C_WHH2), (const float2*)(ws + C_WTR2),
                                   ws + F_BTR, ws + F_HNER, ws + F_HRE, ws + F_HSH, ws + F_AUX);
  k_post<<<512, 320, 0, stream>>>(ws + F_HSH, ws + F_HNER, ws + F_HRE,
                                  nW, nb, rW, rb, nhW, nhb, rhW, rhb, mask,
                                  ws + F_HG0, ws + F_HG1, ws + F_A0, ws + F_E0, ws + F_A1, ws + F_E1);
  k_gmf<<<8, 320, 0, stream>>>(ws + F_HG0, ws + F_HG1, nhW, rhW, mask, ws + F_GF0, ws + F_GF1);
  k_pair7<<<4096, 256, 0, stream>>>(ws + F_A0, ws + F_E0, ws + F_GF0, ng, nbe, ntW, ntb,
                                    ws + F_A1, ws + F_E1, ws + F_GF1, rg, rbe, rtW, rtb,
                                    mask, d_out);
  k_sent<<<1, 256, 0, stream>>>(mask, x, d_out, hostcode);
}

// Round 11
// 1327.797 us; speedup vs baseline: 1.0969x; 1.0296x over previous
//
#include <hip/hip_runtime.h>

#define LLEN 128
#define BB 4
#define DD 768
#define HH 300
#define G5 1500
#define H3 900
#define NTT 7
#define NRR 12
#define NCHB 10
#define RPB 150
#define OPB 30

// ---- fp32 workspace layout (ws as float*) ----
#define C_WIH  0
#define C_X    1152000
#define C_WHH2 1545216
#define C_WTR2 1995216
#define F_BIH  2265216
#define F_BTR  2266720
#define F_PRE  2267040
// PRE region reused after the scan:
#define F_HG0  (F_PRE)
#define F_HG1  (F_PRE+153600)
#define F_A0   (F_PRE+307200)
#define F_E0   (F_PRE+460800)
#define F_GF0  (F_PRE+616832)
#define F_GF1  (F_PRE+618048)
// beyond PRE:
#define F_HNER (F_PRE+768000)
#define F_HRE  (F_HNER+153600)
#define F_HSH  (F_HRE+153600)
#define F_A1   0
#define F_E1   153600
#define F_AUX  (F_HSH+153600)
// scanA exchange buffers in the scan-dead C_WIH region [0,1152000):
//   partials: part(buf,b) = buf*96000 + b*24000: 1500 rows x 16 floats
//   (cols 0..9 partial sums, 10..11 zero pads, 12..15 never read) [R6/R9-proven]
//   c_pub: 192000 + (buf*4+b)*304
#define P_CPUB 192000
// aux per-batch (AUXB floats): scanB selftest words (tst @ gb+2240, seflag @ gb+2272)
#define AUXB   2432
#define AUX_FL 9728
// int area (2048 ints, zeroed per launch with AGENT stores — these lines are
// touched EXCLUSIVELY by agent-scope ops by every kernel, so LLC is authoritative):
//   chunk0 (scanA): claim [0,32); per batch b at [32+64b): slots[0..15], abort@+24
//   chunk1 (scanB): claim [640,672); per batch b at [672+64b): slotsA[16] slotsB[16] atf[5]
//   done[4] @ [1536,1540)  (scanA completion counters; scanB skips batch iff ==NCHB)
#define WS_NEED_BYTES ((size_t)(F_AUX+11776)*4)

typedef unsigned short u16;
typedef unsigned int u32;
typedef float f4 __attribute__((ext_vector_type(4)));
typedef int i4 __attribute__((ext_vector_type(4)));

__device__ __forceinline__ float bf2f(u16 u) {
  union { u32 i; float f; } v; v.i = ((u32)u) << 16; return v.f;
}
__device__ __forceinline__ float bflo(u32 u) {
  union { u32 i; float f; } v; v.i = u << 16; return v.f;
}
__device__ __forceinline__ float bfhi(u32 u) {
  union { u32 i; float f; } v; v.i = u & 0xffff0000u; return v.f;
}
__device__ __forceinline__ u16 f2bf(float f) {
  union { float f; u32 i; } v; v.f = f;
  u32 r = v.i + 0x7fffu + ((v.i >> 16) & 1u);
  return (u16)(r >> 16);
}
__device__ __forceinline__ float ldin(const void* p, int i, bool f32) {
  return f32 ? ((const float*)p)[i] : bf2f(((const u16*)p)[i]);
}
__device__ __forceinline__ bool is32(const void* mk) {
  return ((const u16*)mk)[0] == 0;
}
__device__ __forceinline__ float wsum(float x) {
  #pragma unroll
  for (int d = 1; d < 64; d <<= 1) x += __shfl_xor(x, d);
  return x;
}
// ---- agent-scope (LLC) accessors ----
__device__ __forceinline__ void astore(float* p, float v) {
  union { float f; int i; } u; u.f = v;
  __hip_atomic_store((int*)p, u.i, __ATOMIC_RELAXED, __HIP_MEMORY_SCOPE_AGENT);
}
// proven agent-scope inter-block barrier (scanB selftest/claim only)
__device__ __forceinline__ void gbar(int* flag, int tid, int target) {
  __syncthreads();
  if (tid == 0) {
    __builtin_amdgcn_s_waitcnt(0);
    __hip_atomic_fetch_add(flag, 1, __ATOMIC_RELAXED, __HIP_MEMORY_SCOPE_AGENT);
    int it = 0;
    while (__hip_atomic_load(flag, __ATOMIC_RELAXED, __HIP_MEMORY_SCOPE_AGENT) < target) {
      __builtin_amdgcn_s_sleep(1);
      if (++it > 50000) break;
    }
  }
  __syncthreads();
}
// ---- scoped exchange primitives (mode 1 = XCD/L2, mode 0 = agent/LLC) ----
__device__ __forceinline__ f4 ld4x(const f4* p, int mode) {
  f4 v;
  if (mode)
    asm volatile("global_load_dwordx4 %0, %1, off sc0\n\ts_waitcnt vmcnt(0)"
                 : "=v"(v) : "v"(p) : "memory");
  else
    asm volatile("global_load_dwordx4 %0, %1, off sc0 sc1\n\ts_waitcnt vmcnt(0)"
                 : "=v"(v) : "v"(p) : "memory");
  return v;
}
__device__ __forceinline__ float ld1x(const float* p, int mode) {
  float v;
  if (mode)
    asm volatile("global_load_dword %0, %1, off sc0\n\ts_waitcnt vmcnt(0)"
                 : "=v"(v) : "v"(p) : "memory");
  else
    asm volatile("global_load_dword %0, %1, off sc0 sc1\n\ts_waitcnt vmcnt(0)"
                 : "=v"(v) : "v"(p) : "memory");
  return v;
}
__device__ __forceinline__ int ldix(const int* p, int mode) {
  int v;
  if (mode)
    asm volatile("global_load_dword %0, %1, off sc0\n\ts_waitcnt vmcnt(0)"
                 : "=v"(v) : "v"(p) : "memory");
  else
    asm volatile("global_load_dword %0, %1, off sc0 sc1\n\ts_waitcnt vmcnt(0)"
                 : "=v"(v) : "v"(p) : "memory");
  return v;
}
__device__ __forceinline__ void exst(float* p, float v, int mode) {
  if (mode) *p = v; else astore(p, v);
}
// 9 overlapped dwordx4 from one 64B-aligned base (3 rows x 3 quads), L2-local
__device__ __forceinline__ void ld9(const float* base,
                                    f4& a0, f4& a1, f4& a2, f4& a3, f4& a4,
                                    f4& a5, f4& a6, f4& a7, f4& a8) {
  asm volatile(
    "global_load_dwordx4 %0, %9, off sc0\n\t"
    "global_load_dwordx4 %1, %9, off offset:16 sc0\n\t"
    "global_load_dwordx4 %2, %9, off offset:32 sc0\n\t"
    "global_load_dwordx4 %3, %9, off offset:64 sc0\n\t"
    "global_load_dwordx4 %4, %9, off offset:80 sc0\n\t"
    "global_load_dwordx4 %5, %9, off offset:96 sc0\n\t"
    "global_load_dwordx4 %6, %9, off offset:128 sc0\n\t"
    "global_load_dwordx4 %7, %9, off offset:144 sc0\n\t"
    "global_load_dwordx4 %8, %9, off offset:160 sc0\n\t"
    "s_waitcnt vmcnt(0)"
    : "=&v"(a0), "=&v"(a1), "=&v"(a2), "=&v"(a3), "=&v"(a4),
      "=&v"(a5), "=&v"(a6), "=&v"(a7), "=&v"(a8)
    : "v"(base) : "memory");
}
// poll all 10 arrival slots (12 loaded; last 2 zero padding)
__device__ __forceinline__ int poll10(const int* slots, int tok, int mode) {
  i4 a, b, c;
  if (mode)
    asm volatile("global_load_dwordx4 %0, %3, off sc0\n\t"
                 "global_load_dwordx4 %1, %4, off sc0\n\t"
                 "global_load_dwordx4 %2, %5, off sc0\n\t"
                 "s_waitcnt vmcnt(0)"
                 : "=&v"(a), "=&v"(b), "=&v"(c)
                 : "v"(slots), "v"(slots + 4), "v"(slots + 8) : "memory");
  else
    asm volatile("global_load_dwordx4 %0, %3, off sc0 sc1\n\t"
                 "global_load_dwordx4 %1, %4, off sc0 sc1\n\t"
                 "global_load_dwordx4 %2, %5, off sc0 sc1\n\t"
                 "s_waitcnt vmcnt(0)"
                 : "=&v"(a), "=&v"(b), "=&v"(c)
                 : "v"(slots), "v"(slots + 4), "v"(slots + 8) : "memory");
  return (a.x >= tok) & (a.y >= tok) & (a.z >= tok) & (a.w >= tok) &
         (b.x >= tok) & (b.y >= tok) & (b.z >= tok) & (b.w >= tok) &
         (c.x >= tok) & (c.y >= tok);
}
// slot barrier (scanB, proven): drain + sync + tid0 token store; wave 0 polls
__device__ __forceinline__ void sbar(int* slots, int ch, int tok, int tid, int mode) {
  asm volatile("s_waitcnt vmcnt(0)" ::: "memory");
  __syncthreads();
  if (tid == 0) {
    if (mode) slots[ch] = tok;
    else __hip_atomic_store(slots + ch, tok, __ATOMIC_RELAXED, __HIP_MEMORY_SCOPE_AGENT);
  }
  if (tid < 64) {
    int it = 0;
    while (!poll10(slots, tok, mode)) {
      __builtin_amdgcn_s_sleep(1);
      if (++it > 5000) break;
    }
  }
  __syncthreads();
}
// scanA slot barrier: AGENT-scope tokens (LLC-exclusive lines, stale-proof) +
// L2-local payload (covered by drain-before-token). Timeout -> abort propagation.
__device__ __forceinline__ void sbarA(int* slots, int* abf, int ch, int tok, int tid,
                                      volatile int* s_fail) {
  asm volatile("s_waitcnt vmcnt(0)" ::: "memory");  // payload drained to our L2
  __syncthreads();
  if (tid == 0)
    __hip_atomic_store(slots + ch, tok, __ATOMIC_RELAXED, __HIP_MEMORY_SCOPE_AGENT);
  if (tid < 64) {
    int it = 0;
    while (!poll10(slots, tok, 0)) {   // mode 0 = agent/LLC reads
      __builtin_amdgcn_s_sleep(1);
      ++it;
      if ((it & 255) == 0 &&
          __hip_atomic_load(abf, __ATOMIC_RELAXED, __HIP_MEMORY_SCOPE_AGENT) != 0) {
        *s_fail = 1; break;
      }
      if (it > 8000) {
        __hip_atomic_store(abf, 1, __ATOMIC_RELAXED, __HIP_MEMORY_SCOPE_AGENT);
        *s_fail = 1; break;
      }
    }
  }
  __syncthreads();
}
// claim (xcd, rank) via HW_REG_XCC_ID + grid rendezvous (agent-only lines)
__device__ __forceinline__ int claim_bc(int* cl, int nb) {
  unsigned xcd;
  asm volatile("s_getreg_b32 %0, hwreg(HW_REG_XCC_ID)" : "=s"(xcd));
  xcd &= 7u;
  int rank = __hip_atomic_fetch_add(cl + xcd, 1, __ATOMIC_RELAXED, __HIP_MEMORY_SCOPE_AGENT);
  __hip_atomic_fetch_add(cl + 8, 1, __ATOMIC_RELAXED, __HIP_MEMORY_SCOPE_AGENT);
  int it = 0;
  while (__hip_atomic_load(cl + 8, __ATOMIC_RELAXED, __HIP_MEMORY_SCOPE_AGENT) < nb) {
    __builtin_amdgcn_s_sleep(2);
    if (++it > 100000) break;
  }
  int base = 0;
  for (unsigned x = 0; x < xcd; ++x)
    base += __hip_atomic_load(cl + x, __ATOMIC_RELAXED, __HIP_MEMORY_SCOPE_AGENT) / NCHB;
  int cnt = __hip_atomic_load(cl + xcd, __ATOMIC_RELAXED, __HIP_MEMORY_SCOPE_AGENT);
  int slot = base + rank / NCHB;
  return (rank < (cnt / NCHB) * NCHB && slot < BB) ? (slot * 16 + rank % NCHB) : -1;
}

// ---- canonicalize + fused pre-GEMM (pre reads bf16 inputs directly) ----
__global__ void k_canon(const void* xo, const void* mk, const void* Wih, const void* bih,
                        const void* Whh, const void* bhh, const void* Wtr, const void* btr,
                        float* ws) {
  __shared__ __align__(16) float xl[8 * DD];
  bool f32 = is32(mk);
  int piece = blockIdx.y;
  int i0 = blockIdx.x * 256 + threadIdx.x;
  int stride = gridDim.x * 256;
  switch (piece) {
    case 0: for (int i = i0; i < 225000; i += stride) {   // W2hh repack
      int k2 = i / G5, out = i - k2 * G5;
      float2 v;
      v.x = ldin(Whh, out * HH + 2 * k2, f32);
      v.y = ldin(Whh, out * HH + 2 * k2 + 1, f32);
      ((float2*)(ws + C_WHH2))[i] = v;
    } break;
    case 1: for (int i = i0; i < 135000; i += stride) {   // W2tr repack
      int k2 = i / HH, out = i - k2 * HH;
      float2 v;
      v.x = ldin(Wtr, out * H3 + 2 * k2, f32);
      v.y = ldin(Wtr, out * H3 + 2 * k2 + 1, f32);
      ((float2*)(ws + C_WTR2))[i] = v;
    } break;
    case 2: for (int i = i0; i < 1824; i += stride) {     // bias sums
      if (i < 1504) ws[F_BIH + i] = (i < G5) ? ldin(bih, i, f32) + ldin(bhh, i, f32) : 0.f;
      else { int j = i - 1504; ws[F_BTR + j] = (j < HH) ? ldin(btr, j, f32) : 0.f; }
    } break;
    case 3: for (int i = i0; i < 11776; i += stride) {    // aux zero
      if (i < AUX_FL) ws[F_AUX + i] = 0.f;                // float aux (selftest words)
      else {                                               // int control area: AGENT zero
        int* ip = (int*)(ws + F_AUX + AUX_FL);
        __hip_atomic_store(ip + (i - AUX_FL), 0, __ATOMIC_RELAXED, __HIP_MEMORY_SCOPE_AGENT);
      }
    } break;
    case 4: {  // pre = x @ W_ih^T + (b_ih + b_hh); direct bf16 reads (bit-identical)
      if (blockIdx.x >= 128) return;
      int tid = threadIdx.x;
      int lb0 = ((int)blockIdx.x >> 1) * 8;
      int half = blockIdx.x & 1;
      float* pre = ws + F_PRE;
      if (f32) {
        const float* X = (const float*)xo;
        for (int e = tid; e < 8 * DD; e += 256) xl[e] = X[(size_t)lb0 * DD + e];
      } else {
        const u16* X = (const u16*)xo;
        for (int e = tid; e < 8 * DD; e += 256) xl[e] = bf2f(X[(size_t)lb0 * DD + e]);
      }
      __syncthreads();
      for (int j = half * 750 + tid; j < half * 750 + 750; j += 256) {
        float acc[8] = {0.f, 0.f, 0.f, 0.f, 0.f, 0.f, 0.f, 0.f};
        if (f32) {
          const float4* w = (const float4*)((const float*)Wih + (size_t)j * DD);
          #pragma unroll 2
          for (int k = 0; k < DD / 4; ++k) {
            float4 u = w[k];
            #pragma unroll
            for (int r = 0; r < 8; ++r) {
              const float4 p = *(const float4*)(xl + r * DD + k * 4);
              acc[r] += u.x * p.x + u.y * p.y + u.z * p.z + u.w * p.w;
            }
          }
        } else {
          const u16* wr = (const u16*)Wih + (size_t)j * DD;
          #pragma unroll 2
          for (int k = 0; k < DD; k += 8) {
            uint4 wv = *(const uint4*)(wr + k);
            float w0 = bflo(wv.x), w1 = bfhi(wv.x), w2 = bflo(wv.y), w3 = bfhi(wv.y);
            float w4 = bflo(wv.z), w5 = bfhi(wv.z), w6 = bflo(wv.w), w7 = bfhi(wv.w);
            #pragma unroll
            for (int r = 0; r < 8; ++r) {
              const float4 p1 = *(const float4*)(xl + r * DD + k);
              const float4 p2 = *(const float4*)(xl + r * DD + k + 4);
              acc[r] += w0 * p1.x + w1 * p1.y + w2 * p1.z + w3 * p1.w
                      + w4 * p2.x + w5 * p2.y + w6 * p2.z + w7 * p2.w;
            }
          }
        }
        float bias = ldin(bih, j, f32) + ldin(bhh, j, f32);
        #pragma unroll
        for (int r = 0; r < 8; ++r) pre[(size_t)(lb0 + r) * G5 + j] = acc[r] + bias;
      }
    } break;
  }
}

// ---- scanA: R9/R10-proven 1-barrier/step (unchanged) ----
__global__ void __launch_bounds__(512, 2) k_scanA(const float* pre, const float2* W2h, const float2* W2t,
                                                  const float* btrf, float* hner, float* hre, float* hsh,
                                                  float* aux, float* xw) {
  __shared__ __align__(16) float ga_l[1504];
  __shared__ __align__(16) float vv_l[1204];
  __shared__ __align__(16) float tnh_l[304];
  __shared__ __align__(16) float cat_l[904];
  __shared__ __align__(16) float ci_l[304];
  __shared__ __align__(16) float ps[512];
  __shared__ __align__(16) float h_loc[32];
  __shared__ int s_bc;
  __shared__ int s_fail;
  int tid = threadIdx.x;
  int* ibase = (int*)(aux + AUX_FL);
  if (tid == 0) { s_bc = claim_bc(ibase, (int)gridDim.x); s_fail = 0; }
  __syncthreads();
  int bc = s_bc;
  if (bc < 0) return;
  int b = bc >> 4, ch = bc & 15;
  int* slots = ibase + 32 + b * 64;
  int* abf   = slots + 24;
  int* done  = ibase + 1536;

  // zero pad columns (10,11) of both partial buffers (plain stores to our L2;
  // covered for readers by the drain in the first sbarA)
  if (ch < 2) {
    float* pb0 = xw + (size_t)ch * 96000 + b * 24000;
    for (int i = tid; i < 3000; i += 512) {
      int row = i >> 1, col = 10 + (i & 1);
      pb0[row * 16 + col] = 0.f;
    }
  }

  int o0 = 3 * tid;
  float2 wh2[45];
  if (tid < 500) {
    #pragma unroll
    for (int j = 0; j < 3; ++j)
      #pragma unroll
      for (int kk = 0; kk < 15; ++kk)
        wh2[j * 15 + kk] = W2h[(size_t)(ch * 15 + kk) * G5 + (o0 + j)];
  }
  int o2 = tid % OPB, jj = tid / OPB;
  float2 wt[29];
  int k2b = jj * 29;
  int k2e = (k2b + 29 < 450) ? (k2b + 29) : 450;
  int nk2 = k2e - k2b;
  if (tid < 480) {
    const float2* wp = W2t + (size_t)k2b * HH + (ch * OPB + o2);
    #pragma unroll
    for (int q = 0; q < 29; ++q) if (q < nk2) wt[q] = wp[(size_t)q * HH];
  }
  float pv0 = 0.f, pv1 = 0.f, pv2 = 0.f;
  if (tid < 500) {
    const float* pr = pre + (size_t)b * G5 + o0;
    pv0 = pr[0]; pv1 = pr[1]; pv2 = pr[2];
  }
  __syncthreads();

  for (int t = 0; t < LLEN; ++t) {
    int buf = t & 1;
    float* pb = xw + (size_t)buf * 96000 + b * 24000;
    if (t > 0) {
      if (tid < 500) {
        float2 h2[15];
        #pragma unroll
        for (int kk = 0; kk < 15; ++kk) h2[kk] = *(const float2*)(h_loc + 2 * kk);
        #pragma unroll
        for (int j = 0; j < 3; ++j) {
          float acc = 0.f;
          #pragma unroll
          for (int kk = 0; kk < 15; ++kk)
            acc += wh2[j * 15 + kk].x * h2[kk].x + wh2[j * 15 + kk].y * h2[kk].y;
          pb[(size_t)(o0 + j) * 16 + ch] = acc;
        }
      }
      sbarA(slots, abf, ch, t, tid, &s_fail);   // the ONLY inter-block barrier
      if (s_fail) return;                        // desync: scanB redoes this batch
      if (tid < 500) {
        f4 a0, a1, a2, a3, a4, a5, a6, a7, a8;
        ld9(pb + (size_t)o0 * 16, a0, a1, a2, a3, a4, a5, a6, a7, a8);
        ga_l[o0]     = pv0 + (((a0.x + a0.y) + (a0.z + a0.w)) +
                              ((a1.x + a1.y) + (a1.z + a1.w)) +
                              ((a2.x + a2.y) + (a2.z + a2.w)));
        ga_l[o0 + 1] = pv1 + (((a3.x + a3.y) + (a3.z + a3.w)) +
                              ((a4.x + a4.y) + (a4.z + a4.w)) +
                              ((a5.x + a5.y) + (a5.z + a5.w)));
        ga_l[o0 + 2] = pv2 + (((a6.x + a6.y) + (a6.z + a6.w)) +
                              ((a7.x + a7.y) + (a7.z + a7.w)) +
                              ((a8.x + a8.y) + (a8.z + a8.w)));
      }
      if (tid < 75) {
        const float* cp = xw + P_CPUB + (size_t)(((t - 1) & 1) * 4 + b) * 304;
        f4 v = ld4x((const f4*)cp + tid, 1);
        *(f4*)(ci_l + 4 * tid) = v;
      }
    } else {
      if (tid < 500) { ga_l[o0] = pv0; ga_l[o0 + 1] = pv1; ga_l[o0 + 2] = pv2; }
    }
    __syncthreads();
    if (tid < HH) tnh_l[tid] = tanhf(ga_l[tid]);
    {
      int w = tid >> 6, ln = tid & 63;
      if (w >= 4) {
        int c = w - 3;
        const float* g = ga_l + c * 300;
        int e0 = ln * 5;
        float ex0 = 0.f, ex1 = 0.f, ex2 = 0.f, ex3 = 0.f, ex4 = 0.f;
        if (ln < 60) {
          ex0 = __expf(g[e0]); ex1 = __expf(g[e0 + 1]); ex2 = __expf(g[e0 + 2]);
          ex3 = __expf(g[e0 + 3]); ex4 = __expf(g[e0 + 4]);
        }
        float p = ((ex0 + ex1) + (ex2 + ex3)) + ex4;
        float inc = p;
        #pragma unroll
        for (int d = 1; d < 64; d <<= 1) { float o = __shfl_up(inc, d); if (ln >= d) inc += o; }
        float S = __shfl(inc, 59);
        float invS = 1.f / S;
        float run = inc - p;
        if (ln < 60) {
          float* vv = vv_l + (c - 1) * 300 + e0;
          run += ex0; vv[0] = run * invS;
          run += ex1; vv[1] = run * invS;
          run += ex2; vv[2] = run * invS;
          run += ex3; vv[3] = run * invS;
          run += ex4; vv[4] = run * invS;
        }
      }
    }
    if (t + 1 < LLEN && tid < 500) {
      const float* pr = pre + ((size_t)(t + 1) * BB + b) * G5 + o0;
      pv0 = pr[0]; pv1 = pr[1]; pv2 = pr[2];
    }
    __syncthreads();
    if (tid < HH) {
      float c = tnh_l[tid];
      float v0 = vv_l[tid], v1 = vv_l[300 + tid], v2 = vv_l[600 + tid], v3 = vv_l[900 + tid];
      float eg_cin = 1.f - v0, rg_cin = v1, eg_c = 1.f - v2, rg_c = v3;
      float ci = (t > 0) ? ci_l[tid] : 0.f;
      float ov_c = rg_c * eg_c;
      float up_c = rg_c - ov_c, dn_c = eg_c - ov_c;
      float ov_i = rg_cin * eg_cin;
      float up_i = rg_cin - ov_i, dn_i = eg_cin - ov_i;
      float share = ov_i * ci + ov_c * c;
      float c_re  = up_i * ci + up_c * c + share;
      float c_ner = dn_i * ci + dn_c * c + share;
      cat_l[tid] = c_re; cat_l[HH + tid] = c_ner; cat_l[2 * HH + tid] = share;
      int sb = ch * OPB;
      if (tid >= sb && tid < sb + OPB) {
        size_t ob = ((size_t)t * BB + b) * HH + tid;
        hner[ob] = tanhf(c_ner); hre[ob] = tanhf(c_re); hsh[ob] = tanhf(share);
      }
    }
    __syncthreads();
    if (tid < 480) {
      float acc = 0.f;
      #pragma unroll
      for (int q = 0; q < 29; ++q)
        if (q < nk2) acc += wt[q].x * cat_l[2 * (k2b + q)] + wt[q].y * cat_l[2 * (k2b + q) + 1];
      ps[tid] = acc;
    }
    __syncthreads();
    if (tid < OPB) {
      float co = btrf[ch * OPB + tid];
      #pragma unroll
      for (int q = 0; q < 16; ++q) co += ps[q * OPB + tid];
      h_loc[tid] = tanhf(co);
      float* cp = xw + P_CPUB + (size_t)(buf * 4 + b) * 304;
      cp[ch * OPB + tid] = co;
    }
    __syncthreads();
  }
  // completed with zero timeouts -> publish; scanB (stream-serialized) skips batch
  if (tid == 0 && s_fail == 0)
    __hip_atomic_fetch_add(done + b, 1, __ATOMIC_RELAXED, __HIP_MEMORY_SCOPE_AGENT);
}

// ---- scanB: R4-proven 2-barrier kernel; fast-exit when scanA handled all batches ----
__global__ void __launch_bounds__(512, 2) k_scanB(const float* pre, const float2* W2h, const float2* W2t,
                                                  const float* btrf, float* hner, float* hre, float* hsh,
                                                  float* aux) {
  __shared__ __align__(16) float h_l[304];
  __shared__ __align__(16) float ci_l[304];
  __shared__ __align__(16) float ga_l[1504];
  __shared__ __align__(16) float cat_l[904];
  __shared__ __align__(16) float ps[512];
  __shared__ __align__(16) float sums_l[8];
  __shared__ float exv[160];
  __shared__ int s_bc, s_mode, s_skip;
  int tid = threadIdx.x;
  int* ibase = (int*)(aux + AUX_FL);
  int* done = ibase + 1536;
  // pre-claim fast path: if scanA completed every batch, skip the rendezvous entirely
  if (tid == 0) {
    int ok = 1;
    #pragma unroll
    for (int q = 0; q < BB; ++q)
      ok &= (__hip_atomic_load(done + q, __ATOMIC_RELAXED, __HIP_MEMORY_SCOPE_AGENT) == NCHB);
    s_skip = ok;
  }
  __syncthreads();
  if (s_skip) return;
  int* cl2 = ibase + 640;
  if (tid == 0) s_bc = claim_bc(cl2, (int)gridDim.x);
  __syncthreads();
  int bc = s_bc;
  if (bc < 0) return;
  int b = bc >> 4, ch = bc & 15;
  if (tid == 0)
    s_skip = (__hip_atomic_load(done + b, __ATOMIC_RELAXED, __HIP_MEMORY_SCOPE_AGENT) == NCHB);
  __syncthreads();
  if (s_skip) return;  // scanA fully produced this batch
  int s = ch >> 1;
  int r0 = ch * RPB;
  float* gb   = aux + b * AUXB;
  float* cb   = gb + 1504;
  float* hb   = gb + 1808;
  float* sums = gb + 2112;
  int* slotsA = ibase + 672 + b * 64;
  int* slotsB = slotsA + 16;
  int* atf    = slotsA + 32;

  // ---- selftest (R4-proven form) ----
  {
    float* tst = gb + 2240;
    int* seflag = (int*)(gb + 2272);
    if (ch == 0 && tid == 0) tst[0] = 1.0f;
    gbar(atf + 0, tid, NCHB);
    if (tid == 0) { float w1 = ld1x(tst, 1); (void)w1; }
    gbar(atf + 1, tid, NCHB);
    if (ch == 0 && tid == 0) { tst[0] = 2.0f; __builtin_amdgcn_s_waitcnt(0); }
    if (ch == 1 && tid == 0)
      __hip_atomic_fetch_add(seflag, 1, __ATOMIC_RELAXED, __HIP_MEMORY_SCOPE_WORKGROUP);
    gbar(atf + 2, tid, NCHB);
    if (tid == 0) {
      float w2 = ld1x(tst, 1);
      int fv = ldix(seflag, 1);
      if (w2 != 2.0f || fv != 1)
        __hip_atomic_fetch_or(atf + 4, 1, __ATOMIC_RELAXED, __HIP_MEMORY_SCOPE_AGENT);
    }
    gbar(atf + 3, tid, NCHB);
    if (tid == 0)
      s_mode = (__hip_atomic_load(atf + 4, __ATOMIC_RELAXED, __HIP_MEMORY_SCOPE_AGENT) == 0) ? 1 : 0;
    __syncthreads();
  }
  int mode = s_mode;

  int j = tid / RPB, r = tid - j * RPB;
  int o2 = tid % OPB, jj = tid / OPB;
  int kb = j * 100;

  float2 wh[50];
  if (tid < 450) {
    const float2* wp = W2h + (size_t)(j * 50) * G5 + (r0 + r);
    #pragma unroll
    for (int kk = 0; kk < 50; ++kk) wh[kk] = wp[(size_t)kk * G5];
  }
  float2 wt[29];
  int k2b = jj * 29;
  int k2e = (k2b + 29 < 450) ? (k2b + 29) : 450;
  int nk2 = k2e - k2b;
  if (tid < 480) {
    const float2* wp = W2t + (size_t)k2b * HH + (ch * OPB + o2);
    #pragma unroll
    for (int q = 0; q < 29; ++q) if (q < nk2) wt[q] = wp[(size_t)q * HH];
  }
  float pv = 0.f;
  if (tid < RPB) pv = pre[(size_t)b * G5 + r0 + tid];
  __syncthreads();

  for (int t = 0; t < LLEN; ++t) {
    if (t > 0) {
      if (tid < 75)       { f4 v = ld4x((const f4*)hb + tid, mode); *(f4*)(h_l + 4 * tid) = v; }
      else if (tid < 150) { int q = tid - 75; f4 v = ld4x((const f4*)cb + q, mode); *(f4*)(ci_l + 4 * q) = v; }
      __syncthreads();
    }
    if (tid < 450) {
      float acc = (j == 0) ? pv : 0.f;
      if (t > 0) {
        #pragma unroll
        for (int kk = 0; kk < 50; ++kk)
          acc += wh[kk].x * h_l[kb + 2 * kk] + wh[kk].y * h_l[kb + 2 * kk + 1];
      }
      ps[tid] = acc;
    }
    __syncthreads();
    if (tid < RPB) {
      float g = ps[tid] + ps[RPB + tid] + ps[2 * RPB + tid];
      if (s == 0) exst(gb + r0 + tid, tanhf(g), mode);
      else exv[tid] = __expf(g);
    }
    if (s > 0) {
      __syncthreads();
      if (tid < 30) {
        int base2 = tid * 5;
        float e0 = exv[base2], e1 = exv[base2 + 1], e2 = exv[base2 + 2],
              e3 = exv[base2 + 3], e4 = exv[base2 + 4];
        float p = ((e0 + e1) + (e2 + e3)) + e4;
        float inc = p;
        #pragma unroll
        for (int d = 1; d < 32; d <<= 1) { float o = __shfl_up(inc, d); if (tid >= d) inc += o; }
        float tot = __shfl(inc, 29);
        float run = inc - p;
        run += e0; exst(gb + r0 + base2,     run, mode);
        run += e1; exst(gb + r0 + base2 + 1, run, mode);
        run += e2; exst(gb + r0 + base2 + 2, run, mode);
        run += e3; exst(gb + r0 + base2 + 3, run, mode);
        run += e4; exst(gb + r0 + base2 + 4, run, mode);
        if (tid == 0) exst(sums + (ch - 2), tot, mode);
      }
    }
    sbar(slotsA, ch, t + 1, tid, mode);
    if (tid < 375)      { f4 v = ld4x((const f4*)gb + tid, mode); *(f4*)(ga_l + 4 * tid) = v; }
    else if (tid < 377) { int q = tid - 375; f4 v = ld4x((const f4*)sums + q, mode); *(f4*)(sums_l + 4 * q) = v; }
    float pvn = 0.f;
    if (t + 1 < LLEN && tid < RPB) pvn = pre[((size_t)(t + 1) * BB + b) * G5 + r0 + tid];
    __syncthreads();
    if (tid < HH) {
      float c = ga_l[tid];
      float v[4];
      #pragma unroll
      for (int s1 = 0; s1 < 4; ++s1) {
        float raw = ga_l[(s1 + 1) * HH + tid];
        float off = (tid >= RPB) ? sums_l[2 * s1] : 0.f;
        float S = sums_l[2 * s1] + sums_l[2 * s1 + 1];
        v[s1] = (raw + off) / S;
      }
      float eg_cin = 1.f - v[0], rg_cin = v[1], eg_c = 1.f - v[2], rg_c = v[3];
      float ci = (t > 0) ? ci_l[tid] : 0.f;
      float ov_c = rg_c * eg_c;
      float up_c = rg_c - ov_c, dn_c = eg_c - ov_c;
      float ov_i = rg_cin * eg_cin;
      float up_i = rg_cin - ov_i, dn_i = eg_cin - ov_i;
      float share = ov_i * ci + ov_c * c;
      float c_re  = up_i * ci + up_c * c + share;
      float c_ner = dn_i * ci + dn_c * c + share;
      cat_l[tid] = c_re; cat_l[HH + tid] = c_ner; cat_l[2 * HH + tid] = share;
      int sb = ch * OPB;
      if (tid >= sb && tid < sb + OPB) {
        size_t ob = ((size_t)t * BB + b) * HH + tid;
        hner[ob] = tanhf(c_ner); hre[ob] = tanhf(c_re); hsh[ob] = tanhf(share);
      }
    }
    __syncthreads();
    if (tid < 480) {
      float acc = 0.f;
      #pragma unroll
      for (int q = 0; q < 29; ++q)
        if (q < nk2) acc += wt[q].x * cat_l[2 * (k2b + q)] + wt[q].y * cat_l[2 * (k2b + q) + 1];
      ps[tid] = acc;
    }
    __syncthreads();
    if (tid < OPB) {
      float co = btrf[ch * OPB + tid];
      #pragma unroll
      for (int q = 0; q < 16; ++q) co += ps[q * OPB + tid];
      exst(cb + ch * OPB + tid, co, mode);
      exst(hb + ch * OPB + tid, tanhf(co), mode);
    }
    if (t + 1 < LLEN) sbar(slotsB, ch, t + 1, tid, mode);
    pv = pvn;
  }
}

// ---- fused h_glob + A/E features ----
__global__ void k_post(const float* hsh, const float* hner, const float* hre,
                       const void* nW, const void* nb, const void* rW, const void* rb,
                       const void* nhW, const void* nhb, const void* rhW, const void* rhb,
                       const void* mk, float* hg0, float* hg1,
                       float* A0, float* E0, float* A1, float* E1) {
  bool f32 = is32(mk);
  int role = blockIdx.x >> 8;   // 0 = glob, 1 = feat
  int sub  = blockIdx.x & 255;
  int task = sub >> 7;
  int lb0 = (sub & 127) * 4;
  __shared__ __align__(16) float buf[2400];
  int tid = threadIdx.x;
  if (role == 0) {
    const float* tsk = task ? hre : hner;
    const void* gWo = task ? rW : nW;
    const void* gbo = task ? rb : nb;
    float* hg = task ? hg1 : hg0;
    for (int e = tid; e < 2400; e += 320) {
      int rr = e / 600, c = e - rr * 600;
      buf[e] = (c < HH) ? hsh[(size_t)(lb0 + rr) * HH + c] : tsk[(size_t)(lb0 + rr) * HH + (c - HH)];
    }
    __syncthreads();
    if (tid < HH) {
      float bias = ldin(gbo, tid, f32);
      float acc[4] = {bias, bias, bias, bias};
      if (f32) {
        const float4* row = (const float4*)((const float*)gWo + (size_t)tid * 600);
        #pragma unroll 2
        for (int k = 0; k < 150; ++k) {
          float4 u = row[k];
          #pragma unroll
          for (int rr = 0; rr < 4; ++rr) {
            const float4 cv = *(const float4*)(buf + rr * 600 + 4 * k);
            acc[rr] += u.x * cv.x + u.y * cv.y + u.z * cv.z + u.w * cv.w;
          }
        }
      } else {
        for (int k = 0; k < 600; ++k) {
          float w = ldin(gWo, tid * 600 + k, f32);
          #pragma unroll
          for (int rr = 0; rr < 4; ++rr) acc[rr] += w * buf[rr * 600 + k];
        }
      }
      #pragma unroll
      for (int rr = 0; rr < 4; ++rr) hg[(size_t)(lb0 + rr) * HH + tid] = tanhf(acc[rr]);
    }
  } else {
    const float* tsk = task ? hre : hner;
    const void* hWo = task ? rhW : nhW;
    const void* hbo = task ? rhb : nhb;
    float* A = task ? A1 : A0;
    float* E = task ? E1 : E0;
    for (int e = tid; e < 1200; e += 320) {
      int rr = e / 300, c = e - rr * 300;
      buf[e] = tsk[(size_t)(lb0 + rr) * HH + c];
    }
    __syncthreads();
    if (tid < HH) {
      float bias = ldin(hbo, tid, f32);
      float a[4] = {bias, bias, bias, bias};
      float ev[4] = {0.f, 0.f, 0.f, 0.f};
      if (f32) {
        const float4* r1 = (const float4*)((const float*)hWo + (size_t)tid * H3);
        const float4* r2 = (const float4*)((const float*)hWo + (size_t)tid * H3 + HH);
        #pragma unroll 2
        for (int k = 0; k < 75; ++k) {
          float4 u = r1[k], w2 = r2[k];
          #pragma unroll
          for (int rr = 0; rr < 4; ++rr) {
            const float4 tv = *(const float4*)(buf + rr * 300 + 4 * k);
            a[rr]  += u.x * tv.x + u.y * tv.y + u.z * tv.z + u.w * tv.w;
            ev[rr] += w2.x * tv.x + w2.y * tv.y + w2.z * tv.z + w2.w * tv.w;
          }
        }
      } else {
        for (int k = 0; k < HH; ++k) {
          float w1 = ldin(hWo, tid * H3 + k, f32);
          float w2 = ldin(hWo, tid * H3 + HH + k, f32);
          #pragma unroll
          for (int rr = 0; rr < 4; ++rr) {
            a[rr] += w1 * buf[rr * 300 + k];
            ev[rr] += w2 * buf[rr * 300 + k];
          }
        }
      }
      #pragma unroll
      for (int rr = 0; rr < 4; ++rr) {
        A[(size_t)(lb0 + rr) * HH + tid] = a[rr];
        E[(size_t)(lb0 + rr) * HH + tid] = ev[rr];
      }
    }
  }
}

// ---- fused gmax + gf ----
__global__ void k_gmf(const float* hg0, const float* hg1, const void* nhW, const void* rhW,
                      const void* mk, float* Gf0, float* Gf1) {
  bool f32 = is32(mk);
  int task = blockIdx.x >> 2, b = blockIdx.x & 3;
  const float* hg = task ? hg1 : hg0;
  const void* hWo = task ? rhW : nhW;
  float* Gf = task ? Gf1 : Gf0;
  __shared__ __align__(16) float gl[304];
  int tid = threadIdx.x;
  if (tid < HH) {
    float m = -1e30f;
    for (int l = 0; l < LLEN; ++l) m = fmaxf(m, hg[((size_t)l * BB + b) * HH + tid]);
    gl[tid] = m;
  }
  __syncthreads();
  if (tid < HH) {
    float acc = 0.f;
    if (f32) {
      const float4* row = (const float4*)((const float*)hWo + (size_t)tid * H3 + 600);
      #pragma unroll 5
      for (int k = 0; k < 75; ++k) {
        float4 u = row[k];
        const float4 gv = *(const float4*)(gl + 4 * k);
        acc += u.x * gv.x + u.y * gv.y + u.z * gv.z + u.w * gv.w;
      }
    } else {
      for (int k = 0; k < HH; ++k) acc += gl[k] * ldin(hWo, tid * H3 + 600 + k, f32);
    }
    Gf[b * HH + tid] = acc;
  }
}

// ---- pair epilogue v7: 8 j-pairs per block; fully-masked NER blocks skip compute ----
__global__ void __launch_bounds__(256) k_pair7(const float* A0, const float* E0, const float* Gf0,
                                               const void* lg0, const void* lb0_, const void* tW0, const void* tb0,
                                               const float* A1, const float* E1, const float* Gf1,
                                               const void* lg1, const void* lb1_, const void* tW1, const void* tb1,
                                               const void* mk, void* outv) {
  __shared__ float lg_l[304], lb_l[304], tb_l[16];
  __shared__ float tw_l[3616];
  bool f32 = is32(mk);
  int tau = blockIdx.x >> 11;
  int bid = blockIdx.x & 2047;
  int i = bid >> 4;
  int j0 = (bid & 15) << 3;
  int T = tau ? NRR : NTT;
  int diag = tau ? 0 : 1;
  int Toff = tau ? 458752 : 0;
  int tid = threadIdx.x;
  int b = tid >> 6, ln = tid & 63;
  if (diag && j0 + 7 < i) {  // block-uniform: entire 8-j tile below diagonal -> zeros
    if (ln < T) {
      #pragma unroll
      for (int dj = 0; dj < 8; ++dj) {
        size_t obase = (size_t)Toff + ((size_t)(i * LLEN + j0 + dj) * BB + b) * T;
        if (f32) ((float*)outv)[obase + ln] = 0.f;
        else ((u16*)outv)[obase + ln] = 0;
      }
    }
    return;
  }
  const float* A  = tau ? A1 : A0;
  const float* E  = tau ? E1 : E0;
  const float* Gf = tau ? Gf1 : Gf0;
  const void* lgo = tau ? lg1 : lg0;
  const void* lbo = tau ? lb1_ : lb0_;
  const void* tWo = tau ? tW1 : tW0;
  const void* tbo = tau ? tb1 : tb0;
  for (int i2 = tid; i2 < HH; i2 += 256) { lg_l[i2] = ldin(lgo, i2, f32); lb_l[i2] = ldin(lbo, i2, f32); }
  for (int i2 = tid; i2 < T * HH; i2 += 256) tw_l[i2] = ldin(tWo, i2, f32);
  if (tid < T) tb_l[tid] = ldin(tbo, tid, f32);
  __syncthreads();
  const float* ar = A  + (size_t)(i * BB + b) * HH;
  const float* gr = Gf + (size_t)b * HH;
  bool ok4 = ln < 44;
  float a0 = ar[ln]       + gr[ln];
  float a1 = ar[64 + ln]  + gr[64 + ln];
  float a2 = ar[128 + ln] + gr[128 + ln];
  float a3 = ar[192 + ln] + gr[192 + ln];
  float a4 = ok4 ? (ar[256 + ln] + gr[256 + ln]) : 0.f;
  float mi = ldin(mk, i * BB + b, f32);
  for (int dj = 0; dj < 8; ++dj) {
    int jx = j0 + dj;
    const float* er = E + (size_t)(jx * BB + b) * HH;
    float u0 = a0 + er[ln];
    float u1 = a1 + er[64 + ln];
    float u2 = a2 + er[128 + ln];
    float u3 = a3 + er[192 + ln];
    float u4 = ok4 ? (a4 + er[256 + ln]) : 0.f;
    float s1 = ((u0 + u1) + (u2 + u3)) + u4;
    float s2 = ((u0 * u0 + u1 * u1) + (u2 * u2 + u3 * u3)) + u4 * u4;
    #pragma unroll
    for (int d = 1; d < 64; d <<= 1) { s1 += __shfl_xor(s1, d); s2 += __shfl_xor(s2, d); }
    float mean = s1 * (1.f / 300.f);
    float var = s2 * (1.f / 300.f) - mean * mean;
    float rstd = rsqrtf(var + 1e-5f);
    {
      float y;
      y = (u0 - mean) * rstd * lg_l[ln]       + lb_l[ln];       u0 = (y > 0.f) ? y : __expf(y) - 1.f;
      y = (u1 - mean) * rstd * lg_l[64 + ln]  + lb_l[64 + ln];  u1 = (y > 0.f) ? y : __expf(y) - 1.f;
      y = (u2 - mean) * rstd * lg_l[128 + ln] + lb_l[128 + ln]; u2 = (y > 0.f) ? y : __expf(y) - 1.f;
      y = (u3 - mean) * rstd * lg_l[192 + ln] + lb_l[192 + ln]; u3 = (y > 0.f) ? y : __expf(y) - 1.f;
      if (ok4) {
        y = (u4 - mean) * rstd * lg_l[256 + ln] + lb_l[256 + ln];
        u4 = (y > 0.f) ? y : __expf(y) - 1.f;
      }
    }
    float m = mi * ldin(mk, jx * BB + b, f32);
    if (diag && jx < i) m = 0.f;
    size_t obase = (size_t)Toff + ((size_t)(i * LLEN + jx) * BB + b) * T;
    float mine = 0.f;
    for (int t = 0; t < T; ++t) {
      const float* twr = tw_l + t * HH;
      float s = u0 * twr[ln] + u1 * twr[64 + ln] + u2 * twr[128 + ln] + u3 * twr[192 + ln];
      if (ok4) s += u4 * twr[256 + ln];
      s = wsum(s);
      s += tb_l[t];
      float o = m / (1.f + __expf(-s));
      mine = (ln == t) ? o : mine;
    }
    if (ln < T) {
      if (f32) ((float*)outv)[obase + ln] = mine;
      else ((u16*)outv)[obase + ln] = f2bf(mine);
    }
  }
}

// ---- sentinel ----
__global__ void k_sent(const void* mk, const void* xo, void* outv, int hostcode) {
  __shared__ int bad;
  if (threadIdx.x == 0) bad = 0;
  __syncthreads();
  bool f32 = is32(mk);
  for (int i = threadIdx.x; i < 4096; i += 256) {
    float v = ldin(xo, i, f32);
    if (!(v == v) || fabsf(v) > 1e6f) bad = 1;
  }
  __syncthreads();
  if (threadIdx.x == 0) {
    float code = (float)hostcode;
    if (bad) code = fmaxf(code, 88.f);
    if (code > 0.f) {
      if (f32) ((float*)outv)[0] = code;
      else ((u16*)outv)[0] = f2bf(code);
    }
  }
}

extern "C" void kernel_launch(void* const* d_in, const int* in_sizes, int n_in,
                              void* d_out, int out_size, void* d_ws, size_t ws_size,
                              hipStream_t stream) {
  const void* x    = d_in[0];
  const void* mask = d_in[1];
  const void* Wih  = d_in[2];
  const void* bih  = d_in[3];
  const void* Whh  = d_in[4];
  const void* bhh  = d_in[5];
  const void* Wtr  = d_in[6];
  const void* btr  = d_in[7];
  const void* nW   = d_in[8];
  const void* nb   = d_in[9];
  const void* nhW  = d_in[10];
  const void* nhb  = d_in[11];
  const void* ng   = d_in[12];
  const void* nbe  = d_in[13];
  const void* ntW  = d_in[14];
  const void* ntb  = d_in[15];
  const void* rW   = d_in[16];
  const void* rb   = d_in[17];
  const void* rhW  = d_in[18];
  const void* rhb  = d_in[19];
  const void* rg   = d_in[20];
  const void* rbe  = d_in[21];
  const void* rtW  = d_in[22];
  const void* rtb  = d_in[23];
  float* ws = (float*)d_ws;

  static const int exp_sz[24] = {393216, 512, 1152000, 1500, 450000, 1500, 270000, 300,
                                 180000, 300, 270000, 300, 300, 300, 2100, 7,
                                 180000, 300, 270000, 300, 300, 300, 3600, 12};
  int hostcode = 0;
  if (n_in != 24) hostcode = 890;
  else {
    for (int ii = 0; ii < 24; ++ii)
      if (in_sizes[ii] != exp_sz[ii]) { hostcode = 900 + ii; break; }
  }
  if (hostcode == 0 && out_size != 1245184) hostcode = 880;
  if (hostcode == 0 && ws_size < WS_NEED_BYTES) hostcode = 1099;

  dim3 gc(512, 5);
  k_canon<<<gc, 256, 0, stream>>>(x, mask, Wih, bih, Whh, bhh, Wtr, btr, ws);
  k_scanA<<<128, 512, 0, stream>>>(ws + F_PRE, (const float2*)(ws + C_WHH2), (const float2*)(ws + C_WTR2),
                                   ws + F_BTR, ws + F_HNER, ws + F_HRE, ws + F_HSH, ws + F_AUX, ws);
  k_scanB<<<128, 512, 0, stream>>>(ws + F_PRE, (const float2*)(ws + C_WHH2), (const float2*)(ws + C_WTR2),
                                   ws + F_BTR, ws + F_HNER, ws + F_HRE, ws + F_HSH, ws + F_AUX);
  k_post<<<512, 320, 0, stream>>>(ws + F_HSH, ws + F_HNER, ws + F_HRE,
                                  nW, nb, rW, rb, nhW, nhb, rhW, rhb, mask,
                                  ws + F_HG0, ws + F_HG1, ws + F_A0, ws + F_E0, ws + F_A1, ws + F_E1);
  k_gmf<<<8, 320, 0, stream>>>(ws + F_HG0, ws + F_HG1, nhW, rhW, mask, ws + F_GF0, ws + F_GF1);
  k_pair7<<<4096, 256, 0, stream>>>(ws + F_A0, ws + F_E0, ws + F_GF0, ng, nbe, ntW, ntb,
                                    ws + F_A1, ws + F_E1, ws + F_GF1, rg, rbe, rtW, rtb,
                                    mask, d_out);
  k_sent<<<1, 256, 0, stream>>>(mask, x, d_out, hostcode);
}

// Round 12
// 1244.735 us; speedup vs baseline: 1.1701x; 1.0667x over previous
//
#include <hip/hip_runtime.h>

#define LLEN 128
#define BB 4
#define DD 768
#define HH 300
#define G5 1500
#define H3 900
#define NTT 7
#define NRR 12
#define NCHB 10
#define RPB 150
#define OPB 30

// ---- fp32 workspace layout (ws as float*) ----
#define C_WIH  0
#define C_X    1152000
#define C_WHH2 1545216
#define C_WTR2 1995216
#define F_BIH  2265216
#define F_BTR  2266720
#define F_PRE  2267040
// PRE region reused after the scan:
#define F_HG0  (F_PRE)
#define F_HG1  (F_PRE+153600)
#define F_A0   (F_PRE+307200)
#define F_E0   (F_PRE+460800)
#define F_GF0  (F_PRE+616832)
#define F_GF1  (F_PRE+618048)
// beyond PRE:
#define F_HNER (F_PRE+768000)
#define F_HRE  (F_HNER+153600)
#define F_HSH  (F_HRE+153600)
#define F_A1   0
#define F_E1   153600
#define F_AUX  (F_HSH+153600)
// scanA exchange buffers in the scan-dead C_WIH region [0,1152000):
//   partials: part(buf,b) = buf*96000 + b*24000: 1500 rows x 16 floats
//   (cols 0..9 partial sums, 10..11 zero pads, 12..15 never read) [R6/R9-proven]
//   c_pub: 192000 + (buf*4+b)*304
#define P_CPUB 192000
// aux per-batch (AUXB floats): scanB selftest words (tst @ gb+2240, seflag @ gb+2272)
#define AUXB   2432
#define AUX_FL 9728
// int area (2048 ints, zeroed per launch with AGENT stores — these lines are
// touched EXCLUSIVELY by agent-scope ops by every kernel, so LLC is authoritative):
//   chunk0 (scanA): claim [0,32); per batch b at [32+64b): slots[0..15], abort@+24
//   chunk1 (scanB): claim [640,672); per batch b at [672+64b): slotsA[16] slotsB[16] atf[5]
//   done[4] @ [1536,1540)  (scanA completion counters; scanB skips batch iff ==NCHB)
#define WS_NEED_BYTES ((size_t)(F_AUX+11776)*4)

typedef unsigned short u16;
typedef unsigned int u32;
typedef float f4 __attribute__((ext_vector_type(4)));
typedef int i4 __attribute__((ext_vector_type(4)));

__device__ __forceinline__ float bf2f(u16 u) {
  union { u32 i; float f; } v; v.i = ((u32)u) << 16; return v.f;
}
__device__ __forceinline__ float bflo(u32 u) {
  union { u32 i; float f; } v; v.i = u << 16; return v.f;
}
__device__ __forceinline__ float bfhi(u32 u) {
  union { u32 i; float f; } v; v.i = u & 0xffff0000u; return v.f;
}
__device__ __forceinline__ u16 f2bf(float f) {
  union { float f; u32 i; } v; v.f = f;
  u32 r = v.i + 0x7fffu + ((v.i >> 16) & 1u);
  return (u16)(r >> 16);
}
__device__ __forceinline__ float ldin(const void* p, int i, bool f32) {
  return f32 ? ((const float*)p)[i] : bf2f(((const u16*)p)[i]);
}
__device__ __forceinline__ bool is32(const void* mk) {
  return ((const u16*)mk)[0] == 0;
}
__device__ __forceinline__ float wsum(float x) {
  #pragma unroll
  for (int d = 1; d < 64; d <<= 1) x += __shfl_xor(x, d);
  return x;
}
// ---- agent-scope (LLC) accessors ----
__device__ __forceinline__ void astore(float* p, float v) {
  union { float f; int i; } u; u.f = v;
  __hip_atomic_store((int*)p, u.i, __ATOMIC_RELAXED, __HIP_MEMORY_SCOPE_AGENT);
}
// proven agent-scope inter-block barrier (scanB selftest/claim only)
__device__ __forceinline__ void gbar(int* flag, int tid, int target) {
  __syncthreads();
  if (tid == 0) {
    __builtin_amdgcn_s_waitcnt(0);
    __hip_atomic_fetch_add(flag, 1, __ATOMIC_RELAXED, __HIP_MEMORY_SCOPE_AGENT);
    int it = 0;
    while (__hip_atomic_load(flag, __ATOMIC_RELAXED, __HIP_MEMORY_SCOPE_AGENT) < target) {
      __builtin_amdgcn_s_sleep(1);
      if (++it > 50000) break;
    }
  }
  __syncthreads();
}
// ---- scoped exchange primitives (mode 1 = XCD/L2, mode 0 = agent/LLC) ----
__device__ __forceinline__ f4 ld4x(const f4* p, int mode) {
  f4 v;
  if (mode)
    asm volatile("global_load_dwordx4 %0, %1, off sc0\n\ts_waitcnt vmcnt(0)"
                 : "=v"(v) : "v"(p) : "memory");
  else
    asm volatile("global_load_dwordx4 %0, %1, off sc0 sc1\n\ts_waitcnt vmcnt(0)"
                 : "=v"(v) : "v"(p) : "memory");
  return v;
}
__device__ __forceinline__ float ld1x(const float* p, int mode) {
  float v;
  if (mode)
    asm volatile("global_load_dword %0, %1, off sc0\n\ts_waitcnt vmcnt(0)"
                 : "=v"(v) : "v"(p) : "memory");
  else
    asm volatile("global_load_dword %0, %1, off sc0 sc1\n\ts_waitcnt vmcnt(0)"
                 : "=v"(v) : "v"(p) : "memory");
  return v;
}
__device__ __forceinline__ int ldix(const int* p, int mode) {
  int v;
  if (mode)
    asm volatile("global_load_dword %0, %1, off sc0\n\ts_waitcnt vmcnt(0)"
                 : "=v"(v) : "v"(p) : "memory");
  else
    asm volatile("global_load_dword %0, %1, off sc0 sc1\n\ts_waitcnt vmcnt(0)"
                 : "=v"(v) : "v"(p) : "memory");
  return v;
}
__device__ __forceinline__ void exst(float* p, float v, int mode) {
  if (mode) *p = v; else astore(p, v);
}
// 9 overlapped dwordx4 from one 64B-aligned base (3 rows x 3 quads), L2-local
__device__ __forceinline__ void ld9(const float* base,
                                    f4& a0, f4& a1, f4& a2, f4& a3, f4& a4,
                                    f4& a5, f4& a6, f4& a7, f4& a8) {
  asm volatile(
    "global_load_dwordx4 %0, %9, off sc0\n\t"
    "global_load_dwordx4 %1, %9, off offset:16 sc0\n\t"
    "global_load_dwordx4 %2, %9, off offset:32 sc0\n\t"
    "global_load_dwordx4 %3, %9, off offset:64 sc0\n\t"
    "global_load_dwordx4 %4, %9, off offset:80 sc0\n\t"
    "global_load_dwordx4 %5, %9, off offset:96 sc0\n\t"
    "global_load_dwordx4 %6, %9, off offset:128 sc0\n\t"
    "global_load_dwordx4 %7, %9, off offset:144 sc0\n\t"
    "global_load_dwordx4 %8, %9, off offset:160 sc0\n\t"
    "s_waitcnt vmcnt(0)"
    : "=&v"(a0), "=&v"(a1), "=&v"(a2), "=&v"(a3), "=&v"(a4),
      "=&v"(a5), "=&v"(a6), "=&v"(a7), "=&v"(a8)
    : "v"(base) : "memory");
}
// poll all 10 arrival slots (12 loaded; last 2 zero padding)
__device__ __forceinline__ int poll10(const int* slots, int tok, int mode) {
  i4 a, b, c;
  if (mode)
    asm volatile("global_load_dwordx4 %0, %3, off sc0\n\t"
                 "global_load_dwordx4 %1, %4, off sc0\n\t"
                 "global_load_dwordx4 %2, %5, off sc0\n\t"
                 "s_waitcnt vmcnt(0)"
                 : "=&v"(a), "=&v"(b), "=&v"(c)
                 : "v"(slots), "v"(slots + 4), "v"(slots + 8) : "memory");
  else
    asm volatile("global_load_dwordx4 %0, %3, off sc0 sc1\n\t"
                 "global_load_dwordx4 %1, %4, off sc0 sc1\n\t"
                 "global_load_dwordx4 %2, %5, off sc0 sc1\n\t"
                 "s_waitcnt vmcnt(0)"
                 : "=&v"(a), "=&v"(b), "=&v"(c)
                 : "v"(slots), "v"(slots + 4), "v"(slots + 8) : "memory");
  return (a.x >= tok) & (a.y >= tok) & (a.z >= tok) & (a.w >= tok) &
         (b.x >= tok) & (b.y >= tok) & (b.z >= tok) & (b.w >= tok) &
         (c.x >= tok) & (c.y >= tok);
}
// slot barrier (scanB, proven): drain + sync + tid0 token store; wave 0 polls
__device__ __forceinline__ void sbar(int* slots, int ch, int tok, int tid, int mode) {
  asm volatile("s_waitcnt vmcnt(0)" ::: "memory");
  __syncthreads();
  if (tid == 0) {
    if (mode) slots[ch] = tok;
    else __hip_atomic_store(slots + ch, tok, __ATOMIC_RELAXED, __HIP_MEMORY_SCOPE_AGENT);
  }
  if (tid < 64) {
    int it = 0;
    while (!poll10(slots, tok, mode)) {
      __builtin_amdgcn_s_sleep(1);
      if (++it > 5000) break;
    }
  }
  __syncthreads();
}
// scanA slot barrier: AGENT-scope tokens (LLC-exclusive lines, stale-proof) +
// L2-local payload (covered by drain-before-token). Tight-spin first, then sleep.
__device__ __forceinline__ void sbarA(int* slots, int* abf, int ch, int tok, int tid,
                                      volatile int* s_fail) {
  asm volatile("s_waitcnt vmcnt(0)" ::: "memory");  // payload drained to our L2
  __syncthreads();
  if (tid == 0)
    __hip_atomic_store(slots + ch, tok, __ATOMIC_RELAXED, __HIP_MEMORY_SCOPE_AGENT);
  if (tid < 64) {
    int it = 0;
    while (!poll10(slots, tok, 0)) {   // mode 0 = agent/LLC reads
      ++it;
      if (it > 24) __builtin_amdgcn_s_sleep(1);  // tight-spin early for fast release
      if ((it & 255) == 0 &&
          __hip_atomic_load(abf, __ATOMIC_RELAXED, __HIP_MEMORY_SCOPE_AGENT) != 0) {
        *s_fail = 1; break;
      }
      if (it > 8000) {
        __hip_atomic_store(abf, 1, __ATOMIC_RELAXED, __HIP_MEMORY_SCOPE_AGENT);
        *s_fail = 1; break;
      }
    }
  }
  __syncthreads();
}
// claim (xcd, rank) via HW_REG_XCC_ID + grid rendezvous (agent-only lines)
__device__ __forceinline__ int claim_bc(int* cl, int nb) {
  unsigned xcd;
  asm volatile("s_getreg_b32 %0, hwreg(HW_REG_XCC_ID)" : "=s"(xcd));
  xcd &= 7u;
  int rank = __hip_atomic_fetch_add(cl + xcd, 1, __ATOMIC_RELAXED, __HIP_MEMORY_SCOPE_AGENT);
  __hip_atomic_fetch_add(cl + 8, 1, __ATOMIC_RELAXED, __HIP_MEMORY_SCOPE_AGENT);
  int it = 0;
  while (__hip_atomic_load(cl + 8, __ATOMIC_RELAXED, __HIP_MEMORY_SCOPE_AGENT) < nb) {
    __builtin_amdgcn_s_sleep(2);
    if (++it > 100000) break;
  }
  int base = 0;
  for (unsigned x = 0; x < xcd; ++x)
    base += __hip_atomic_load(cl + x, __ATOMIC_RELAXED, __HIP_MEMORY_SCOPE_AGENT) / NCHB;
  int cnt = __hip_atomic_load(cl + xcd, __ATOMIC_RELAXED, __HIP_MEMORY_SCOPE_AGENT);
  int slot = base + rank / NCHB;
  return (rank < (cnt / NCHB) * NCHB && slot < BB) ? (slot * 16 + rank % NCHB) : -1;
}

// ---- canonicalize + fused pre-GEMM (pre reads bf16 inputs directly) ----
__global__ void k_canon(const void* xo, const void* mk, const void* Wih, const void* bih,
                        const void* Whh, const void* bhh, const void* Wtr, const void* btr,
                        float* ws) {
  __shared__ __align__(16) float xl[8 * DD];
  bool f32 = is32(mk);
  int piece = blockIdx.y;
  int i0 = blockIdx.x * 256 + threadIdx.x;
  int stride = gridDim.x * 256;
  switch (piece) {
    case 0: for (int i = i0; i < 225000; i += stride) {   // W2hh repack
      int k2 = i / G5, out = i - k2 * G5;
      float2 v;
      v.x = ldin(Whh, out * HH + 2 * k2, f32);
      v.y = ldin(Whh, out * HH + 2 * k2 + 1, f32);
      ((float2*)(ws + C_WHH2))[i] = v;
    } break;
    case 1: for (int i = i0; i < 135000; i += stride) {   // W2tr repack
      int k2 = i / HH, out = i - k2 * HH;
      float2 v;
      v.x = ldin(Wtr, out * H3 + 2 * k2, f32);
      v.y = ldin(Wtr, out * H3 + 2 * k2 + 1, f32);
      ((float2*)(ws + C_WTR2))[i] = v;
    } break;
    case 2: for (int i = i0; i < 1824; i += stride) {     // bias sums
      if (i < 1504) ws[F_BIH + i] = (i < G5) ? ldin(bih, i, f32) + ldin(bhh, i, f32) : 0.f;
      else { int j = i - 1504; ws[F_BTR + j] = (j < HH) ? ldin(btr, j, f32) : 0.f; }
    } break;
    case 3: for (int i = i0; i < 11776; i += stride) {    // aux zero
      if (i < AUX_FL) ws[F_AUX + i] = 0.f;                // float aux (selftest words)
      else {                                               // int control area: AGENT zero
        int* ip = (int*)(ws + F_AUX + AUX_FL);
        __hip_atomic_store(ip + (i - AUX_FL), 0, __ATOMIC_RELAXED, __HIP_MEMORY_SCOPE_AGENT);
      }
    } break;
    case 4: {  // pre = x @ W_ih^T + (b_ih + b_hh); direct bf16 reads (bit-identical)
      if (blockIdx.x >= 128) return;
      int tid = threadIdx.x;
      int lb0 = ((int)blockIdx.x >> 1) * 8;
      int half = blockIdx.x & 1;
      float* pre = ws + F_PRE;
      if (f32) {
        const float* X = (const float*)xo;
        for (int e = tid; e < 8 * DD; e += 256) xl[e] = X[(size_t)lb0 * DD + e];
      } else {
        const u16* X = (const u16*)xo;
        for (int e = tid; e < 8 * DD; e += 256) xl[e] = bf2f(X[(size_t)lb0 * DD + e]);
      }
      __syncthreads();
      for (int j = half * 750 + tid; j < half * 750 + 750; j += 256) {
        float acc[8] = {0.f, 0.f, 0.f, 0.f, 0.f, 0.f, 0.f, 0.f};
        if (f32) {
          const float4* w = (const float4*)((const float*)Wih + (size_t)j * DD);
          #pragma unroll 2
          for (int k = 0; k < DD / 4; ++k) {
            float4 u = w[k];
            #pragma unroll
            for (int r = 0; r < 8; ++r) {
              const float4 p = *(const float4*)(xl + r * DD + k * 4);
              acc[r] += u.x * p.x + u.y * p.y + u.z * p.z + u.w * p.w;
            }
          }
        } else {
          const u16* wr = (const u16*)Wih + (size_t)j * DD;
          #pragma unroll 2
          for (int k = 0; k < DD; k += 8) {
            uint4 wv = *(const uint4*)(wr + k);
            float w0 = bflo(wv.x), w1 = bfhi(wv.x), w2 = bflo(wv.y), w3 = bfhi(wv.y);
            float w4 = bflo(wv.z), w5 = bfhi(wv.z), w6 = bflo(wv.w), w7 = bfhi(wv.w);
            #pragma unroll
            for (int r = 0; r < 8; ++r) {
              const float4 p1 = *(const float4*)(xl + r * DD + k);
              const float4 p2 = *(const float4*)(xl + r * DD + k + 4);
              acc[r] += w0 * p1.x + w1 * p1.y + w2 * p1.z + w3 * p1.w
                      + w4 * p2.x + w5 * p2.y + w6 * p2.z + w7 * p2.w;
            }
          }
        }
        float bias = ldin(bih, j, f32) + ldin(bhh, j, f32);
        #pragma unroll
        for (int r = 0; r < 8; ++r) pre[(size_t)(lb0 + r) * G5 + j] = acc[r] + bias;
      }
    } break;
  }
}

// ---- scanA: 1-barrier/step; W-phase via 16-lane shuffle reduction (no LDS, -1 sync) ----
__global__ void __launch_bounds__(512, 2) k_scanA(const float* pre, const float2* W2h, const float2* W2t,
                                                  const float* btrf, float* hner, float* hre, float* hsh,
                                                  float* aux, float* xw) {
  __shared__ __align__(16) float ga_l[1504];
  __shared__ __align__(16) float vv_l[1204];
  __shared__ __align__(16) float tnh_l[304];
  __shared__ __align__(16) float cat_l[904];
  __shared__ __align__(16) float ci_l[304];
  __shared__ __align__(16) float h_loc[32];
  __shared__ int s_bc;
  __shared__ int s_fail;
  int tid = threadIdx.x;
  int* ibase = (int*)(aux + AUX_FL);
  if (tid == 0) { s_bc = claim_bc(ibase, (int)gridDim.x); s_fail = 0; }
  __syncthreads();
  int bc = s_bc;
  if (bc < 0) return;
  int b = bc >> 4, ch = bc & 15;
  int* slots = ibase + 32 + b * 64;
  int* abf   = slots + 24;
  int* done  = ibase + 1536;

  // zero pad columns (10,11) of both partial buffers (plain stores to our L2;
  // covered for readers by the drain in the first sbarA)
  if (ch < 2) {
    float* pb0 = xw + (size_t)ch * 96000 + b * 24000;
    for (int i = tid; i < 3000; i += 512) {
      int row = i >> 1, col = 10 + (i & 1);
      pb0[row * 16 + col] = 0.f;
    }
  }

  int o0 = 3 * tid;
  float2 wh2[45];
  if (tid < 500) {
    #pragma unroll
    for (int j = 0; j < 3; ++j)
      #pragma unroll
      for (int kk = 0; kk < 15; ++kk)
        wh2[j * 15 + kk] = W2h[(size_t)(ch * 15 + kk) * G5 + (o0 + j)];
  }
  // Wtr split: output oo = tid>>4 (30 outputs), k-slice sub = tid&15 (29 k2 each)
  int oo = tid >> 4, sub = tid & 15;
  float2 wt[29];
  int k2b = sub * 29;
  int k2e = (k2b + 29 < 450) ? (k2b + 29) : 450;
  int nk2 = k2e - k2b;
  if (tid < 480) {
    const float2* wp = W2t + (size_t)k2b * HH + (ch * OPB + oo);
    #pragma unroll
    for (int q = 0; q < 29; ++q) if (q < nk2) wt[q] = wp[(size_t)q * HH];
  }
  float pv0 = 0.f, pv1 = 0.f, pv2 = 0.f;
  if (tid < 500) {
    const float* pr = pre + (size_t)b * G5 + o0;
    pv0 = pr[0]; pv1 = pr[1]; pv2 = pr[2];
  }
  __syncthreads();

  for (int t = 0; t < LLEN; ++t) {
    int buf = t & 1;
    float* pb = xw + (size_t)buf * 96000 + b * 24000;
    if (t > 0) {
      if (tid < 500) {
        float2 h2[15];
        #pragma unroll
        for (int kk = 0; kk < 15; ++kk) h2[kk] = *(const float2*)(h_loc + 2 * kk);
        #pragma unroll
        for (int j = 0; j < 3; ++j) {
          float acc = 0.f;
          #pragma unroll
          for (int kk = 0; kk < 15; ++kk)
            acc += wh2[j * 15 + kk].x * h2[kk].x + wh2[j * 15 + kk].y * h2[kk].y;
          pb[(size_t)(o0 + j) * 16 + ch] = acc;
        }
      }
      sbarA(slots, abf, ch, t, tid, &s_fail);   // the ONLY inter-block barrier
      if (s_fail) return;                        // desync: scanB redoes this batch
      if (tid < 500) {
        f4 a0, a1, a2, a3, a4, a5, a6, a7, a8;
        ld9(pb + (size_t)o0 * 16, a0, a1, a2, a3, a4, a5, a6, a7, a8);
        ga_l[o0]     = pv0 + (((a0.x + a0.y) + (a0.z + a0.w)) +
                              ((a1.x + a1.y) + (a1.z + a1.w)) +
                              ((a2.x + a2.y) + (a2.z + a2.w)));
        ga_l[o0 + 1] = pv1 + (((a3.x + a3.y) + (a3.z + a3.w)) +
                              ((a4.x + a4.y) + (a4.z + a4.w)) +
                              ((a5.x + a5.y) + (a5.z + a5.w)));
        ga_l[o0 + 2] = pv2 + (((a6.x + a6.y) + (a6.z + a6.w)) +
                              ((a7.x + a7.y) + (a7.z + a7.w)) +
                              ((a8.x + a8.y) + (a8.z + a8.w)));
      }
      if (tid < 75) {
        const float* cp = xw + P_CPUB + (size_t)(((t - 1) & 1) * 4 + b) * 304;
        f4 v = ld4x((const f4*)cp + tid, 1);
        *(f4*)(ci_l + 4 * tid) = v;
      }
    } else {
      if (tid < 500) { ga_l[o0] = pv0; ga_l[o0 + 1] = pv1; ga_l[o0 + 2] = pv2; }
    }
    __syncthreads();
    if (tid < HH) tnh_l[tid] = tanhf(ga_l[tid]);
    {
      int w = tid >> 6, ln = tid & 63;
      if (w >= 4) {
        int c = w - 3;
        const float* g = ga_l + c * 300;
        int e0 = ln * 5;
        float ex0 = 0.f, ex1 = 0.f, ex2 = 0.f, ex3 = 0.f, ex4 = 0.f;
        if (ln < 60) {
          ex0 = __expf(g[e0]); ex1 = __expf(g[e0 + 1]); ex2 = __expf(g[e0 + 2]);
          ex3 = __expf(g[e0 + 3]); ex4 = __expf(g[e0 + 4]);
        }
        float p = ((ex0 + ex1) + (ex2 + ex3)) + ex4;
        float inc = p;
        #pragma unroll
        for (int d = 1; d < 64; d <<= 1) { float o = __shfl_up(inc, d); if (ln >= d) inc += o; }
        float S = __shfl(inc, 59);
        float invS = 1.f / S;
        float run = inc - p;
        if (ln < 60) {
          float* vv = vv_l + (c - 1) * 300 + e0;
          run += ex0; vv[0] = run * invS;
          run += ex1; vv[1] = run * invS;
          run += ex2; vv[2] = run * invS;
          run += ex3; vv[3] = run * invS;
          run += ex4; vv[4] = run * invS;
        }
      }
    }
    if (t + 1 < LLEN && tid < 500) {
      const float* pr = pre + ((size_t)(t + 1) * BB + b) * G5 + o0;
      pv0 = pr[0]; pv1 = pr[1]; pv2 = pr[2];
    }
    __syncthreads();
    if (tid < HH) {
      float c = tnh_l[tid];
      float v0 = vv_l[tid], v1 = vv_l[300 + tid], v2 = vv_l[600 + tid], v3 = vv_l[900 + tid];
      float eg_cin = 1.f - v0, rg_cin = v1, eg_c = 1.f - v2, rg_c = v3;
      float ci = (t > 0) ? ci_l[tid] : 0.f;
      float ov_c = rg_c * eg_c;
      float up_c = rg_c - ov_c, dn_c = eg_c - ov_c;
      float ov_i = rg_cin * eg_cin;
      float up_i = rg_cin - ov_i, dn_i = eg_cin - ov_i;
      float share = ov_i * ci + ov_c * c;
      float c_re  = up_i * ci + up_c * c + share;
      float c_ner = dn_i * ci + dn_c * c + share;
      cat_l[tid] = c_re; cat_l[HH + tid] = c_ner; cat_l[2 * HH + tid] = share;
      int sb = ch * OPB;
      if (tid >= sb && tid < sb + OPB) {
        size_t ob = ((size_t)t * BB + b) * HH + tid;
        hner[ob] = tanhf(c_ner); hre[ob] = tanhf(c_re); hsh[ob] = tanhf(share);
      }
    }
    __syncthreads();
    // W: own Wtr slice via 16-lane shuffle reduction (no LDS staging, no extra sync)
    if (tid < 480) {
      float acc = 0.f;
      #pragma unroll
      for (int q = 0; q < 29; ++q)
        if (q < nk2) acc += wt[q].x * cat_l[2 * (k2b + q)] + wt[q].y * cat_l[2 * (k2b + q) + 1];
      #pragma unroll
      for (int d = 1; d < 16; d <<= 1) acc += __shfl_xor(acc, d);
      if (sub == 0) {
        float co = btrf[ch * OPB + oo] + acc;
        h_loc[oo] = tanhf(co);
        float* cp = xw + P_CPUB + (size_t)(buf * 4 + b) * 304;
        cp[ch * OPB + oo] = co;
      }
    }
    __syncthreads();
  }
  // completed with zero timeouts -> publish; scanB (stream-serialized) skips batch
  if (tid == 0 && s_fail == 0)
    __hip_atomic_fetch_add(done + b, 1, __ATOMIC_RELAXED, __HIP_MEMORY_SCOPE_AGENT);
}

// ---- scanB: R4-proven 2-barrier kernel; fast-exit when scanA handled all batches ----
__global__ void __launch_bounds__(512, 2) k_scanB(const float* pre, const float2* W2h, const float2* W2t,
                                                  const float* btrf, float* hner, float* hre, float* hsh,
                                                  float* aux) {
  __shared__ __align__(16) float h_l[304];
  __shared__ __align__(16) float ci_l[304];
  __shared__ __align__(16) float ga_l[1504];
  __shared__ __align__(16) float cat_l[904];
  __shared__ __align__(16) float ps[512];
  __shared__ __align__(16) float sums_l[8];
  __shared__ float exv[160];
  __shared__ int s_bc, s_mode, s_skip;
  int tid = threadIdx.x;
  int* ibase = (int*)(aux + AUX_FL);
  int* done = ibase + 1536;
  // pre-claim fast path: if scanA completed every batch, skip the rendezvous entirely
  if (tid == 0) {
    int ok = 1;
    #pragma unroll
    for (int q = 0; q < BB; ++q)
      ok &= (__hip_atomic_load(done + q, __ATOMIC_RELAXED, __HIP_MEMORY_SCOPE_AGENT) == NCHB);
    s_skip = ok;
  }
  __syncthreads();
  if (s_skip) return;
  int* cl2 = ibase + 640;
  if (tid == 0) s_bc = claim_bc(cl2, (int)gridDim.x);
  __syncthreads();
  int bc = s_bc;
  if (bc < 0) return;
  int b = bc >> 4, ch = bc & 15;
  if (tid == 0)
    s_skip = (__hip_atomic_load(done + b, __ATOMIC_RELAXED, __HIP_MEMORY_SCOPE_AGENT) == NCHB);
  __syncthreads();
  if (s_skip) return;  // scanA fully produced this batch
  int s = ch >> 1;
  int r0 = ch * RPB;
  float* gb   = aux + b * AUXB;
  float* cb   = gb + 1504;
  float* hb   = gb + 1808;
  float* sums = gb + 2112;
  int* slotsA = ibase + 672 + b * 64;
  int* slotsB = slotsA + 16;
  int* atf    = slotsA + 32;

  // ---- selftest (R4-proven form) ----
  {
    float* tst = gb + 2240;
    int* seflag = (int*)(gb + 2272);
    if (ch == 0 && tid == 0) tst[0] = 1.0f;
    gbar(atf + 0, tid, NCHB);
    if (tid == 0) { float w1 = ld1x(tst, 1); (void)w1; }
    gbar(atf + 1, tid, NCHB);
    if (ch == 0 && tid == 0) { tst[0] = 2.0f; __builtin_amdgcn_s_waitcnt(0); }
    if (ch == 1 && tid == 0)
      __hip_atomic_fetch_add(seflag, 1, __ATOMIC_RELAXED, __HIP_MEMORY_SCOPE_WORKGROUP);
    gbar(atf + 2, tid, NCHB);
    if (tid == 0) {
      float w2 = ld1x(tst, 1);
      int fv = ldix(seflag, 1);
      if (w2 != 2.0f || fv != 1)
        __hip_atomic_fetch_or(atf + 4, 1, __ATOMIC_RELAXED, __HIP_MEMORY_SCOPE_AGENT);
    }
    gbar(atf + 3, tid, NCHB);
    if (tid == 0)
      s_mode = (__hip_atomic_load(atf + 4, __ATOMIC_RELAXED, __HIP_MEMORY_SCOPE_AGENT) == 0) ? 1 : 0;
    __syncthreads();
  }
  int mode = s_mode;

  int j = tid / RPB, r = tid - j * RPB;
  int o2 = tid % OPB, jj = tid / OPB;
  int kb = j * 100;

  float2 wh[50];
  if (tid < 450) {
    const float2* wp = W2h + (size_t)(j * 50) * G5 + (r0 + r);
    #pragma unroll
    for (int kk = 0; kk < 50; ++kk) wh[kk] = wp[(size_t)kk * G5];
  }
  float2 wt[29];
  int k2b = jj * 29;
  int k2e = (k2b + 29 < 450) ? (k2b + 29) : 450;
  int nk2 = k2e - k2b;
  if (tid < 480) {
    const float2* wp = W2t + (size_t)k2b * HH + (ch * OPB + o2);
    #pragma unroll
    for (int q = 0; q < 29; ++q) if (q < nk2) wt[q] = wp[(size_t)q * HH];
  }
  float pv = 0.f;
  if (tid < RPB) pv = pre[(size_t)b * G5 + r0 + tid];
  __syncthreads();

  for (int t = 0; t < LLEN; ++t) {
    if (t > 0) {
      if (tid < 75)       { f4 v = ld4x((const f4*)hb + tid, mode); *(f4*)(h_l + 4 * tid) = v; }
      else if (tid < 150) { int q = tid - 75; f4 v = ld4x((const f4*)cb + q, mode); *(f4*)(ci_l + 4 * q) = v; }
      __syncthreads();
    }
    if (tid < 450) {
      float acc = (j == 0) ? pv : 0.f;
      if (t > 0) {
        #pragma unroll
        for (int kk = 0; kk < 50; ++kk)
          acc += wh[kk].x * h_l[kb + 2 * kk] + wh[kk].y * h_l[kb + 2 * kk + 1];
      }
      ps[tid] = acc;
    }
    __syncthreads();
    if (tid < RPB) {
      float g = ps[tid] + ps[RPB + tid] + ps[2 * RPB + tid];
      if (s == 0) exst(gb + r0 + tid, tanhf(g), mode);
      else exv[tid] = __expf(g);
    }
    if (s > 0) {
      __syncthreads();
      if (tid < 30) {
        int base2 = tid * 5;
        float e0 = exv[base2], e1 = exv[base2 + 1], e2 = exv[base2 + 2],
              e3 = exv[base2 + 3], e4 = exv[base2 + 4];
        float p = ((e0 + e1) + (e2 + e3)) + e4;
        float inc = p;
        #pragma unroll
        for (int d = 1; d < 32; d <<= 1) { float o = __shfl_up(inc, d); if (tid >= d) inc += o; }
        float tot = __shfl(inc, 29);
        float run = inc - p;
        run += e0; exst(gb + r0 + base2,     run, mode);
        run += e1; exst(gb + r0 + base2 + 1, run, mode);
        run += e2; exst(gb + r0 + base2 + 2, run, mode);
        run += e3; exst(gb + r0 + base2 + 3, run, mode);
        run += e4; exst(gb + r0 + base2 + 4, run, mode);
        if (tid == 0) exst(sums + (ch - 2), tot, mode);
      }
    }
    sbar(slotsA, ch, t + 1, tid, mode);
    if (tid < 375)      { f4 v = ld4x((const f4*)gb + tid, mode); *(f4*)(ga_l + 4 * tid) = v; }
    else if (tid < 377) { int q = tid - 375; f4 v = ld4x((const f4*)sums + q, mode); *(f4*)(sums_l + 4 * q) = v; }
    float pvn = 0.f;
    if (t + 1 < LLEN && tid < RPB) pvn = pre[((size_t)(t + 1) * BB + b) * G5 + r0 + tid];
    __syncthreads();
    if (tid < HH) {
      float c = ga_l[tid];
      float v[4];
      #pragma unroll
      for (int s1 = 0; s1 < 4; ++s1) {
        float raw = ga_l[(s1 + 1) * HH + tid];
        float off = (tid >= RPB) ? sums_l[2 * s1] : 0.f;
        float S = sums_l[2 * s1] + sums_l[2 * s1 + 1];
        v[s1] = (raw + off) / S;
      }
      float eg_cin = 1.f - v[0], rg_cin = v[1], eg_c = 1.f - v[2], rg_c = v[3];
      float ci = (t > 0) ? ci_l[tid] : 0.f;
      float ov_c = rg_c * eg_c;
      float up_c = rg_c - ov_c, dn_c = eg_c - ov_c;
      float ov_i = rg_cin * eg_cin;
      float up_i = rg_cin - ov_i, dn_i = eg_cin - ov_i;
      float share = ov_i * ci + ov_c * c;
      float c_re  = up_i * ci + up_c * c + share;
      float c_ner = dn_i * ci + dn_c * c + share;
      cat_l[tid] = c_re; cat_l[HH + tid] = c_ner; cat_l[2 * HH + tid] = share;
      int sb = ch * OPB;
      if (tid >= sb && tid < sb + OPB) {
        size_t ob = ((size_t)t * BB + b) * HH + tid;
        hner[ob] = tanhf(c_ner); hre[ob] = tanhf(c_re); hsh[ob] = tanhf(share);
      }
    }
    __syncthreads();
    if (tid < 480) {
      float acc = 0.f;
      #pragma unroll
      for (int q = 0; q < 29; ++q)
        if (q < nk2) acc += wt[q].x * cat_l[2 * (k2b + q)] + wt[q].y * cat_l[2 * (k2b + q) + 1];
      ps[tid] = acc;
    }
    __syncthreads();
    if (tid < OPB) {
      float co = btrf[ch * OPB + tid];
      #pragma unroll
      for (int q = 0; q < 16; ++q) co += ps[q * OPB + tid];
      exst(cb + ch * OPB + tid, co, mode);
      exst(hb + ch * OPB + tid, tanhf(co), mode);
    }
    if (t + 1 < LLEN) sbar(slotsB, ch, t + 1, tid, mode);
    pv = pvn;
  }
}

// ---- fused h_glob + A/E features ----
__global__ void k_post(const float* hsh, const float* hner, const float* hre,
                       const void* nW, const void* nb, const void* rW, const void* rb,
                       const void* nhW, const void* nhb, const void* rhW, const void* rhb,
                       const void* mk, float* hg0, float* hg1,
                       float* A0, float* E0, float* A1, float* E1) {
  bool f32 = is32(mk);
  int role = blockIdx.x >> 8;   // 0 = glob, 1 = feat
  int sub  = blockIdx.x & 255;
  int task = sub >> 7;
  int lb0 = (sub & 127) * 4;
  __shared__ __align__(16) float buf[2400];
  int tid = threadIdx.x;
  if (role == 0) {
    const float* tsk = task ? hre : hner;
    const void* gWo = task ? rW : nW;
    const void* gbo = task ? rb : nb;
    float* hg = task ? hg1 : hg0;
    for (int e = tid; e < 2400; e += 320) {
      int rr = e / 600, c = e - rr * 600;
      buf[e] = (c < HH) ? hsh[(size_t)(lb0 + rr) * HH + c] : tsk[(size_t)(lb0 + rr) * HH + (c - HH)];
    }
    __syncthreads();
    if (tid < HH) {
      float bias = ldin(gbo, tid, f32);
      float acc[4] = {bias, bias, bias, bias};
      if (f32) {
        const float4* row = (const float4*)((const float*)gWo + (size_t)tid * 600);
        #pragma unroll 2
        for (int k = 0; k < 150; ++k) {
          float4 u = row[k];
          #pragma unroll
          for (int rr = 0; rr < 4; ++rr) {
            const float4 cv = *(const float4*)(buf + rr * 600 + 4 * k);
            acc[rr] += u.x * cv.x + u.y * cv.y + u.z * cv.z + u.w * cv.w;
          }
        }
      } else {
        for (int k = 0; k < 600; ++k) {
          float w = ldin(gWo, tid * 600 + k, f32);
          #pragma unroll
          for (int rr = 0; rr < 4; ++rr) acc[rr] += w * buf[rr * 600 + k];
        }
      }
      #pragma unroll
      for (int rr = 0; rr < 4; ++rr) hg[(size_t)(lb0 + rr) * HH + tid] = tanhf(acc[rr]);
    }
  } else {
    const float* tsk = task ? hre : hner;
    const void* hWo = task ? rhW : nhW;
    const void* hbo = task ? rhb : nhb;
    float* A = task ? A1 : A0;
    float* E = task ? E1 : E0;
    for (int e = tid; e < 1200; e += 320) {
      int rr = e / 300, c = e - rr * 300;
      buf[e] = tsk[(size_t)(lb0 + rr) * HH + c];
    }
    __syncthreads();
    if (tid < HH) {
      float bias = ldin(hbo, tid, f32);
      float a[4] = {bias, bias, bias, bias};
      float ev[4] = {0.f, 0.f, 0.f, 0.f};
      if (f32) {
        const float4* r1 = (const float4*)((const float*)hWo + (size_t)tid * H3);
        const float4* r2 = (const float4*)((const float*)hWo + (size_t)tid * H3 + HH);
        #pragma unroll 2
        for (int k = 0; k < 75; ++k) {
          float4 u = r1[k], w2 = r2[k];
          #pragma unroll
          for (int rr = 0; rr < 4; ++rr) {
            const float4 tv = *(const float4*)(buf + rr * 300 + 4 * k);
            a[rr]  += u.x * tv.x + u.y * tv.y + u.z * tv.z + u.w * tv.w;
            ev[rr] += w2.x * tv.x + w2.y * tv.y + w2.z * tv.z + w2.w * tv.w;
          }
        }
      } else {
        for (int k = 0; k < HH; ++k) {
          float w1 = ldin(hWo, tid * H3 + k, f32);
          float w2 = ldin(hWo, tid * H3 + HH + k, f32);
          #pragma unroll
          for (int rr = 0; rr < 4; ++rr) {
            a[rr] += w1 * buf[rr * 300 + k];
            ev[rr] += w2 * buf[rr * 300 + k];
          }
        }
      }
      #pragma unroll
      for (int rr = 0; rr < 4; ++rr) {
        A[(size_t)(lb0 + rr) * HH + tid] = a[rr];
        E[(size_t)(lb0 + rr) * HH + tid] = ev[rr];
      }
    }
  }
}

// ---- fused gmax + gf ----
__global__ void k_gmf(const float* hg0, const float* hg1, const void* nhW, const void* rhW,
                      const void* mk, float* Gf0, float* Gf1) {
  bool f32 = is32(mk);
  int task = blockIdx.x >> 2, b = blockIdx.x & 3;
  const float* hg = task ? hg1 : hg0;
  const void* hWo = task ? rhW : nhW;
  float* Gf = task ? Gf1 : Gf0;
  __shared__ __align__(16) float gl[304];
  int tid = threadIdx.x;
  if (tid < HH) {
    float m = -1e30f;
    for (int l = 0; l < LLEN; ++l) m = fmaxf(m, hg[((size_t)l * BB + b) * HH + tid]);
    gl[tid] = m;
  }
  __syncthreads();
  if (tid < HH) {
    float acc = 0.f;
    if (f32) {
      const float4* row = (const float4*)((const float*)hWo + (size_t)tid * H3 + 600);
      #pragma unroll 5
      for (int k = 0; k < 75; ++k) {
        float4 u = row[k];
        const float4 gv = *(const float4*)(gl + 4 * k);
        acc += u.x * gv.x + u.y * gv.y + u.z * gv.z + u.w * gv.w;
      }
    } else {
      for (int k = 0; k < HH; ++k) acc += gl[k] * ldin(hWo, tid * H3 + 600 + k, f32);
    }
    Gf[b * HH + tid] = acc;
  }
}

// ---- pair epilogue v7: 8 j-pairs per block; fully-masked NER blocks skip compute ----
__global__ void __launch_bounds__(256) k_pair7(const float* A0, const float* E0, const float* Gf0,
                                               const void* lg0, const void* lb0_, const void* tW0, const void* tb0,
                                               const float* A1, const float* E1, const float* Gf1,
                                               const void* lg1, const void* lb1_, const void* tW1, const void* tb1,
                                               const void* mk, void* outv) {
  __shared__ float lg_l[304], lb_l[304], tb_l[16];
  __shared__ float tw_l[3616];
  bool f32 = is32(mk);
  int tau = blockIdx.x >> 11;
  int bid = blockIdx.x & 2047;
  int i = bid >> 4;
  int j0 = (bid & 15) << 3;
  int T = tau ? NRR : NTT;
  int diag = tau ? 0 : 1;
  int Toff = tau ? 458752 : 0;
  int tid = threadIdx.x;
  int b = tid >> 6, ln = tid & 63;
  if (diag && j0 + 7 < i) {  // block-uniform: entire 8-j tile below diagonal -> zeros
    if (ln < T) {
      #pragma unroll
      for (int dj = 0; dj < 8; ++dj) {
        size_t obase = (size_t)Toff + ((size_t)(i * LLEN + j0 + dj) * BB + b) * T;
        if (f32) ((float*)outv)[obase + ln] = 0.f;
        else ((u16*)outv)[obase + ln] = 0;
      }
    }
    return;
  }
  const float* A  = tau ? A1 : A0;
  const float* E  = tau ? E1 : E0;
  const float* Gf = tau ? Gf1 : Gf0;
  const void* lgo = tau ? lg1 : lg0;
  const void* lbo = tau ? lb1_ : lb0_;
  const void* tWo = tau ? tW1 : tW0;
  const void* tbo = tau ? tb1 : tb0;
  for (int i2 = tid; i2 < HH; i2 += 256) { lg_l[i2] = ldin(lgo, i2, f32); lb_l[i2] = ldin(lbo, i2, f32); }
  for (int i2 = tid; i2 < T * HH; i2 += 256) tw_l[i2] = ldin(tWo, i2, f32);
  if (tid < T) tb_l[tid] = ldin(tbo, tid, f32);
  __syncthreads();
  const float* ar = A  + (size_t)(i * BB + b) * HH;
  const float* gr = Gf + (size_t)b * HH;
  bool ok4 = ln < 44;
  float a0 = ar[ln]       + gr[ln];
  float a1 = ar[64 + ln]  + gr[64 + ln];
  float a2 = ar[128 + ln] + gr[128 + ln];
  float a3 = ar[192 + ln] + gr[192 + ln];
  float a4 = ok4 ? (ar[256 + ln] + gr[256 + ln]) : 0.f;
  float mi = ldin(mk, i * BB + b, f32);
  for (int dj = 0; dj < 8; ++dj) {
    int jx = j0 + dj;
    const float* er = E + (size_t)(jx * BB + b) * HH;
    float u0 = a0 + er[ln];
    float u1 = a1 + er[64 + ln];
    float u2 = a2 + er[128 + ln];
    float u3 = a3 + er[192 + ln];
    float u4 = ok4 ? (a4 + er[256 + ln]) : 0.f;
    float s1 = ((u0 + u1) + (u2 + u3)) + u4;
    float s2 = ((u0 * u0 + u1 * u1) + (u2 * u2 + u3 * u3)) + u4 * u4;
    #pragma unroll
    for (int d = 1; d < 64; d <<= 1) { s1 += __shfl_xor(s1, d); s2 += __shfl_xor(s2, d); }
    float mean = s1 * (1.f / 300.f);
    float var = s2 * (1.f / 300.f) - mean * mean;
    float rstd = rsqrtf(var + 1e-5f);
    {
      float y;
      y = (u0 - mean) * rstd * lg_l[ln]       + lb_l[ln];       u0 = (y > 0.f) ? y : __expf(y) - 1.f;
      y = (u1 - mean) * rstd * lg_l[64 + ln]  + lb_l[64 + ln];  u1 = (y > 0.f) ? y : __expf(y) - 1.f;
      y = (u2 - mean) * rstd * lg_l[128 + ln] + lb_l[128 + ln]; u2 = (y > 0.f) ? y : __expf(y) - 1.f;
      y = (u3 - mean) * rstd * lg_l[192 + ln] + lb_l[192 + ln]; u3 = (y > 0.f) ? y : __expf(y) - 1.f;
      if (ok4) {
        y = (u4 - mean) * rstd * lg_l[256 + ln] + lb_l[256 + ln];
        u4 = (y > 0.f) ? y : __expf(y) - 1.f;
      }
    }
    float m = mi * ldin(mk, jx * BB + b, f32);
    if (diag && jx < i) m = 0.f;
    size_t obase = (size_t)Toff + ((size_t)(i * LLEN + jx) * BB + b) * T;
    float mine = 0.f;
    for (int t = 0; t < T; ++t) {
      const float* twr = tw_l + t * HH;
      float s = u0 * twr[ln] + u1 * twr[64 + ln] + u2 * twr[128 + ln] + u3 * twr[192 + ln];
      if (ok4) s += u4 * twr[256 + ln];
      s = wsum(s);
      s += tb_l[t];
      float o = m / (1.f + __expf(-s));
      mine = (ln == t) ? o : mine;
    }
    if (ln < T) {
      if (f32) ((float*)outv)[obase + ln] = mine;
      else ((u16*)outv)[obase + ln] = f2bf(mine);
    }
  }
}

// ---- sentinel ----
__global__ void k_sent(const void* mk, const void* xo, void* outv, int hostcode) {
  __shared__ int bad;
  if (threadIdx.x == 0) bad = 0;
  __syncthreads();
  bool f32 = is32(mk);
  for (int i = threadIdx.x; i < 4096; i += 256) {
    float v = ldin(xo, i, f32);
    if (!(v == v) || fabsf(v) > 1e6f) bad = 1;
  }
  __syncthreads();
  if (threadIdx.x == 0) {
    float code = (float)hostcode;
    if (bad) code = fmaxf(code, 88.f);
    if (code > 0.f) {
      if (f32) ((float*)outv)[0] = code;
      else ((u16*)outv)[0] = f2bf(code);
    }
  }
}

extern "C" void kernel_launch(void* const* d_in, const int* in_sizes, int n_in,
                              void* d_out, int out_size, void* d_ws, size_t ws_size,
                              hipStream_t stream) {
  const void* x    = d_in[0];
  const void* mask = d_in[1];
  const void* Wih  = d_in[2];
  const void* bih  = d_in[3];
  const void* Whh  = d_in[4];
  const void* bhh  = d_in[5];
  const void* Wtr  = d_in[6];
  const void* btr  = d_in[7];
  const void* nW   = d_in[8];
  const void* nb   = d_in[9];
  const void* nhW  = d_in[10];
  const void* nhb  = d_in[11];
  const void* ng   = d_in[12];
  const void* nbe  = d_in[13];
  const void* ntW  = d_in[14];
  const void* ntb  = d_in[15];
  const void* rW   = d_in[16];
  const void* rb   = d_in[17];
  const void* rhW  = d_in[18];
  const void* rhb  = d_in[19];
  const void* rg   = d_in[20];
  const void* rbe  = d_in[21];
  const void* rtW  = d_in[22];
  const void* rtb  = d_in[23];
  float* ws = (float*)d_ws;

  static const int exp_sz[24] = {393216, 512, 1152000, 1500, 450000, 1500, 270000, 300,
                                 180000, 300, 270000, 300, 300, 300, 2100, 7,
                                 180000, 300, 270000, 300, 300, 300, 3600, 12};
  int hostcode = 0;
  if (n_in != 24) hostcode = 890;
  else {
    for (int ii = 0; ii < 24; ++ii)
      if (in_sizes[ii] != exp_sz[ii]) { hostcode = 900 + ii; break; }
  }
  if (hostcode == 0 && out_size != 1245184) hostcode = 880;
  if (hostcode == 0 && ws_size < WS_NEED_BYTES) hostcode = 1099;

  dim3 gc(512, 5);
  k_canon<<<gc, 256, 0, stream>>>(x, mask, Wih, bih, Whh, bhh, Wtr, btr, ws);
  k_scanA<<<128, 512, 0, stream>>>(ws + F_PRE, (const float2*)(ws + C_WHH2), (const float2*)(ws + C_WTR2),
                                   ws + F_BTR, ws + F_HNER, ws + F_HRE, ws + F_HSH, ws + F_AUX, ws);
  k_scanB<<<128, 512, 0, stream>>>(ws + F_PRE, (const float2*)(ws + C_WHH2), (const float2*)(ws + C_WTR2),
                                   ws + F_BTR, ws + F_HNER, ws + F_HRE, ws + F_HSH, ws + F_AUX);
  k_post<<<512, 320, 0, stream>>>(ws + F_HSH, ws + F_HNER, ws + F_HRE,
                                  nW, nb, rW, rb, nhW, nhb, rhW, rhb, mask,
                                  ws + F_HG0, ws + F_HG1, ws + F_A0, ws + F_E0, ws + F_A1, ws + F_E1);
  k_gmf<<<8, 320, 0, stream>>>(ws + F_HG0, ws + F_HG1, nhW, rhW, mask, ws + F_GF0, ws + F_GF1);
  k_pair7<<<4096, 256, 0, stream>>>(ws + F_A0, ws + F_E0, ws + F_GF0, ng, nbe, ntW, ntb,
                                    ws + F_A1, ws + F_E1, ws + F_GF1, rg, rbe, rtW, rtb,
                                    mask, d_out);
  k_sent<<<1, 256, 0, stream>>>(mask, x, d_out, hostcode);
}